// Round 5
// baseline (1132.393 us; speedup 1.0000x reference)
//
#include <hip/hip_runtime.h>

#define DD 128

typedef __attribute__((ext_vector_type(8))) short bh8;       // 8 bf16 (as i16 bits)
typedef __attribute__((ext_vector_type(8))) unsigned short us8;
typedef __attribute__((ext_vector_type(4))) float f4;
typedef unsigned int u32;

// ================= CSR build (real edges only; self-loops handled analytically) =================

__global__ __launch_bounds__(256) void init_counts_k(int* cn, int* ce, int N, int E) {
  int g = blockIdx.x * blockDim.x + threadIdx.x;
  if (g < E) ce[g] = 0;
  if (g < N) cn[g] = 0;
}

__global__ __launch_bounds__(256) void hist_k(const int* __restrict__ ni, const int* __restrict__ ei,
                                              int* cn, int* ce, int nnz) {
  int stride = gridDim.x * blockDim.x;
  for (int j = blockIdx.x * blockDim.x + threadIdx.x; j < nnz; j += stride) {
    atomicAdd(&cn[ni[j]], 1);
    atomicAdd(&ce[ei[j]], 1);
  }
}

__global__ __launch_bounds__(1024) void exscan2_k(const int* __restrict__ cn, int* offs_n, int N,
                                                  const int* __restrict__ ce, int* offs_e, int E) {
  const int* cnt = blockIdx.x ? ce : cn;
  int* offs = blockIdx.x ? offs_e : offs_n;
  int n = blockIdx.x ? E : N;
  __shared__ int sums[1024];
  __shared__ int carry;
  const int tid = threadIdx.x;
  if (tid == 0) carry = 0;
  __syncthreads();
  const int PER = 8;
  const int CH = 1024 * PER;
  for (int base = 0; base < n; base += CH) {
    int i0 = base + tid * PER;
    int v[PER]; int s = 0;
    #pragma unroll
    for (int j = 0; j < PER; ++j) { int i = i0 + j; int t = (i < n) ? cnt[i] : 0; v[j] = t; s += t; }
    sums[tid] = s;
    __syncthreads();
    for (int off = 1; off < 1024; off <<= 1) {
      int t = (tid >= off) ? sums[tid - off] : 0;
      __syncthreads();
      sums[tid] += t;
      __syncthreads();
    }
    int excl = sums[tid] - s + carry;
    #pragma unroll
    for (int j = 0; j < PER; ++j) { int i = i0 + j; if (i < n) offs[i] = excl; excl += v[j]; }
    __syncthreads();
    if (tid == 0) carry += sums[1023];
    __syncthreads();
  }
  if (tid == 0) offs[n] = carry;
}

// inverse degrees (Dn includes +1 self) + staged cursors + legacy cursors
__global__ __launch_bounds__(256) void fill_deg_k(const int* __restrict__ offs_n, const int* __restrict__ offs_e,
                                                  float* Dn_inv, float* De_inv,
                                                  int* cur_be, int* cur_bn, int* cur_n, int* cur_e,
                                                  int N, int E, int NBE, int NBN) {
  int g = blockIdx.x * blockDim.x + threadIdx.x;
  if (g < E) {
    int b = offs_e[g], e = offs_e[g + 1];
    De_inv[g] = (e > b) ? 1.0f / (float)(e - b) : 0.0f;
    cur_e[g] = b;
  }
  if (g < N) {
    int b = offs_n[g], e = offs_n[g + 1];
    Dn_inv[g] = 1.0f / (float)(e - b + 1);   // +1 for the self loop
    cur_n[g] = b;
  }
  if (g < NBE) {
    int r1 = (g + 1) * 32; if (r1 > E) r1 = E;
    int o0 = offs_e[g * 32], o1 = offs_e[r1];
    int C = o1 - o0, base = 8 * o0;
    #pragma unroll
    for (int k = 0; k < 8; ++k) cur_be[g * 8 + k] = base + k * C;
  }
  if (g < NBN) {
    int r1 = (g + 1) * 32; if (r1 > N) r1 = N;
    int o0 = offs_n[g * 32], o1 = offs_n[r1];
    int C = o1 - o0, base = 8 * o0;
    #pragma unroll
    for (int k = 0; k < 8; ++k) cur_bn[g * 8 + k] = base + k * C;
  }
}

// XCD-local binning
__global__ __launch_bounds__(256) void partition2_k(const int* __restrict__ ni, const int* __restrict__ ei,
                                                    int* cur_be, int* cur_bn,
                                                    u32* __restrict__ SE, u32* __restrict__ SN, int nnz) {
  int xcd;
  asm volatile("s_getreg_b32 %0, hwreg(HW_REG_XCC_ID)" : "=s"(xcd));
  xcd &= 7;
  int stride = gridDim.x * blockDim.x;
  for (int j = blockIdx.x * blockDim.x + threadIdx.x; j < nnz; j += stride) {
    int n = ni[j], e = ei[j];
    int pe = atomicAdd(&cur_be[(e >> 5) * 8 + xcd], 1);
    SE[pe] = ((u32)(e & 31) << 17) | (u32)n;
    int pn = atomicAdd(&cur_bn[(n >> 5) * 8 + xcd], 1);
    SN[pn] = ((u32)(n & 31) << 17) | (u32)e;
  }
}

__global__ __launch_bounds__(256) void scatter2_k(const u32* __restrict__ S, const int* __restrict__ offs,
                                                  const int* __restrict__ cur_b,
                                                  int* __restrict__ list, int nRows) {
  __shared__ int cur[32];
  const int b = blockIdx.x;
  const int i0 = b << 5;
  const int tid = threadIdx.x;
  if (tid < 32) {
    int row = i0 + tid;
    cur[tid] = (row < nRows) ? offs[row] : 0;
  }
  __syncthreads();
  int r1 = i0 + 32; if (r1 > nRows) r1 = nRows;
  const int o0 = offs[i0];
  const int C = offs[r1] - o0;
  #pragma unroll 1
  for (int k = 0; k < 8; ++k) {
    int sbeg = 8 * o0 + k * C;
    int send = cur_b[b * 8 + k];
    for (int i = sbeg + tid; i < send; i += 256) {
      u32 v = S[i];
      int pos = atomicAdd(&cur[v >> 17], 1);
      list[pos] = (int)(v & 0x1FFFFu);
    }
  }
}

// legacy fallback scatter
__global__ __launch_bounds__(256) void fill_nnz_k(const int* __restrict__ ni, const int* __restrict__ ei,
                                                  int* cur_n, int* cur_e, int* listN, int* listE, int nnz) {
  int stride = gridDim.x * blockDim.x;
  for (int j = blockIdx.x * blockDim.x + threadIdx.x; j < nnz; j += stride) {
    int n = ni[j], e = ei[j];
    int pn = atomicAdd(&cur_n[n], 1); listN[pn] = e;
    int pe = atomicAdd(&cur_e[e], 1); listE[pe] = n;
  }
}

// ================= gathers (width 256, 1 wave/row) =================

// edge rows (real edges only): e = prelu(De_inv*sum(t[members]) + bias)
// optional split copies to d2a/d2b (layer 2 e-outputs)
template<int SPLIT>
__global__ __launch_bounds__(256) void gather_edge_k(const float* __restrict__ src,
                                                     const int* __restrict__ offs, const int* __restrict__ list,
                                                     const float* __restrict__ De_inv,
                                                     const float* __restrict__ b1, const float* __restrict__ b2,
                                                     const float* __restrict__ alphap,
                                                     float* __restrict__ e_full,
                                                     float* __restrict__ d2a, float* __restrict__ d2b, int E) {
  const int wave = threadIdx.x >> 6, lane = threadIdx.x & 63;
  const int row = blockIdx.x * 4 + wave;
  if (row >= E) return;
  const int c = lane * 4;
  const int beg = offs[row], end = offs[row + 1];
  float4 a0 = {0,0,0,0}, a1 = {0,0,0,0}, a2 = {0,0,0,0}, a3 = {0,0,0,0};
  int i = beg;
  for (; i + 3 < end; i += 4) {
    int s0 = list[i], s1 = list[i + 1], s2 = list[i + 2], s3 = list[i + 3];
    float4 v0 = *(const float4*)&src[(size_t)s0 * 256 + c];
    float4 v1 = *(const float4*)&src[(size_t)s1 * 256 + c];
    float4 v2 = *(const float4*)&src[(size_t)s2 * 256 + c];
    float4 v3 = *(const float4*)&src[(size_t)s3 * 256 + c];
    a0.x += v0.x; a0.y += v0.y; a0.z += v0.z; a0.w += v0.w;
    a1.x += v1.x; a1.y += v1.y; a1.z += v1.z; a1.w += v1.w;
    a2.x += v2.x; a2.y += v2.y; a2.z += v2.z; a2.w += v2.w;
    a3.x += v3.x; a3.y += v3.y; a3.z += v3.z; a3.w += v3.w;
  }
  for (; i < end; ++i) {
    float4 v = *(const float4*)&src[(size_t)list[i] * 256 + c];
    a0.x += v.x; a0.y += v.y; a0.z += v.z; a0.w += v.w;
  }
  float sc = De_inv[row];
  const float* bp = (c < 128) ? (b1 + c) : (b2 + c - 128);
  float4 bt = *(const float4*)bp;
  float al = *alphap;
  float4 o;
  o.x = sc * ((a0.x + a1.x) + (a2.x + a3.x)) + bt.x;
  o.y = sc * ((a0.y + a1.y) + (a2.y + a3.y)) + bt.y;
  o.z = sc * ((a0.z + a1.z) + (a2.z + a3.z)) + bt.z;
  o.w = sc * ((a0.w + a1.w) + (a2.w + a3.w)) + bt.w;
  o.x = (o.x >= 0.f) ? o.x : al * o.x;
  o.y = (o.y >= 0.f) ? o.y : al * o.y;
  o.z = (o.z >= 0.f) ? o.z : al * o.z;
  o.w = (o.w >= 0.f) ? o.w : al * o.w;
  *(float4*)&e_full[(size_t)row * 256 + c] = o;
  if constexpr (SPLIT == 1) {
    if (c < 128) *(float4*)&d2a[(size_t)row * DD + c] = o;
    else         *(float4*)&d2b[(size_t)row * DD + c - 128] = o;
  }
}

// node rows: dst = Dn_inv * ( prelu(t[row]+bias) + sum(e_full[edges]) )
__global__ __launch_bounds__(256) void gather_node_k(const float* __restrict__ e_full,
                                                     const float* __restrict__ t,
                                                     const int* __restrict__ offs, const int* __restrict__ list,
                                                     const float* __restrict__ Dn_inv,
                                                     const float* __restrict__ b1, const float* __restrict__ b2,
                                                     const float* __restrict__ alphap,
                                                     float* __restrict__ dst, int N) {
  const int wave = threadIdx.x >> 6, lane = threadIdx.x & 63;
  const int row = blockIdx.x * 4 + wave;
  if (row >= N) return;
  const int c = lane * 4;
  const int beg = offs[row], end = offs[row + 1];
  float4 a0 = {0,0,0,0}, a1 = {0,0,0,0}, a2 = {0,0,0,0}, a3 = {0,0,0,0};
  int i = beg;
  for (; i + 3 < end; i += 4) {
    int s0 = list[i], s1 = list[i + 1], s2 = list[i + 2], s3 = list[i + 3];
    float4 v0 = *(const float4*)&e_full[(size_t)s0 * 256 + c];
    float4 v1 = *(const float4*)&e_full[(size_t)s1 * 256 + c];
    float4 v2 = *(const float4*)&e_full[(size_t)s2 * 256 + c];
    float4 v3 = *(const float4*)&e_full[(size_t)s3 * 256 + c];
    a0.x += v0.x; a0.y += v0.y; a0.z += v0.z; a0.w += v0.w;
    a1.x += v1.x; a1.y += v1.y; a1.z += v1.z; a1.w += v1.w;
    a2.x += v2.x; a2.y += v2.y; a2.z += v2.z; a2.w += v2.w;
    a3.x += v3.x; a3.y += v3.y; a3.z += v3.z; a3.w += v3.w;
  }
  for (; i < end; ++i) {
    float4 v = *(const float4*)&e_full[(size_t)list[i] * 256 + c];
    a0.x += v.x; a0.y += v.y; a0.z += v.z; a0.w += v.w;
  }
  // self edge: prelu(t[row] + bias), De=1
  float4 tv = *(const float4*)&t[(size_t)row * 256 + c];
  const float* bp = (c < 128) ? (b1 + c) : (b2 + c - 128);
  float4 bt = *(const float4*)bp;
  float al = *alphap;
  float sx = tv.x + bt.x; sx = (sx >= 0.f) ? sx : al * sx;
  float sy = tv.y + bt.y; sy = (sy >= 0.f) ? sy : al * sy;
  float sz = tv.z + bt.z; sz = (sz >= 0.f) ? sz : al * sz;
  float sw = tv.w + bt.w; sw = (sw >= 0.f) ? sw : al * sw;
  float sc = Dn_inv[row];
  float4 o;
  o.x = sc * (sx + ((a0.x + a1.x) + (a2.x + a3.x)));
  o.y = sc * (sy + ((a0.y + a1.y) + (a2.y + a3.y)));
  o.z = sc * (sz + ((a0.z + a1.z) + (a2.z + a3.z)));
  o.w = sc * (sw + ((a0.w + a1.w) + (a2.w + a3.w)));
  *(float4*)&dst[(size_t)row * 256 + c] = o;
}

// ================= weight prep =================

struct WPtrs { const float* p[16]; };

__global__ __launch_bounds__(256) void prep_w_k(WPtrs wp, char* dst) {
  int m = blockIdx.x >> 3, s = blockIdx.x & 7;
  const float* W = wp.p[m];
  int t = threadIdx.x;
  int n = t & 127;
  int k0 = s * 16 + (t >> 7) * 8;
  us8 vhi, vlo;
  #pragma unroll
  for (int j = 0; j < 8; ++j) {
    float x = W[(size_t)(k0 + j) * DD + n];
    u32 ux = __builtin_bit_cast(u32, x);
    float hf = __builtin_bit_cast(float, ux & 0xFFFF0000u);
    float l = x - hf;
    vhi[j] = (unsigned short)(ux >> 16);
    vlo[j] = (unsigned short)(__builtin_bit_cast(u32, l) >> 16);
  }
  char* base = dst + (size_t)m * 65536;
  int byte = n * 256 + k0 * 2;
  byte ^= (n & 7) << 4;
  *(us8*)(base + byte) = vhi;
  *(us8*)(base + 32768 + byte) = vlo;
}

// ================= MFMA machinery =================

__device__ __forceinline__ void stage_w(const char* gsrc, char* lds, int tid) {
  int wave = tid >> 6, lane = tid & 63;
  #pragma unroll
  for (int i = 0; i < 16; ++i) {
    int off = (wave * 16 + i) * 1024;
    __builtin_amdgcn_global_load_lds(
        (const __attribute__((address_space(1))) u32*)(gsrc + off + lane * 16),
        (__attribute__((address_space(3))) u32*)(lds + off), 16, 0, 0);
  }
}

__device__ __forceinline__ void split8(const float vs[8], bh8& hi, bh8& lo) {
  #pragma unroll
  for (int j = 0; j < 8; ++j) {
    u32 u = __builtin_bit_cast(u32, vs[j]);
    float hf = __builtin_bit_cast(float, u & 0xFFFF0000u);
    float l = vs[j] - hf;
    hi[j] = (short)(u >> 16);
    lo[j] = (short)(__builtin_bit_cast(u32, l) >> 16);
  }
}

__device__ __forceinline__ void mk_afrag(const float* rowp, int koff, bh8& hi, bh8& lo) {
  float4 v0 = *(const float4*)(rowp + koff);
  float4 v1 = *(const float4*)(rowp + koff + 4);
  float vs[8] = {v0.x, v0.y, v0.z, v0.w, v1.x, v1.y, v1.z, v1.w};
  split8(vs, hi, lo);
}

struct AFrag { bh8 hi[4]; bh8 lo[4]; };

__device__ __forceinline__ void load_afragS(const float* __restrict__ A, size_t astride, int acoff,
                                            int rbase, int nrows, int lane, AFrag& f) {
  int r = rbase + (lane & 15);
  if (r >= nrows) r = nrows - 1;
  const float* rowp = A + (size_t)r * astride + acoff;
  const int koff0 = (lane >> 4) * 8;
  #pragma unroll
  for (int ks = 0; ks < 4; ++ks) mk_afrag(rowp, ks * 32 + koff0, f.hi[ks], f.lo[ks]);
}

__device__ __forceinline__ void mfma_ks(const bh8& ahi, const bh8& alo, const char* Wl,
                                        int ks, int lane, f4 acc[8]) {
  const int koff0 = (lane >> 4) * 8;
  const int k2 = (ks * 32 + koff0) * 2;
  #pragma unroll
  for (int cb = 0; cb < 8; ++cb) {
    int n = cb * 16 + (lane & 15);
    int byte = (n * 256 + k2) ^ ((n & 7) << 4);
    bh8 bhiF = *(const bh8*)(Wl + byte);
    bh8 bloF = *(const bh8*)(Wl + 32768 + byte);
    acc[cb] = __builtin_amdgcn_mfma_f32_16x16x32_bf16(ahi, bhiF, acc[cb], 0, 0, 0);
    acc[cb] = __builtin_amdgcn_mfma_f32_16x16x32_bf16(ahi, bloF, acc[cb], 0, 0, 0);
    acc[cb] = __builtin_amdgcn_mfma_f32_16x16x32_bf16(alo, bhiF, acc[cb], 0, 0, 0);
  }
}

__device__ __forceinline__ void mfma_passS(const float* __restrict__ A, size_t astride, int acoff,
                                           const char* Wl, int rbase, int nrows, int lane, f4 acc[8]) {
  int r = rbase + (lane & 15);
  if (r >= nrows) r = nrows - 1;
  const float* rowp = A + (size_t)r * astride + acoff;
  const int koff0 = (lane >> 4) * 8;
  #pragma unroll
  for (int ks = 0; ks < 4; ++ks) {
    bh8 ahi, alo;
    mk_afrag(rowp, ks * 32 + koff0, ahi, alo);
    mfma_ks(ahi, alo, Wl, ks, lane, acc);
  }
}

__device__ __forceinline__ void mfma_pass_frag(const AFrag& f, const char* Wl, int lane, f4 acc[8]) {
  #pragma unroll
  for (int ks = 0; ks < 4; ++ks) mfma_ks(f.hi[ks], f.lo[ks], Wl, ks, lane, acc);
}

template<int MODE>
__device__ __forceinline__ void epilogueS(f4 acc[8], const float* bias, const float* alphap,
                                          float* out, size_t ostride, int ocoff,
                                          int rbase, int nrows, int lane) {
  float al = 0.f;
  if constexpr (MODE == 1) al = *alphap;
  const int cidx = lane & 15;
  int rq = rbase + (lane >> 4) * 4;
  float b8[8];
  if constexpr (MODE == 1) {
    #pragma unroll
    for (int cb = 0; cb < 8; ++cb) b8[cb] = bias[cb * 16 + cidx];
  }
  #pragma unroll
  for (int q = 0; q < 4; ++q) {
    int row = rq + q;
    if (row < nrows) {
      float* op = out + (size_t)row * ostride + ocoff + cidx;
      #pragma unroll
      for (int cb = 0; cb < 8; ++cb) {
        float v = acc[cb][q];
        if constexpr (MODE == 1) { v += b8[cb]; v = (v >= 0.f) ? v : al * v; }
        op[cb * 16] = v;
      }
    }
  }
}

#define ACC_ZERO(acc) { _Pragma("unroll") for (int cb = 0; cb < 8; ++cb) acc[cb] = {0.f, 0.f, 0.f, 0.f}; }

// ================= GEMM kernels =================

// persistent (tile-looped): out halves h1 = A1@W1 (+act), h2 = A2@W2 (+act)
template<int MODE>
__global__ __launch_bounds__(256, 2) void gemm_halves_k(const float* __restrict__ A1, size_t as1, int ac1, const char* W1, const float* b1_,
                                                        const float* __restrict__ A2, size_t as2, int ac2, const char* W2, const float* b2_,
                                                        const float* __restrict__ alphap,
                                                        float* __restrict__ out, int nrows, int ntiles) {
  __shared__ char Wl[65536];
  const int wave = threadIdx.x >> 6, lane = threadIdx.x & 63;
  f4 acc[8];
  stage_w(W1, Wl, threadIdx.x);
  __syncthreads();
  for (int t = blockIdx.x; t < ntiles; t += gridDim.x) {
    int rbase = t * 64 + wave * 16;
    ACC_ZERO(acc);
    mfma_passS(A1, as1, ac1, Wl, rbase, nrows, lane, acc);
    epilogueS<MODE>(acc, b1_, alphap, out, 256, 0, rbase, nrows, lane);
  }
  __syncthreads();
  stage_w(W2, Wl, threadIdx.x);
  __syncthreads();
  for (int t = blockIdx.x; t < ntiles; t += gridDim.x) {
    int rbase = t * 64 + wave * 16;
    ACC_ZERO(acc);
    mfma_passS(A2, as2, ac2, Wl, rbase, nrows, lane, acc);
    epilogueS<MODE>(acc, b2_, alphap, out, 256, 128, rbase, nrows, lane);
  }
}

// encoder final (persistent): n1/n2 + nn1 halves
__global__ __launch_bounds__(256, 2) void enc_final_k(const float* __restrict__ agg, const char* W1, const float* b1_,
                                                      const char* W2, const float* b2_,
                                                      const float* __restrict__ alphap,
                                                      float* __restrict__ n1, float* __restrict__ n2,
                                                      float* __restrict__ nn1, int nrows, int ntiles) {
  __shared__ char Wl[65536];
  const int wave = threadIdx.x >> 6, lane = threadIdx.x & 63;
  const int cidx = lane & 15;
  f4 acc[8];
  float al = *alphap;
  #pragma unroll 1
  for (int h = 0; h < 2; ++h) {
    if (h) __syncthreads();
    stage_w(h ? W2 : W1, Wl, threadIdx.x);
    __syncthreads();
    const float* bp = h ? b2_ : b1_;
    float* nout = h ? n2 : n1;
    float b8[8];
    #pragma unroll
    for (int cb = 0; cb < 8; ++cb) b8[cb] = bp[cb * 16 + cidx];
    for (int t = blockIdx.x; t < ntiles; t += gridDim.x) {
      int rbase = t * 64 + wave * 16;
      ACC_ZERO(acc);
      mfma_passS(agg, 256, h * 128, Wl, rbase, nrows, lane, acc);
      int rq = rbase + (lane >> 4) * 4;
      #pragma unroll
      for (int q = 0; q < 4; ++q) {
        int row = rq + q;
        if (row < nrows) {
          float* op = nout + (size_t)row * DD + cidx;
          float* op2 = nn1 + (size_t)row * 256 + h * 128 + cidx;
          #pragma unroll
          for (int cb = 0; cb < 8; ++cb) {
            float v = acc[cb][q] + b8[cb];
            v = (v >= 0.f) ? v : al * v;
            op[cb * 16] = v;
            op2[cb * 16] = v;
          }
        }
      }
    }
  }
}

// decoder pair layer: o1 = prelu(xA@WxA + agg_h@WeA + bA); o2 = prelu(xB@WxB + agg_h@WeB + bB)
__global__ __launch_bounds__(256, 2) void dec_pair_k(const float* __restrict__ xA, const float* __restrict__ xB,
                                                     const float* __restrict__ agg, int acoff,
                                                     const char* WxA, const char* WeA, const float* bA,
                                                     const char* WxB, const char* WeB, const float* bB,
                                                     const float* __restrict__ alphap,
                                                     float* __restrict__ o1, float* __restrict__ o2, int nrows) {
  __shared__ char Wl[65536];
  const int wave = threadIdx.x >> 6, lane = threadIdx.x & 63;
  const int rbase = blockIdx.x * 64 + wave * 16;
  AFrag fa;
  load_afragS(agg, 256, acoff, rbase, nrows, lane, fa);
  f4 acc[8];
  stage_w(WxA, Wl, threadIdx.x);
  __syncthreads();
  ACC_ZERO(acc);
  mfma_passS(xA, DD, 0, Wl, rbase, nrows, lane, acc);
  __syncthreads();
  stage_w(WeA, Wl, threadIdx.x);
  __syncthreads();
  mfma_pass_frag(fa, Wl, lane, acc);
  epilogueS<1>(acc, bA, alphap, o1, DD, 0, rbase, nrows, lane);
  __syncthreads();
  stage_w(WxB, Wl, threadIdx.x);
  __syncthreads();
  ACC_ZERO(acc);
  mfma_passS(xB, DD, 0, Wl, rbase, nrows, lane, acc);
  __syncthreads();
  stage_w(WeB, Wl, threadIdx.x);
  __syncthreads();
  mfma_pass_frag(fa, Wl, lane, acc);
  epilogueS<1>(acc, bB, alphap, o2, DD, 0, rbase, nrows, lane);
}

// ================= host =================

extern "C" void kernel_launch(void* const* d_in, const int* in_sizes, int n_in,
                              void* d_out, int out_size, void* d_ws, size_t ws_size,
                              hipStream_t stream) {
  const float* x        = (const float*)d_in[0];
  const float* xx       = (const float*)d_in[1];
  const int*   node_idx = (const int*)d_in[2];
  const int*   edge_idx = (const int*)d_in[3];
  const float* alphap   = (const float*)d_in[6];
  const float* e1_Wn2e  = (const float*)d_in[7];
  const float* e1_bn2e  = (const float*)d_in[8];
  const float* e1_We2n  = (const float*)d_in[9];
  const float* e1_be2n  = (const float*)d_in[10];
  const float* e2_Wn2e  = (const float*)d_in[11];
  const float* e2_bn2e  = (const float*)d_in[12];
  const float* e2_We2n  = (const float*)d_in[13];
  const float* e2_be2n  = (const float*)d_in[14];
  const float* d1_We    = (const float*)d_in[15];
  const float* d1_Wx    = (const float*)d_in[16];
  const float* d1_b     = (const float*)d_in[17];
  const float* d2_We    = (const float*)d_in[18];
  const float* d2_Wx    = (const float*)d_in[19];
  const float* d2_b     = (const float*)d_in[20];

  const int N   = in_sizes[0] / DD;
  const int NNZ = in_sizes[2];
  const int E   = (out_size - 1024 * N) / 256;
  const int NBE = (E + 31) >> 5;
  const int NBN = (N + 31) >> 5;

  // ---- d_out slot map ----
  float* out  = (float*)d_out;
  float* nn1  = out;
  float* n1   = out + (size_t)N * 256;
  float* e1o  = n1 + (size_t)N * DD;
  float* n2   = e1o + (size_t)E * DD;
  float* e2o  = n2 + (size_t)N * DD;
  float* x11  = e2o + (size_t)E * DD;
  float* x21  = x11 + (size_t)N * DD;
  float* x12  = x21 + (size_t)N * DD;
  float* x22  = x12 + (size_t)N * DD;

  // ---- workspace carve ----
  size_t off = 0;
  char* w0 = (char*)d_ws;
  auto carve = [&](size_t bytes) -> void* {
    void* p = (void*)(w0 + off);
    off += (bytes + 255) & ~(size_t)255;
    return p;
  };
  int* cn      = (int*)carve((size_t)N * 4);
  int* ce      = (int*)carve((size_t)E * 4);
  int* offs_n  = (int*)carve((size_t)(N + 1) * 4);
  int* offs_e  = (int*)carve((size_t)(E + 1) * 4);
  int* listN   = (int*)carve((size_t)NNZ * 4);
  int* listE   = (int*)carve((size_t)NNZ * 4);
  float* Dn_inv = (float*)carve((size_t)N * 4);
  float* De_inv = (float*)carve((size_t)E * 4);
  char* Wprep  = (char*)carve((size_t)16 * 65536);
  float* t0    = (float*)carve((size_t)N * 256 * 4);
  float* t1    = (float*)carve((size_t)N * 256 * 4);
  float* agg   = (float*)carve((size_t)N * 256 * 4);
  float* e_full = (float*)carve((size_t)E * 256 * 4);
  int* cur_n   = (int*)carve((size_t)N * 4);
  int* cur_e   = (int*)carve((size_t)E * 4);
  // staged-CSR extras
  int* cur_be  = (int*)carve((size_t)NBE * 8 * 4);
  int* cur_bn  = (int*)carve((size_t)NBN * 8 * 4);
  u32* SE      = (u32*)carve((size_t)NNZ * 8 * 4);
  u32* SN      = (u32*)carve((size_t)NNZ * 8 * 4);
  const bool staged = off <= ws_size;

  // ---- weight prep table ----
  WPtrs wp;
  wp.p[0] = e1_Wn2e;  wp.p[1] = e1_Wn2e + DD * DD;
  wp.p[2] = e1_We2n;  wp.p[3] = e1_We2n + DD * DD;
  wp.p[4] = e2_Wn2e;  wp.p[5] = e2_Wn2e + DD * DD;
  wp.p[6] = e2_We2n;  wp.p[7] = e2_We2n + DD * DD;
  wp.p[8] = d1_We;    wp.p[9] = d1_We + DD * DD;
  wp.p[10] = d1_Wx;   wp.p[11] = d1_Wx + DD * DD;
  wp.p[12] = d2_We;   wp.p[13] = d2_We + DD * DD;
  wp.p[14] = d2_Wx;   wp.p[15] = d2_Wx + DD * DD;
  auto WP = [&](int i) -> const char* { return Wprep + (size_t)i * 65536; };

  const int thr = 256;
  const int gMax = ((N > E ? N : E) + thr - 1) / thr;
  int gNNZ = (NNZ + thr - 1) / thr; if (gNNZ > 2048) gNNZ = 2048;
  const int NT = (N + 63) / 64;        // 64-row tiles
  const int gGemm = NT;                // per-tile kernels (dec_pair)
  const int gPers = (NT + 1) / 2;      // persistent 2-tile kernels
  const int gGatE = (E + 3) / 4;
  const int gGatN = (N + 3) / 4;

  prep_w_k<<<128, 256, 0, stream>>>(wp, Wprep);
  init_counts_k<<<gMax, thr, 0, stream>>>(cn, ce, N, E);
  hist_k<<<gNNZ, thr, 0, stream>>>(node_idx, edge_idx, cn, ce, NNZ);
  exscan2_k<<<2, 1024, 0, stream>>>(cn, offs_n, N, ce, offs_e, E);
  fill_deg_k<<<gMax, thr, 0, stream>>>(offs_n, offs_e, Dn_inv, De_inv,
                                       cur_be, cur_bn, cur_n, cur_e, N, E, NBE, NBN);

  if (staged) {
    partition2_k<<<gNNZ, thr, 0, stream>>>(node_idx, edge_idx, cur_be, cur_bn, SE, SN, NNZ);
    scatter2_k<<<NBE, 256, 0, stream>>>(SE, offs_e, cur_be, listE, E);
    scatter2_k<<<NBN, 256, 0, stream>>>(SN, offs_n, cur_bn, listN, N);
  } else {
    fill_nnz_k<<<gNNZ, thr, 0, stream>>>(node_idx, edge_idx, cur_n, cur_e, listN, listE, NNZ);
  }

  // ---- fused dual-encoder (width-256: half1 = enc1, half2 = enc2) ----
  // L1 in: t0 = [x@W0 | xx@W4]
  gemm_halves_k<0><<<gPers, 256, 0, stream>>>(x, DD, 0, WP(0), nullptr,
                                              xx, DD, 0, WP(4), nullptr, alphap, t0, N, NT);
  // e(L1) real edges
  gather_edge_k<0><<<gGatE, 256, 0, stream>>>(t0, offs_e, listE, De_inv, e1_bn2e, e2_bn2e,
                                              alphap, e_full, nullptr, nullptr, E);
  // t1 = Dn_inv*(prelu(t0+bn2e_0) + seg_n(e))
  gather_node_k<<<gGatN, 256, 0, stream>>>(e_full, t0, offs_n, listN, Dn_inv, e1_bn2e, e2_bn2e,
                                           alphap, t1, N);
  // hidden: t0 = prelu(t1@We2n_0 + be2n_0)
  gemm_halves_k<1><<<gPers, 256, 0, stream>>>(t1, 256, 0, WP(2), e1_be2n,
                                              t1, 256, 128, WP(6), e2_be2n, alphap, t0, N, NT);
  // L2 in: t1 = hidden@Wn2e_1
  gemm_halves_k<0><<<gPers, 256, 0, stream>>>(t0, 256, 0, WP(1), nullptr,
                                              t0, 256, 128, WP(5), nullptr, alphap, t1, N, NT);
  // e(L2) (+ e1o/e2o outputs)
  gather_edge_k<1><<<gGatE, 256, 0, stream>>>(t1, offs_e, listE, De_inv, e1_bn2e + DD, e2_bn2e + DD,
                                              alphap, e_full, e1o, e2o, E);
  // agg = Dn_inv*(prelu(t1+bn2e_1) + seg_n(e))
  gather_node_k<<<gGatN, 256, 0, stream>>>(e_full, t1, offs_n, listN, Dn_inv, e1_bn2e + DD, e2_bn2e + DD,
                                           alphap, agg, N);
  // n1, n2, nn1
  enc_final_k<<<gPers, 256, 0, stream>>>(agg, WP(3), e1_be2n + DD, WP(7), e2_be2n + DD,
                                         alphap, n1, n2, nn1, N, NT);

  // ---- decoders ----
  float* dt0 = t0;
  float* dt1 = t0 + (size_t)N * DD;
  dec_pair_k<<<gGemm, 256, 0, stream>>>(n1, n1, agg, 0, WP(10), WP(8), d1_b, WP(14), WP(12), d2_b,
                                        alphap, dt0, dt1, N);
  dec_pair_k<<<gGemm, 256, 0, stream>>>(dt0, dt1, agg, 0, WP(11), WP(9), d1_b + DD, WP(15), WP(13), d2_b + DD,
                                        alphap, x11, x22, N);
  dec_pair_k<<<gGemm, 256, 0, stream>>>(n2, n2, agg, 128, WP(10), WP(8), d1_b, WP(14), WP(12), d2_b,
                                        alphap, dt0, dt1, N);
  dec_pair_k<<<gGemm, 256, 0, stream>>>(dt0, dt1, agg, 128, WP(11), WP(9), d1_b + DD, WP(15), WP(13), d2_b + DD,
                                        alphap, x12, x21, N);
}

// Round 6
// 969.844 us; speedup vs baseline: 1.1676x; 1.1676x over previous
//
#include <hip/hip_runtime.h>

#define DD 128

typedef __attribute__((ext_vector_type(8))) short bh8;       // 8 bf16 (as i16 bits)
typedef __attribute__((ext_vector_type(8))) unsigned short us8;
typedef __attribute__((ext_vector_type(4))) float f4;
typedef unsigned int u32;

// ================= CSR build (real edges only; self-loops handled analytically) =================

__global__ __launch_bounds__(256) void init_counts_k(int* cn, int* ce, int N, int E) {
  int g = blockIdx.x * blockDim.x + threadIdx.x;
  if (g < E) ce[g] = 0;
  if (g < N) cn[g] = 0;
}

__global__ __launch_bounds__(256) void hist_k(const int* __restrict__ ni, const int* __restrict__ ei,
                                              int* cn, int* ce, int nnz) {
  int stride = gridDim.x * blockDim.x;
  for (int j = blockIdx.x * blockDim.x + threadIdx.x; j < nnz; j += stride) {
    atomicAdd(&cn[ni[j]], 1);
    atomicAdd(&ce[ei[j]], 1);
  }
}

__global__ __launch_bounds__(1024) void exscan2_k(const int* __restrict__ cn, int* offs_n, int N,
                                                  const int* __restrict__ ce, int* offs_e, int E) {
  const int* cnt = blockIdx.x ? ce : cn;
  int* offs = blockIdx.x ? offs_e : offs_n;
  int n = blockIdx.x ? E : N;
  __shared__ int sums[1024];
  __shared__ int carry;
  const int tid = threadIdx.x;
  if (tid == 0) carry = 0;
  __syncthreads();
  const int PER = 8;
  const int CH = 1024 * PER;
  for (int base = 0; base < n; base += CH) {
    int i0 = base + tid * PER;
    int v[PER]; int s = 0;
    #pragma unroll
    for (int j = 0; j < PER; ++j) { int i = i0 + j; int t = (i < n) ? cnt[i] : 0; v[j] = t; s += t; }
    sums[tid] = s;
    __syncthreads();
    for (int off = 1; off < 1024; off <<= 1) {
      int t = (tid >= off) ? sums[tid - off] : 0;
      __syncthreads();
      sums[tid] += t;
      __syncthreads();
    }
    int excl = sums[tid] - s + carry;
    #pragma unroll
    for (int j = 0; j < PER; ++j) { int i = i0 + j; if (i < n) offs[i] = excl; excl += v[j]; }
    __syncthreads();
    if (tid == 0) carry += sums[1023];
    __syncthreads();
  }
  if (tid == 0) offs[n] = carry;
}

// inverse degrees (Dn includes +1 self) + staged cursors + legacy cursors
__global__ __launch_bounds__(256) void fill_deg_k(const int* __restrict__ offs_n, const int* __restrict__ offs_e,
                                                  float* Dn_inv, float* De_inv,
                                                  int* cur_be, int* cur_bn, int* cur_n, int* cur_e,
                                                  int N, int E, int NBE, int NBN) {
  int g = blockIdx.x * blockDim.x + threadIdx.x;
  if (g < E) {
    int b = offs_e[g], e = offs_e[g + 1];
    De_inv[g] = (e > b) ? 1.0f / (float)(e - b) : 0.0f;
    cur_e[g] = b;
  }
  if (g < N) {
    int b = offs_n[g], e = offs_n[g + 1];
    Dn_inv[g] = 1.0f / (float)(e - b + 1);   // +1 for the self loop
    cur_n[g] = b;
  }
  if (g < NBE) {
    int r1 = (g + 1) * 32; if (r1 > E) r1 = E;
    int o0 = offs_e[g * 32], o1 = offs_e[r1];
    int C = o1 - o0, base = 8 * o0;
    #pragma unroll
    for (int k = 0; k < 8; ++k) cur_be[g * 8 + k] = base + k * C;
  }
  if (g < NBN) {
    int r1 = (g + 1) * 32; if (r1 > N) r1 = N;
    int o0 = offs_n[g * 32], o1 = offs_n[r1];
    int C = o1 - o0, base = 8 * o0;
    #pragma unroll
    for (int k = 0; k < 8; ++k) cur_bn[g * 8 + k] = base + k * C;
  }
}

// XCD-local binning
__global__ __launch_bounds__(256) void partition2_k(const int* __restrict__ ni, const int* __restrict__ ei,
                                                    int* cur_be, int* cur_bn,
                                                    u32* __restrict__ SE, u32* __restrict__ SN, int nnz) {
  int xcd;
  asm volatile("s_getreg_b32 %0, hwreg(HW_REG_XCC_ID)" : "=s"(xcd));
  xcd &= 7;
  int stride = gridDim.x * blockDim.x;
  for (int j = blockIdx.x * blockDim.x + threadIdx.x; j < nnz; j += stride) {
    int n = ni[j], e = ei[j];
    int pe = atomicAdd(&cur_be[(e >> 5) * 8 + xcd], 1);
    SE[pe] = ((u32)(e & 31) << 17) | (u32)n;
    int pn = atomicAdd(&cur_bn[(n >> 5) * 8 + xcd], 1);
    SN[pn] = ((u32)(n & 31) << 17) | (u32)e;
  }
}

__global__ __launch_bounds__(256) void scatter2_k(const u32* __restrict__ S, const int* __restrict__ offs,
                                                  const int* __restrict__ cur_b,
                                                  int* __restrict__ list, int nRows) {
  __shared__ int cur[32];
  const int b = blockIdx.x;
  const int i0 = b << 5;
  const int tid = threadIdx.x;
  if (tid < 32) {
    int row = i0 + tid;
    cur[tid] = (row < nRows) ? offs[row] : 0;
  }
  __syncthreads();
  int r1 = i0 + 32; if (r1 > nRows) r1 = nRows;
  const int o0 = offs[i0];
  const int C = offs[r1] - o0;
  #pragma unroll 1
  for (int k = 0; k < 8; ++k) {
    int sbeg = 8 * o0 + k * C;
    int send = cur_b[b * 8 + k];
    for (int i = sbeg + tid; i < send; i += 256) {
      u32 v = S[i];
      int pos = atomicAdd(&cur[v >> 17], 1);
      list[pos] = (int)(v & 0x1FFFFu);
    }
  }
}

// legacy fallback scatter
__global__ __launch_bounds__(256) void fill_nnz_k(const int* __restrict__ ni, const int* __restrict__ ei,
                                                  int* cur_n, int* cur_e, int* listN, int* listE, int nnz) {
  int stride = gridDim.x * blockDim.x;
  for (int j = blockIdx.x * blockDim.x + threadIdx.x; j < nnz; j += stride) {
    int n = ni[j], e = ei[j];
    int pn = atomicAdd(&cur_n[n], 1); listN[pn] = e;
    int pe = atomicAdd(&cur_e[e], 1); listE[pe] = n;
  }
}

// ================= gathers (width 256, 1 wave/row) =================

// edge rows (real edges only): e = prelu(De_inv*sum(t[members]) + bias)
template<int SPLIT>
__global__ __launch_bounds__(256) void gather_edge_k(const float* __restrict__ src,
                                                     const int* __restrict__ offs, const int* __restrict__ list,
                                                     const float* __restrict__ De_inv,
                                                     const float* __restrict__ b1, const float* __restrict__ b2,
                                                     const float* __restrict__ alphap,
                                                     float* __restrict__ e_full,
                                                     float* __restrict__ d2a, float* __restrict__ d2b, int E) {
  const int wave = threadIdx.x >> 6, lane = threadIdx.x & 63;
  const int row = blockIdx.x * 4 + wave;
  if (row >= E) return;
  const int c = lane * 4;
  const int beg = offs[row], end = offs[row + 1];
  float4 a0 = {0,0,0,0}, a1 = {0,0,0,0}, a2 = {0,0,0,0}, a3 = {0,0,0,0};
  int i = beg;
  for (; i + 3 < end; i += 4) {
    int s0 = list[i], s1 = list[i + 1], s2 = list[i + 2], s3 = list[i + 3];
    float4 v0 = *(const float4*)&src[(size_t)s0 * 256 + c];
    float4 v1 = *(const float4*)&src[(size_t)s1 * 256 + c];
    float4 v2 = *(const float4*)&src[(size_t)s2 * 256 + c];
    float4 v3 = *(const float4*)&src[(size_t)s3 * 256 + c];
    a0.x += v0.x; a0.y += v0.y; a0.z += v0.z; a0.w += v0.w;
    a1.x += v1.x; a1.y += v1.y; a1.z += v1.z; a1.w += v1.w;
    a2.x += v2.x; a2.y += v2.y; a2.z += v2.z; a2.w += v2.w;
    a3.x += v3.x; a3.y += v3.y; a3.z += v3.z; a3.w += v3.w;
  }
  for (; i < end; ++i) {
    float4 v = *(const float4*)&src[(size_t)list[i] * 256 + c];
    a0.x += v.x; a0.y += v.y; a0.z += v.z; a0.w += v.w;
  }
  float sc = De_inv[row];
  const float* bp = (c < 128) ? (b1 + c) : (b2 + c - 128);
  float4 bt = *(const float4*)bp;
  float al = *alphap;
  float4 o;
  o.x = sc * ((a0.x + a1.x) + (a2.x + a3.x)) + bt.x;
  o.y = sc * ((a0.y + a1.y) + (a2.y + a3.y)) + bt.y;
  o.z = sc * ((a0.z + a1.z) + (a2.z + a3.z)) + bt.z;
  o.w = sc * ((a0.w + a1.w) + (a2.w + a3.w)) + bt.w;
  o.x = (o.x >= 0.f) ? o.x : al * o.x;
  o.y = (o.y >= 0.f) ? o.y : al * o.y;
  o.z = (o.z >= 0.f) ? o.z : al * o.z;
  o.w = (o.w >= 0.f) ? o.w : al * o.w;
  *(float4*)&e_full[(size_t)row * 256 + c] = o;
  if constexpr (SPLIT == 1) {
    if (c < 128) *(float4*)&d2a[(size_t)row * DD + c] = o;
    else         *(float4*)&d2b[(size_t)row * DD + c - 128] = o;
  }
}

// node rows: dst = Dn_inv * ( prelu(t[row]+bias) + sum(e_full[edges]) )
__global__ __launch_bounds__(256) void gather_node_k(const float* __restrict__ e_full,
                                                     const float* __restrict__ t,
                                                     const int* __restrict__ offs, const int* __restrict__ list,
                                                     const float* __restrict__ Dn_inv,
                                                     const float* __restrict__ b1, const float* __restrict__ b2,
                                                     const float* __restrict__ alphap,
                                                     float* __restrict__ dst, int N) {
  const int wave = threadIdx.x >> 6, lane = threadIdx.x & 63;
  const int row = blockIdx.x * 4 + wave;
  if (row >= N) return;
  const int c = lane * 4;
  const int beg = offs[row], end = offs[row + 1];
  float4 a0 = {0,0,0,0}, a1 = {0,0,0,0}, a2 = {0,0,0,0}, a3 = {0,0,0,0};
  int i = beg;
  for (; i + 3 < end; i += 4) {
    int s0 = list[i], s1 = list[i + 1], s2 = list[i + 2], s3 = list[i + 3];
    float4 v0 = *(const float4*)&e_full[(size_t)s0 * 256 + c];
    float4 v1 = *(const float4*)&e_full[(size_t)s1 * 256 + c];
    float4 v2 = *(const float4*)&e_full[(size_t)s2 * 256 + c];
    float4 v3 = *(const float4*)&e_full[(size_t)s3 * 256 + c];
    a0.x += v0.x; a0.y += v0.y; a0.z += v0.z; a0.w += v0.w;
    a1.x += v1.x; a1.y += v1.y; a1.z += v1.z; a1.w += v1.w;
    a2.x += v2.x; a2.y += v2.y; a2.z += v2.z; a2.w += v2.w;
    a3.x += v3.x; a3.y += v3.y; a3.z += v3.z; a3.w += v3.w;
  }
  for (; i < end; ++i) {
    float4 v = *(const float4*)&e_full[(size_t)list[i] * 256 + c];
    a0.x += v.x; a0.y += v.y; a0.z += v.z; a0.w += v.w;
  }
  float4 tv = *(const float4*)&t[(size_t)row * 256 + c];
  const float* bp = (c < 128) ? (b1 + c) : (b2 + c - 128);
  float4 bt = *(const float4*)bp;
  float al = *alphap;
  float sx = tv.x + bt.x; sx = (sx >= 0.f) ? sx : al * sx;
  float sy = tv.y + bt.y; sy = (sy >= 0.f) ? sy : al * sy;
  float sz = tv.z + bt.z; sz = (sz >= 0.f) ? sz : al * sz;
  float sw = tv.w + bt.w; sw = (sw >= 0.f) ? sw : al * sw;
  float sc = Dn_inv[row];
  float4 o;
  o.x = sc * (sx + ((a0.x + a1.x) + (a2.x + a3.x)));
  o.y = sc * (sy + ((a0.y + a1.y) + (a2.y + a3.y)));
  o.z = sc * (sz + ((a0.z + a1.z) + (a2.z + a3.z)));
  o.w = sc * (sw + ((a0.w + a1.w) + (a2.w + a3.w)));
  *(float4*)&dst[(size_t)row * 256 + c] = o;
}

// ================= weight prep =================

struct WPtrs { const float* p[16]; };

__global__ __launch_bounds__(256) void prep_w_k(WPtrs wp, char* dst) {
  int m = blockIdx.x >> 3, s = blockIdx.x & 7;
  const float* W = wp.p[m];
  int t = threadIdx.x;
  int n = t & 127;
  int k0 = s * 16 + (t >> 7) * 8;
  us8 vhi, vlo;
  #pragma unroll
  for (int j = 0; j < 8; ++j) {
    float x = W[(size_t)(k0 + j) * DD + n];
    u32 ux = __builtin_bit_cast(u32, x);
    float hf = __builtin_bit_cast(float, ux & 0xFFFF0000u);
    float l = x - hf;
    vhi[j] = (unsigned short)(ux >> 16);
    vlo[j] = (unsigned short)(__builtin_bit_cast(u32, l) >> 16);
  }
  char* base = dst + (size_t)m * 65536;
  int byte = n * 256 + k0 * 2;
  byte ^= (n & 7) << 4;
  *(us8*)(base + byte) = vhi;
  *(us8*)(base + 32768 + byte) = vlo;
}

// ================= MFMA machinery =================

__device__ __forceinline__ void stage_w(const char* gsrc, char* lds, int tid) {
  int wave = tid >> 6, lane = tid & 63;
  #pragma unroll
  for (int i = 0; i < 16; ++i) {
    int off = (wave * 16 + i) * 1024;
    __builtin_amdgcn_global_load_lds(
        (const __attribute__((address_space(1))) u32*)(gsrc + off + lane * 16),
        (__attribute__((address_space(3))) u32*)(lds + off), 16, 0, 0);
  }
}

__device__ __forceinline__ void split8(const float vs[8], bh8& hi, bh8& lo) {
  #pragma unroll
  for (int j = 0; j < 8; ++j) {
    u32 u = __builtin_bit_cast(u32, vs[j]);
    float hf = __builtin_bit_cast(float, u & 0xFFFF0000u);
    float l = vs[j] - hf;
    hi[j] = (short)(u >> 16);
    lo[j] = (short)(__builtin_bit_cast(u32, l) >> 16);
  }
}

__device__ __forceinline__ void mk_afrag(const float* rowp, int koff, bh8& hi, bh8& lo) {
  float4 v0 = *(const float4*)(rowp + koff);
  float4 v1 = *(const float4*)(rowp + koff + 4);
  float vs[8] = {v0.x, v0.y, v0.z, v0.w, v1.x, v1.y, v1.z, v1.w};
  split8(vs, hi, lo);
}

struct AFrag { bh8 hi[4]; bh8 lo[4]; };

__device__ __forceinline__ void load_afragS(const float* __restrict__ A, size_t astride, int acoff,
                                            int rbase, int nrows, int lane, AFrag& f) {
  int r = rbase + (lane & 15);
  if (r >= nrows) r = nrows - 1;
  const float* rowp = A + (size_t)r * astride + acoff;
  const int koff0 = (lane >> 4) * 8;
  #pragma unroll
  for (int ks = 0; ks < 4; ++ks) mk_afrag(rowp, ks * 32 + koff0, f.hi[ks], f.lo[ks]);
}

__device__ __forceinline__ void mfma_ks(const bh8& ahi, const bh8& alo, const char* Wl,
                                        int ks, int lane, f4 acc[8]) {
  const int koff0 = (lane >> 4) * 8;
  const int k2 = (ks * 32 + koff0) * 2;
  #pragma unroll
  for (int cb = 0; cb < 8; ++cb) {
    int n = cb * 16 + (lane & 15);
    int byte = (n * 256 + k2) ^ ((n & 7) << 4);
    bh8 bhiF = *(const bh8*)(Wl + byte);
    bh8 bloF = *(const bh8*)(Wl + 32768 + byte);
    acc[cb] = __builtin_amdgcn_mfma_f32_16x16x32_bf16(ahi, bhiF, acc[cb], 0, 0, 0);
    acc[cb] = __builtin_amdgcn_mfma_f32_16x16x32_bf16(ahi, bloF, acc[cb], 0, 0, 0);
    acc[cb] = __builtin_amdgcn_mfma_f32_16x16x32_bf16(alo, bhiF, acc[cb], 0, 0, 0);
  }
}

__device__ __forceinline__ void mfma_passS(const float* __restrict__ A, size_t astride, int acoff,
                                           const char* Wl, int rbase, int nrows, int lane, f4 acc[8]) {
  int r = rbase + (lane & 15);
  if (r >= nrows) r = nrows - 1;
  const float* rowp = A + (size_t)r * astride + acoff;
  const int koff0 = (lane >> 4) * 8;
  #pragma unroll
  for (int ks = 0; ks < 4; ++ks) {
    bh8 ahi, alo;
    mk_afrag(rowp, ks * 32 + koff0, ahi, alo);
    mfma_ks(ahi, alo, Wl, ks, lane, acc);
  }
}

__device__ __forceinline__ void mfma_pass_frag(const AFrag& f, const char* Wl, int lane, f4 acc[8]) {
  #pragma unroll
  for (int ks = 0; ks < 4; ++ks) mfma_ks(f.hi[ks], f.lo[ks], Wl, ks, lane, acc);
}

template<int MODE>
__device__ __forceinline__ void epilogueS(f4 acc[8], const float* bias, const float* alphap,
                                          float* out, size_t ostride, int ocoff,
                                          int rbase, int nrows, int lane) {
  float al = 0.f;
  if constexpr (MODE == 1) al = *alphap;
  const int cidx = lane & 15;
  int rq = rbase + (lane >> 4) * 4;
  float b8[8];
  if constexpr (MODE == 1) {
    #pragma unroll
    for (int cb = 0; cb < 8; ++cb) b8[cb] = bias[cb * 16 + cidx];
  }
  #pragma unroll
  for (int q = 0; q < 4; ++q) {
    int row = rq + q;
    if (row < nrows) {
      float* op = out + (size_t)row * ostride + ocoff + cidx;
      #pragma unroll
      for (int cb = 0; cb < 8; ++cb) {
        float v = acc[cb][q];
        if constexpr (MODE == 1) { v += b8[cb]; v = (v >= 0.f) ? v : al * v; }
        op[cb * 16] = v;
      }
    }
  }
}

#define ACC_ZERO(acc) { _Pragma("unroll") for (int cb = 0; cb < 8; ++cb) acc[cb] = {0.f, 0.f, 0.f, 0.f}; }

// ================= GEMM kernels (per-tile grids) =================

// out256 halves: h1 = A1@W1 (+act), h2 = A2@W2 (+act)
template<int MODE>
__global__ __launch_bounds__(256, 2) void gemm_halves_k(const float* __restrict__ A1, size_t as1, int ac1, const char* W1, const float* b1_,
                                                        const float* __restrict__ A2, size_t as2, int ac2, const char* W2, const float* b2_,
                                                        const float* __restrict__ alphap,
                                                        float* __restrict__ out, int nrows) {
  __shared__ char Wl[65536];
  const int wave = threadIdx.x >> 6, lane = threadIdx.x & 63;
  const int rbase = blockIdx.x * 64 + wave * 16;
  f4 acc[8];
  stage_w(W1, Wl, threadIdx.x);
  __syncthreads();
  ACC_ZERO(acc);
  mfma_passS(A1, as1, ac1, Wl, rbase, nrows, lane, acc);
  epilogueS<MODE>(acc, b1_, alphap, out, 256, 0, rbase, nrows, lane);
  __syncthreads();
  stage_w(W2, Wl, threadIdx.x);
  __syncthreads();
  ACC_ZERO(acc);
  mfma_passS(A2, as2, ac2, Wl, rbase, nrows, lane, acc);
  epilogueS<MODE>(acc, b2_, alphap, out, 256, 128, rbase, nrows, lane);
}

// encoder final: n1 = prelu(agg_h1@W1+b1), n2 = prelu(agg_h2@W2+b2); nn1 gets both halves
__global__ __launch_bounds__(256, 2) void enc_final_k(const float* __restrict__ agg, const char* W1, const float* b1_,
                                                      const char* W2, const float* b2_,
                                                      const float* __restrict__ alphap,
                                                      float* __restrict__ n1, float* __restrict__ n2,
                                                      float* __restrict__ nn1, int nrows) {
  __shared__ char Wl[65536];
  const int wave = threadIdx.x >> 6, lane = threadIdx.x & 63;
  const int rbase = blockIdx.x * 64 + wave * 16;
  const int cidx = lane & 15;
  f4 acc[8];
  float al = *alphap;
  #pragma unroll 1
  for (int h = 0; h < 2; ++h) {
    if (h) __syncthreads();
    stage_w(h ? W2 : W1, Wl, threadIdx.x);
    __syncthreads();
    const float* bp = h ? b2_ : b1_;
    float* nout = h ? n2 : n1;
    float b8[8];
    #pragma unroll
    for (int cb = 0; cb < 8; ++cb) b8[cb] = bp[cb * 16 + cidx];
    ACC_ZERO(acc);
    mfma_passS(agg, 256, h * 128, Wl, rbase, nrows, lane, acc);
    int rq = rbase + (lane >> 4) * 4;
    #pragma unroll
    for (int q = 0; q < 4; ++q) {
      int row = rq + q;
      if (row < nrows) {
        float* op = nout + (size_t)row * DD + cidx;
        float* op2 = nn1 + (size_t)row * 256 + h * 128 + cidx;
        #pragma unroll
        for (int cb = 0; cb < 8; ++cb) {
          float v = acc[cb][q] + b8[cb];
          v = (v >= 0.f) ? v : al * v;
          op[cb * 16] = v;
          op2[cb * 16] = v;
        }
      }
    }
  }
}

// decoder pair layer: o1 = prelu(xA@WxA + agg_h@WeA + bA); o2 = prelu(xB@WxB + agg_h@WeB + bB)
__global__ __launch_bounds__(256, 2) void dec_pair_k(const float* __restrict__ xA, const float* __restrict__ xB,
                                                     const float* __restrict__ agg, int acoff,
                                                     const char* WxA, const char* WeA, const float* bA,
                                                     const char* WxB, const char* WeB, const float* bB,
                                                     const float* __restrict__ alphap,
                                                     float* __restrict__ o1, float* __restrict__ o2, int nrows) {
  __shared__ char Wl[65536];
  const int wave = threadIdx.x >> 6, lane = threadIdx.x & 63;
  const int rbase = blockIdx.x * 64 + wave * 16;
  AFrag fa;
  load_afragS(agg, 256, acoff, rbase, nrows, lane, fa);
  f4 acc[8];
  stage_w(WxA, Wl, threadIdx.x);
  __syncthreads();
  ACC_ZERO(acc);
  mfma_passS(xA, DD, 0, Wl, rbase, nrows, lane, acc);
  __syncthreads();
  stage_w(WeA, Wl, threadIdx.x);
  __syncthreads();
  mfma_pass_frag(fa, Wl, lane, acc);
  epilogueS<1>(acc, bA, alphap, o1, DD, 0, rbase, nrows, lane);
  __syncthreads();
  stage_w(WxB, Wl, threadIdx.x);
  __syncthreads();
  ACC_ZERO(acc);
  mfma_passS(xB, DD, 0, Wl, rbase, nrows, lane, acc);
  __syncthreads();
  stage_w(WeB, Wl, threadIdx.x);
  __syncthreads();
  mfma_pass_frag(fa, Wl, lane, acc);
  epilogueS<1>(acc, bB, alphap, o2, DD, 0, rbase, nrows, lane);
}

// ================= host =================

extern "C" void kernel_launch(void* const* d_in, const int* in_sizes, int n_in,
                              void* d_out, int out_size, void* d_ws, size_t ws_size,
                              hipStream_t stream) {
  const float* x        = (const float*)d_in[0];
  const float* xx       = (const float*)d_in[1];
  const int*   node_idx = (const int*)d_in[2];
  const int*   edge_idx = (const int*)d_in[3];
  const float* alphap   = (const float*)d_in[6];
  const float* e1_Wn2e  = (const float*)d_in[7];
  const float* e1_bn2e  = (const float*)d_in[8];
  const float* e1_We2n  = (const float*)d_in[9];
  const float* e1_be2n  = (const float*)d_in[10];
  const float* e2_Wn2e  = (const float*)d_in[11];
  const float* e2_bn2e  = (const float*)d_in[12];
  const float* e2_We2n  = (const float*)d_in[13];
  const float* e2_be2n  = (const float*)d_in[14];
  const float* d1_We    = (const float*)d_in[15];
  const float* d1_Wx    = (const float*)d_in[16];
  const float* d1_b     = (const float*)d_in[17];
  const float* d2_We    = (const float*)d_in[18];
  const float* d2_Wx    = (const float*)d_in[19];
  const float* d2_b     = (const float*)d_in[20];

  const int N   = in_sizes[0] / DD;
  const int NNZ = in_sizes[2];
  const int E   = (out_size - 1024 * N) / 256;
  const int NBE = (E + 31) >> 5;
  const int NBN = (N + 31) >> 5;

  // ---- d_out slot map ----
  float* out  = (float*)d_out;
  float* nn1  = out;
  float* n1   = out + (size_t)N * 256;
  float* e1o  = n1 + (size_t)N * DD;
  float* n2   = e1o + (size_t)E * DD;
  float* e2o  = n2 + (size_t)N * DD;
  float* x11  = e2o + (size_t)E * DD;
  float* x21  = x11 + (size_t)N * DD;
  float* x12  = x21 + (size_t)N * DD;
  float* x22  = x12 + (size_t)N * DD;

  // ---- workspace carve ----
  size_t off = 0;
  char* w0 = (char*)d_ws;
  auto carve = [&](size_t bytes) -> void* {
    void* p = (void*)(w0 + off);
    off += (bytes + 255) & ~(size_t)255;
    return p;
  };
  int* cn      = (int*)carve((size_t)N * 4);
  int* ce      = (int*)carve((size_t)E * 4);
  int* offs_n  = (int*)carve((size_t)(N + 1) * 4);
  int* offs_e  = (int*)carve((size_t)(E + 1) * 4);
  int* listN   = (int*)carve((size_t)NNZ * 4);
  int* listE   = (int*)carve((size_t)NNZ * 4);
  float* Dn_inv = (float*)carve((size_t)N * 4);
  float* De_inv = (float*)carve((size_t)E * 4);
  char* Wprep  = (char*)carve((size_t)16 * 65536);
  float* t0    = (float*)carve((size_t)N * 256 * 4);
  float* t1    = (float*)carve((size_t)N * 256 * 4);
  float* agg   = (float*)carve((size_t)N * 256 * 4);
  float* e_full = (float*)carve((size_t)E * 256 * 4);
  int* cur_n   = (int*)carve((size_t)N * 4);
  int* cur_e   = (int*)carve((size_t)E * 4);
  // staged-CSR extras
  int* cur_be  = (int*)carve((size_t)NBE * 8 * 4);
  int* cur_bn  = (int*)carve((size_t)NBN * 8 * 4);
  u32* SE      = (u32*)carve((size_t)NNZ * 8 * 4);
  u32* SN      = (u32*)carve((size_t)NNZ * 8 * 4);
  const bool staged = off <= ws_size;

  // ---- weight prep table ----
  WPtrs wp;
  wp.p[0] = e1_Wn2e;  wp.p[1] = e1_Wn2e + DD * DD;
  wp.p[2] = e1_We2n;  wp.p[3] = e1_We2n + DD * DD;
  wp.p[4] = e2_Wn2e;  wp.p[5] = e2_Wn2e + DD * DD;
  wp.p[6] = e2_We2n;  wp.p[7] = e2_We2n + DD * DD;
  wp.p[8] = d1_We;    wp.p[9] = d1_We + DD * DD;
  wp.p[10] = d1_Wx;   wp.p[11] = d1_Wx + DD * DD;
  wp.p[12] = d2_We;   wp.p[13] = d2_We + DD * DD;
  wp.p[14] = d2_Wx;   wp.p[15] = d2_Wx + DD * DD;
  auto WP = [&](int i) -> const char* { return Wprep + (size_t)i * 65536; };

  const int thr = 256;
  const int gMax = ((N > E ? N : E) + thr - 1) / thr;
  int gNNZ = (NNZ + thr - 1) / thr; if (gNNZ > 2048) gNNZ = 2048;
  const int NT = (N + 63) / 64;        // 64-row tiles, per-tile grid
  const int gGatE = (E + 3) / 4;
  const int gGatN = (N + 3) / 4;

  prep_w_k<<<128, 256, 0, stream>>>(wp, Wprep);
  init_counts_k<<<gMax, thr, 0, stream>>>(cn, ce, N, E);
  hist_k<<<gNNZ, thr, 0, stream>>>(node_idx, edge_idx, cn, ce, NNZ);
  exscan2_k<<<2, 1024, 0, stream>>>(cn, offs_n, N, ce, offs_e, E);
  fill_deg_k<<<gMax, thr, 0, stream>>>(offs_n, offs_e, Dn_inv, De_inv,
                                       cur_be, cur_bn, cur_n, cur_e, N, E, NBE, NBN);

  if (staged) {
    partition2_k<<<gNNZ, thr, 0, stream>>>(node_idx, edge_idx, cur_be, cur_bn, SE, SN, NNZ);
    scatter2_k<<<NBE, 256, 0, stream>>>(SE, offs_e, cur_be, listE, E);
    scatter2_k<<<NBN, 256, 0, stream>>>(SN, offs_n, cur_bn, listN, N);
  } else {
    fill_nnz_k<<<gNNZ, thr, 0, stream>>>(node_idx, edge_idx, cur_n, cur_e, listN, listE, NNZ);
  }

  // ---- fused dual-encoder (width-256: half1 = enc1, half2 = enc2) ----
  // L1 in: t0 = [x@W0 | xx@W4]
  gemm_halves_k<0><<<NT, 256, 0, stream>>>(x, DD, 0, WP(0), nullptr,
                                           xx, DD, 0, WP(4), nullptr, alphap, t0, N);
  // e(L1) real edges
  gather_edge_k<0><<<gGatE, 256, 0, stream>>>(t0, offs_e, listE, De_inv, e1_bn2e, e2_bn2e,
                                              alphap, e_full, nullptr, nullptr, E);
  // t1 = Dn_inv*(prelu(t0+bn2e_0) + seg_n(e))
  gather_node_k<<<gGatN, 256, 0, stream>>>(e_full, t0, offs_n, listN, Dn_inv, e1_bn2e, e2_bn2e,
                                           alphap, t1, N);
  // hidden: t0 = prelu(t1@We2n_0 + be2n_0)
  gemm_halves_k<1><<<NT, 256, 0, stream>>>(t1, 256, 0, WP(2), e1_be2n,
                                           t1, 256, 128, WP(6), e2_be2n, alphap, t0, N);
  // L2 in: t1 = hidden@Wn2e_1
  gemm_halves_k<0><<<NT, 256, 0, stream>>>(t0, 256, 0, WP(1), nullptr,
                                           t0, 256, 128, WP(5), nullptr, alphap, t1, N);
  // e(L2) (+ e1o/e2o outputs)
  gather_edge_k<1><<<gGatE, 256, 0, stream>>>(t1, offs_e, listE, De_inv, e1_bn2e + DD, e2_bn2e + DD,
                                              alphap, e_full, e1o, e2o, E);
  // agg = Dn_inv*(prelu(t1+bn2e_1) + seg_n(e))
  gather_node_k<<<gGatN, 256, 0, stream>>>(e_full, t1, offs_n, listN, Dn_inv, e1_bn2e + DD, e2_bn2e + DD,
                                           alphap, agg, N);
  // n1, n2, nn1
  enc_final_k<<<NT, 256, 0, stream>>>(agg, WP(3), e1_be2n + DD, WP(7), e2_be2n + DD,
                                      alphap, n1, n2, nn1, N);

  // ---- decoders ----
  float* dt0 = t0;
  float* dt1 = t0 + (size_t)N * DD;
  dec_pair_k<<<NT, 256, 0, stream>>>(n1, n1, agg, 0, WP(10), WP(8), d1_b, WP(14), WP(12), d2_b,
                                     alphap, dt0, dt1, N);
  dec_pair_k<<<NT, 256, 0, stream>>>(dt0, dt1, agg, 0, WP(11), WP(9), d1_b + DD, WP(15), WP(13), d2_b + DD,
                                     alphap, x11, x22, N);
  dec_pair_k<<<NT, 256, 0, stream>>>(n2, n2, agg, 128, WP(10), WP(8), d1_b, WP(14), WP(12), d2_b,
                                     alphap, dt0, dt1, N);
  dec_pair_k<<<NT, 256, 0, stream>>>(dt0, dt1, agg, 128, WP(11), WP(9), d1_b + DD, WP(15), WP(13), d2_b + DD,
                                     alphap, x12, x21, N);
}

// Round 7
// 735.261 us; speedup vs baseline: 1.5401x; 1.3190x over previous
//
#include <hip/hip_runtime.h>

#define DD 128

typedef __attribute__((ext_vector_type(8))) short bh8;       // 8 bf16 (as i16 bits)
typedef __attribute__((ext_vector_type(8))) unsigned short us8;
typedef __attribute__((ext_vector_type(4))) unsigned short us4;
typedef __attribute__((ext_vector_type(4))) float f4;
typedef unsigned int u32;
typedef unsigned short u16;

__device__ __forceinline__ u16 tob(float f) {           // fp32 -> bf16 RNE
  u32 u = __builtin_bit_cast(u32, f);
  u += 0x7FFFu + ((u >> 16) & 1u);
  return (u16)(u >> 16);
}
__device__ __forceinline__ float fb(u16 h) { return __builtin_bit_cast(float, (u32)h << 16); }

// ================= CSR build (real edges only; self-loops analytic) =================

__global__ __launch_bounds__(256) void init_counts_k(int* cn, int* ce, int N, int E) {
  int g = blockIdx.x * blockDim.x + threadIdx.x;
  if (g < E) ce[g] = 0;
  if (g < N) cn[g] = 0;
}

__global__ __launch_bounds__(256) void hist_k(const int* __restrict__ ni, const int* __restrict__ ei,
                                              int* cn, int* ce, int nnz) {
  int stride = gridDim.x * blockDim.x;
  for (int j = blockIdx.x * blockDim.x + threadIdx.x; j < nnz; j += stride) {
    atomicAdd(&cn[ni[j]], 1);
    atomicAdd(&ce[ei[j]], 1);
  }
}

__global__ __launch_bounds__(1024) void exscan2_k(const int* __restrict__ cn, int* offs_n, int N,
                                                  const int* __restrict__ ce, int* offs_e, int E) {
  const int* cnt = blockIdx.x ? ce : cn;
  int* offs = blockIdx.x ? offs_e : offs_n;
  int n = blockIdx.x ? E : N;
  __shared__ int sums[1024];
  __shared__ int carry;
  const int tid = threadIdx.x;
  if (tid == 0) carry = 0;
  __syncthreads();
  const int PER = 8;
  const int CH = 1024 * PER;
  for (int base = 0; base < n; base += CH) {
    int i0 = base + tid * PER;
    int v[PER]; int s = 0;
    #pragma unroll
    for (int j = 0; j < PER; ++j) { int i = i0 + j; int t = (i < n) ? cnt[i] : 0; v[j] = t; s += t; }
    sums[tid] = s;
    __syncthreads();
    for (int off = 1; off < 1024; off <<= 1) {
      int t = (tid >= off) ? sums[tid - off] : 0;
      __syncthreads();
      sums[tid] += t;
      __syncthreads();
    }
    int excl = sums[tid] - s + carry;
    #pragma unroll
    for (int j = 0; j < PER; ++j) { int i = i0 + j; if (i < n) offs[i] = excl; excl += v[j]; }
    __syncthreads();
    if (tid == 0) carry += sums[1023];
    __syncthreads();
  }
  if (tid == 0) offs[n] = carry;
}

__global__ __launch_bounds__(256) void fill_deg_k(const int* __restrict__ offs_n, const int* __restrict__ offs_e,
                                                  float* Dn_inv, float* De_inv,
                                                  int* cur_be, int* cur_bn, int* cur_n, int* cur_e,
                                                  int N, int E, int NBE, int NBN) {
  int g = blockIdx.x * blockDim.x + threadIdx.x;
  if (g < E) {
    int b = offs_e[g], e = offs_e[g + 1];
    De_inv[g] = (e > b) ? 1.0f / (float)(e - b) : 0.0f;
    cur_e[g] = b;
  }
  if (g < N) {
    int b = offs_n[g], e = offs_n[g + 1];
    Dn_inv[g] = 1.0f / (float)(e - b + 1);   // +1 self loop
    cur_n[g] = b;
  }
  if (g < NBE) {
    int r1 = (g + 1) * 32; if (r1 > E) r1 = E;
    int o0 = offs_e[g * 32], o1 = offs_e[r1];
    int C = o1 - o0, base = 8 * o0;
    #pragma unroll
    for (int k = 0; k < 8; ++k) cur_be[g * 8 + k] = base + k * C;
  }
  if (g < NBN) {
    int r1 = (g + 1) * 32; if (r1 > N) r1 = N;
    int o0 = offs_n[g * 32], o1 = offs_n[r1];
    int C = o1 - o0, base = 8 * o0;
    #pragma unroll
    for (int k = 0; k < 8; ++k) cur_bn[g * 8 + k] = base + k * C;
  }
}

__global__ __launch_bounds__(256) void partition2_k(const int* __restrict__ ni, const int* __restrict__ ei,
                                                    int* cur_be, int* cur_bn,
                                                    u32* __restrict__ SE, u32* __restrict__ SN, int nnz) {
  int xcd;
  asm volatile("s_getreg_b32 %0, hwreg(HW_REG_XCC_ID)" : "=s"(xcd));
  xcd &= 7;
  int stride = gridDim.x * blockDim.x;
  for (int j = blockIdx.x * blockDim.x + threadIdx.x; j < nnz; j += stride) {
    int n = ni[j], e = ei[j];
    int pe = atomicAdd(&cur_be[(e >> 5) * 8 + xcd], 1);
    SE[pe] = ((u32)(e & 31) << 17) | (u32)n;
    int pn = atomicAdd(&cur_bn[(n >> 5) * 8 + xcd], 1);
    SN[pn] = ((u32)(n & 31) << 17) | (u32)e;
  }
}

__global__ __launch_bounds__(256) void scatter2_k(const u32* __restrict__ S, const int* __restrict__ offs,
                                                  const int* __restrict__ cur_b,
                                                  int* __restrict__ list, int nRows) {
  __shared__ int cur[32];
  const int b = blockIdx.x;
  const int i0 = b << 5;
  const int tid = threadIdx.x;
  if (tid < 32) {
    int row = i0 + tid;
    cur[tid] = (row < nRows) ? offs[row] : 0;
  }
  __syncthreads();
  int r1 = i0 + 32; if (r1 > nRows) r1 = nRows;
  const int o0 = offs[i0];
  const int C = offs[r1] - o0;
  #pragma unroll 1
  for (int k = 0; k < 8; ++k) {
    int sbeg = 8 * o0 + k * C;
    int send = cur_b[b * 8 + k];
    for (int i = sbeg + tid; i < send; i += 256) {
      u32 v = S[i];
      int pos = atomicAdd(&cur[v >> 17], 1);
      list[pos] = (int)(v & 0x1FFFFu);
    }
  }
}

__global__ __launch_bounds__(256) void fill_nnz_k(const int* __restrict__ ni, const int* __restrict__ ei,
                                                  int* cur_n, int* cur_e, int* listN, int* listE, int nnz) {
  int stride = gridDim.x * blockDim.x;
  for (int j = blockIdx.x * blockDim.x + threadIdx.x; j < nnz; j += stride) {
    int n = ni[j], e = ei[j];
    int pn = atomicAdd(&cur_n[n], 1); listN[pn] = e;
    int pe = atomicAdd(&cur_e[e], 1); listE[pe] = n;
  }
}

// ================= gathers (width 256, bf16 operands, 1 wave/row, 4 bf16/lane) =================

__device__ __forceinline__ void acc4(float4& a, us4 v) {
  a.x += fb(v[0]); a.y += fb(v[1]); a.z += fb(v[2]); a.w += fb(v[3]);
}

// edge rows: e = prelu(De_inv*sum(t[members]) + bias) -> e_fullb (bf16) [+ fp32 split outs]
template<int SPLIT>
__global__ __launch_bounds__(256) void gather_edge_k(const u16* __restrict__ srcb,
                                                     const int* __restrict__ offs, const int* __restrict__ list,
                                                     const float* __restrict__ De_inv,
                                                     const float* __restrict__ b1, const float* __restrict__ b2,
                                                     const float* __restrict__ alphap,
                                                     u16* __restrict__ e_fullb,
                                                     float* __restrict__ d2a, float* __restrict__ d2b, int E) {
  const int wave = threadIdx.x >> 6, lane = threadIdx.x & 63;
  const int row = blockIdx.x * 4 + wave;
  if (row >= E) return;
  const int c = lane * 4;
  const int beg = offs[row], end = offs[row + 1];
  float4 a0 = {0,0,0,0}, a1 = {0,0,0,0}, a2 = {0,0,0,0}, a3 = {0,0,0,0};
  int i = beg;
  for (; i + 3 < end; i += 4) {
    int s0 = list[i], s1 = list[i + 1], s2 = list[i + 2], s3 = list[i + 3];
    us4 v0 = *(const us4*)&srcb[(size_t)s0 * 256 + c];
    us4 v1 = *(const us4*)&srcb[(size_t)s1 * 256 + c];
    us4 v2 = *(const us4*)&srcb[(size_t)s2 * 256 + c];
    us4 v3 = *(const us4*)&srcb[(size_t)s3 * 256 + c];
    acc4(a0, v0); acc4(a1, v1); acc4(a2, v2); acc4(a3, v3);
  }
  for (; i < end; ++i) acc4(a0, *(const us4*)&srcb[(size_t)list[i] * 256 + c]);
  float sc = De_inv[row];
  const float* bp = (c < 128) ? (b1 + c) : (b2 + c - 128);
  float4 bt = *(const float4*)bp;
  float al = *alphap;
  float4 o;
  o.x = sc * ((a0.x + a1.x) + (a2.x + a3.x)) + bt.x;
  o.y = sc * ((a0.y + a1.y) + (a2.y + a3.y)) + bt.y;
  o.z = sc * ((a0.z + a1.z) + (a2.z + a3.z)) + bt.z;
  o.w = sc * ((a0.w + a1.w) + (a2.w + a3.w)) + bt.w;
  o.x = (o.x >= 0.f) ? o.x : al * o.x;
  o.y = (o.y >= 0.f) ? o.y : al * o.y;
  o.z = (o.z >= 0.f) ? o.z : al * o.z;
  o.w = (o.w >= 0.f) ? o.w : al * o.w;
  us4 ob = {tob(o.x), tob(o.y), tob(o.z), tob(o.w)};
  *(us4*)&e_fullb[(size_t)row * 256 + c] = ob;
  if constexpr (SPLIT == 1) {
    if (c < 128) *(float4*)&d2a[(size_t)row * DD + c] = o;
    else         *(float4*)&d2b[(size_t)row * DD + c - 128] = o;
  }
}

// node rows: dst(fp32) = Dn_inv * ( prelu(t[row]+bias) + sum(e_fullb[edges]) )
__global__ __launch_bounds__(256) void gather_node_k(const u16* __restrict__ e_fullb,
                                                     const u16* __restrict__ tb,
                                                     const int* __restrict__ offs, const int* __restrict__ list,
                                                     const float* __restrict__ Dn_inv,
                                                     const float* __restrict__ b1, const float* __restrict__ b2,
                                                     const float* __restrict__ alphap,
                                                     float* __restrict__ dst, int N) {
  const int wave = threadIdx.x >> 6, lane = threadIdx.x & 63;
  const int row = blockIdx.x * 4 + wave;
  if (row >= N) return;
  const int c = lane * 4;
  const int beg = offs[row], end = offs[row + 1];
  float4 a0 = {0,0,0,0}, a1 = {0,0,0,0}, a2 = {0,0,0,0}, a3 = {0,0,0,0};
  int i = beg;
  for (; i + 3 < end; i += 4) {
    int s0 = list[i], s1 = list[i + 1], s2 = list[i + 2], s3 = list[i + 3];
    us4 v0 = *(const us4*)&e_fullb[(size_t)s0 * 256 + c];
    us4 v1 = *(const us4*)&e_fullb[(size_t)s1 * 256 + c];
    us4 v2 = *(const us4*)&e_fullb[(size_t)s2 * 256 + c];
    us4 v3 = *(const us4*)&e_fullb[(size_t)s3 * 256 + c];
    acc4(a0, v0); acc4(a1, v1); acc4(a2, v2); acc4(a3, v3);
  }
  for (; i < end; ++i) acc4(a0, *(const us4*)&e_fullb[(size_t)list[i] * 256 + c]);
  us4 tv4 = *(const us4*)&tb[(size_t)row * 256 + c];
  const float* bp = (c < 128) ? (b1 + c) : (b2 + c - 128);
  float4 bt = *(const float4*)bp;
  float al = *alphap;
  float sx = fb(tv4[0]) + bt.x; sx = (sx >= 0.f) ? sx : al * sx;
  float sy = fb(tv4[1]) + bt.y; sy = (sy >= 0.f) ? sy : al * sy;
  float sz = fb(tv4[2]) + bt.z; sz = (sz >= 0.f) ? sz : al * sz;
  float sw = fb(tv4[3]) + bt.w; sw = (sw >= 0.f) ? sw : al * sw;
  float sc = Dn_inv[row];
  float4 o;
  o.x = sc * (sx + ((a0.x + a1.x) + (a2.x + a3.x)));
  o.y = sc * (sy + ((a0.y + a1.y) + (a2.y + a3.y)));
  o.z = sc * (sz + ((a0.z + a1.z) + (a2.z + a3.z)));
  o.w = sc * (sw + ((a0.w + a1.w) + (a2.w + a3.w)));
  *(float4*)&dst[(size_t)row * 256 + c] = o;
}

// ================= weight prep =================

struct WPtrs { const float* p[16]; };

__global__ __launch_bounds__(256) void prep_w_k(WPtrs wp, char* dst) {
  int m = blockIdx.x >> 3, s = blockIdx.x & 7;
  const float* W = wp.p[m];
  int t = threadIdx.x;
  int n = t & 127;
  int k0 = s * 16 + (t >> 7) * 8;
  us8 vhi, vlo;
  #pragma unroll
  for (int j = 0; j < 8; ++j) {
    float x = W[(size_t)(k0 + j) * DD + n];
    u32 ux = __builtin_bit_cast(u32, x);
    float hf = __builtin_bit_cast(float, ux & 0xFFFF0000u);
    float l = x - hf;
    vhi[j] = (u16)(ux >> 16);
    vlo[j] = (u16)(__builtin_bit_cast(u32, l) >> 16);
  }
  char* base = dst + (size_t)m * 65536;
  int byte = n * 256 + k0 * 2;
  byte ^= (n & 7) << 4;
  *(us8*)(base + byte) = vhi;
  *(us8*)(base + 32768 + byte) = vlo;
}

// ================= MFMA machinery =================

__device__ __forceinline__ void stage_w(const char* gsrc, char* lds, int tid) {
  int wave = tid >> 6, lane = tid & 63;
  #pragma unroll
  for (int i = 0; i < 16; ++i) {
    int off = (wave * 16 + i) * 1024;
    __builtin_amdgcn_global_load_lds(
        (const __attribute__((address_space(1))) u32*)(gsrc + off + lane * 16),
        (__attribute__((address_space(3))) u32*)(lds + off), 16, 0, 0);
  }
}

__device__ __forceinline__ void split8(const float vs[8], bh8& hi, bh8& lo) {
  #pragma unroll
  for (int j = 0; j < 8; ++j) {
    u32 u = __builtin_bit_cast(u32, vs[j]);
    float hf = __builtin_bit_cast(float, u & 0xFFFF0000u);
    float l = vs[j] - hf;
    hi[j] = (short)(u >> 16);
    lo[j] = (short)(__builtin_bit_cast(u32, l) >> 16);
  }
}

__device__ __forceinline__ void mk_afrag(const float* rowp, int koff, bh8& hi, bh8& lo) {
  float4 v0 = *(const float4*)(rowp + koff);
  float4 v1 = *(const float4*)(rowp + koff + 4);
  float vs[8] = {v0.x, v0.y, v0.z, v0.w, v1.x, v1.y, v1.z, v1.w};
  split8(vs, hi, lo);
}

struct AFrag { bh8 hi[4]; bh8 lo[4]; };

__device__ __forceinline__ void load_afragS(const float* __restrict__ A, size_t astride, int acoff,
                                            int rbase, int nrows, int lane, AFrag& f) {
  int r = rbase + (lane & 15);
  if (r >= nrows) r = nrows - 1;
  const float* rowp = A + (size_t)r * astride + acoff;
  const int koff0 = (lane >> 4) * 8;
  #pragma unroll
  for (int ks = 0; ks < 4; ++ks) mk_afrag(rowp, ks * 32 + koff0, f.hi[ks], f.lo[ks]);
}

__device__ __forceinline__ void mfma_ks(const bh8& ahi, const bh8& alo, const char* Wl,
                                        int ks, int lane, f4 acc[8]) {
  const int koff0 = (lane >> 4) * 8;
  const int k2 = (ks * 32 + koff0) * 2;
  #pragma unroll
  for (int cb = 0; cb < 8; ++cb) {
    int n = cb * 16 + (lane & 15);
    int byte = (n * 256 + k2) ^ ((n & 7) << 4);
    bh8 bhiF = *(const bh8*)(Wl + byte);
    bh8 bloF = *(const bh8*)(Wl + 32768 + byte);
    acc[cb] = __builtin_amdgcn_mfma_f32_16x16x32_bf16(ahi, bhiF, acc[cb], 0, 0, 0);
    acc[cb] = __builtin_amdgcn_mfma_f32_16x16x32_bf16(ahi, bloF, acc[cb], 0, 0, 0);
    acc[cb] = __builtin_amdgcn_mfma_f32_16x16x32_bf16(alo, bhiF, acc[cb], 0, 0, 0);
  }
}

__device__ __forceinline__ void mfma_passS(const float* __restrict__ A, size_t astride, int acoff,
                                           const char* Wl, int rbase, int nrows, int lane, f4 acc[8]) {
  int r = rbase + (lane & 15);
  if (r >= nrows) r = nrows - 1;
  const float* rowp = A + (size_t)r * astride + acoff;
  const int koff0 = (lane >> 4) * 8;
  #pragma unroll
  for (int ks = 0; ks < 4; ++ks) {
    bh8 ahi, alo;
    mk_afrag(rowp, ks * 32 + koff0, ahi, alo);
    mfma_ks(ahi, alo, Wl, ks, lane, acc);
  }
}

__device__ __forceinline__ void mfma_pass_frag(const AFrag& f, const char* Wl, int lane, f4 acc[8]) {
  #pragma unroll
  for (int ks = 0; ks < 4; ++ks) mfma_ks(f.hi[ks], f.lo[ks], Wl, ks, lane, acc);
}

// MODE 0: raw; MODE 1: +bias +prelu.  OBF: write bf16 [row*256+...] instead of fp32.
template<int MODE, int OBF>
__device__ __forceinline__ void epilogueS(f4 acc[8], const float* bias, const float* alphap,
                                          void* outp, size_t ostride, int ocoff,
                                          int rbase, int nrows, int lane) {
  float al = 0.f;
  if constexpr (MODE == 1) al = *alphap;
  const int cidx = lane & 15;
  int rq = rbase + (lane >> 4) * 4;
  float b8[8];
  if constexpr (MODE == 1) {
    #pragma unroll
    for (int cb = 0; cb < 8; ++cb) b8[cb] = bias[cb * 16 + cidx];
  }
  #pragma unroll
  for (int q = 0; q < 4; ++q) {
    int row = rq + q;
    if (row < nrows) {
      #pragma unroll
      for (int cb = 0; cb < 8; ++cb) {
        float v = acc[cb][q];
        if constexpr (MODE == 1) { v += b8[cb]; v = (v >= 0.f) ? v : al * v; }
        if constexpr (OBF == 1) {
          u16* op = (u16*)outp + (size_t)row * ostride + ocoff + cidx;
          op[cb * 16] = tob(v);
        } else {
          float* op = (float*)outp + (size_t)row * ostride + ocoff + cidx;
          op[cb * 16] = v;
        }
      }
    }
  }
}

#define ACC_ZERO(acc) { _Pragma("unroll") for (int cb = 0; cb < 8; ++cb) acc[cb] = {0.f, 0.f, 0.f, 0.f}; }

// ================= GEMM kernels (per-tile grids) =================

template<int MODE, int OBF>
__global__ __launch_bounds__(256, 2) void gemm_halves_k(const float* __restrict__ A1, size_t as1, int ac1, const char* W1, const float* b1_,
                                                        const float* __restrict__ A2, size_t as2, int ac2, const char* W2, const float* b2_,
                                                        const float* __restrict__ alphap,
                                                        void* __restrict__ out, int nrows) {
  __shared__ char Wl[65536];
  const int wave = threadIdx.x >> 6, lane = threadIdx.x & 63;
  const int rbase = blockIdx.x * 64 + wave * 16;
  f4 acc[8];
  stage_w(W1, Wl, threadIdx.x);
  __syncthreads();
  ACC_ZERO(acc);
  mfma_passS(A1, as1, ac1, Wl, rbase, nrows, lane, acc);
  epilogueS<MODE, OBF>(acc, b1_, alphap, out, 256, 0, rbase, nrows, lane);
  __syncthreads();
  stage_w(W2, Wl, threadIdx.x);
  __syncthreads();
  ACC_ZERO(acc);
  mfma_passS(A2, as2, ac2, Wl, rbase, nrows, lane, acc);
  epilogueS<MODE, OBF>(acc, b2_, alphap, out, 256, 128, rbase, nrows, lane);
}

__global__ __launch_bounds__(256, 2) void enc_final_k(const float* __restrict__ agg, const char* W1, const float* b1_,
                                                      const char* W2, const float* b2_,
                                                      const float* __restrict__ alphap,
                                                      float* __restrict__ n1, float* __restrict__ n2,
                                                      float* __restrict__ nn1, int nrows) {
  __shared__ char Wl[65536];
  const int wave = threadIdx.x >> 6, lane = threadIdx.x & 63;
  const int rbase = blockIdx.x * 64 + wave * 16;
  const int cidx = lane & 15;
  f4 acc[8];
  float al = *alphap;
  #pragma unroll 1
  for (int h = 0; h < 2; ++h) {
    if (h) __syncthreads();
    stage_w(h ? W2 : W1, Wl, threadIdx.x);
    __syncthreads();
    const float* bp = h ? b2_ : b1_;
    float* nout = h ? n2 : n1;
    float b8[8];
    #pragma unroll
    for (int cb = 0; cb < 8; ++cb) b8[cb] = bp[cb * 16 + cidx];
    ACC_ZERO(acc);
    mfma_passS(agg, 256, h * 128, Wl, rbase, nrows, lane, acc);
    int rq = rbase + (lane >> 4) * 4;
    #pragma unroll
    for (int q = 0; q < 4; ++q) {
      int row = rq + q;
      if (row < nrows) {
        float* op = nout + (size_t)row * DD + cidx;
        float* op2 = nn1 + (size_t)row * 256 + h * 128 + cidx;
        #pragma unroll
        for (int cb = 0; cb < 8; ++cb) {
          float v = acc[cb][q] + b8[cb];
          v = (v >= 0.f) ? v : al * v;
          op[cb * 16] = v;
          op2[cb * 16] = v;
        }
      }
    }
  }
}

// decoder pair layer, 2 streams via blockIdx.y (shared weights)
__global__ __launch_bounds__(256, 2) void dec_pair2_k(const float* __restrict__ xA0, const float* __restrict__ xB0,
                                                      const float* __restrict__ xA1, const float* __restrict__ xB1,
                                                      const float* __restrict__ agg,
                                                      const char* WxA, const char* WeA, const float* bA,
                                                      const char* WxB, const char* WeB, const float* bB,
                                                      const float* __restrict__ alphap,
                                                      float* __restrict__ o1_0, float* __restrict__ o2_0,
                                                      float* __restrict__ o1_1, float* __restrict__ o2_1,
                                                      int nrows) {
  __shared__ char Wl[65536];
  const int y = blockIdx.y;
  const float* xA = y ? xA1 : xA0;
  const float* xB = y ? xB1 : xB0;
  float* o1 = y ? o1_1 : o1_0;
  float* o2 = y ? o2_1 : o2_0;
  const int acoff = y * 128;
  const int wave = threadIdx.x >> 6, lane = threadIdx.x & 63;
  const int rbase = blockIdx.x * 64 + wave * 16;
  AFrag fa;
  load_afragS(agg, 256, acoff, rbase, nrows, lane, fa);
  f4 acc[8];
  stage_w(WxA, Wl, threadIdx.x);
  __syncthreads();
  ACC_ZERO(acc);
  mfma_passS(xA, DD, 0, Wl, rbase, nrows, lane, acc);
  __syncthreads();
  stage_w(WeA, Wl, threadIdx.x);
  __syncthreads();
  mfma_pass_frag(fa, Wl, lane, acc);
  epilogueS<1, 0>(acc, bA, alphap, o1, DD, 0, rbase, nrows, lane);
  __syncthreads();
  stage_w(WxB, Wl, threadIdx.x);
  __syncthreads();
  ACC_ZERO(acc);
  mfma_passS(xB, DD, 0, Wl, rbase, nrows, lane, acc);
  __syncthreads();
  stage_w(WeB, Wl, threadIdx.x);
  __syncthreads();
  mfma_pass_frag(fa, Wl, lane, acc);
  epilogueS<1, 0>(acc, bB, alphap, o2, DD, 0, rbase, nrows, lane);
}

// ================= host =================

extern "C" void kernel_launch(void* const* d_in, const int* in_sizes, int n_in,
                              void* d_out, int out_size, void* d_ws, size_t ws_size,
                              hipStream_t stream) {
  const float* x        = (const float*)d_in[0];
  const float* xx       = (const float*)d_in[1];
  const int*   node_idx = (const int*)d_in[2];
  const int*   edge_idx = (const int*)d_in[3];
  const float* alphap   = (const float*)d_in[6];
  const float* e1_Wn2e  = (const float*)d_in[7];
  const float* e1_bn2e  = (const float*)d_in[8];
  const float* e1_We2n  = (const float*)d_in[9];
  const float* e1_be2n  = (const float*)d_in[10];
  const float* e2_Wn2e  = (const float*)d_in[11];
  const float* e2_bn2e  = (const float*)d_in[12];
  const float* e2_We2n  = (const float*)d_in[13];
  const float* e2_be2n  = (const float*)d_in[14];
  const float* d1_We    = (const float*)d_in[15];
  const float* d1_Wx    = (const float*)d_in[16];
  const float* d1_b     = (const float*)d_in[17];
  const float* d2_We    = (const float*)d_in[18];
  const float* d2_Wx    = (const float*)d_in[19];
  const float* d2_b     = (const float*)d_in[20];

  const int N   = in_sizes[0] / DD;
  const int NNZ = in_sizes[2];
  const int E   = (out_size - 1024 * N) / 256;
  const int NBE = (E + 31) >> 5;
  const int NBN = (N + 31) >> 5;

  // ---- d_out slot map ----
  float* out  = (float*)d_out;
  float* nn1  = out;
  float* n1   = out + (size_t)N * 256;
  float* e1o  = n1 + (size_t)N * DD;
  float* n2   = e1o + (size_t)E * DD;
  float* e2o  = n2 + (size_t)N * DD;
  float* x11  = e2o + (size_t)E * DD;
  float* x21  = x11 + (size_t)N * DD;
  float* x12  = x21 + (size_t)N * DD;
  float* x22  = x12 + (size_t)N * DD;

  // ---- workspace carve ----
  size_t off = 0;
  char* w0 = (char*)d_ws;
  auto carve = [&](size_t bytes) -> void* {
    void* p = (void*)(w0 + off);
    off += (bytes + 255) & ~(size_t)255;
    return p;
  };
  int* cn      = (int*)carve((size_t)N * 4);
  int* ce      = (int*)carve((size_t)E * 4);
  int* offs_n  = (int*)carve((size_t)(N + 1) * 4);
  int* offs_e  = (int*)carve((size_t)(E + 1) * 4);
  int* listN   = (int*)carve((size_t)NNZ * 4);
  int* listE   = (int*)carve((size_t)NNZ * 4);
  float* Dn_inv = (float*)carve((size_t)N * 4);
  float* De_inv = (float*)carve((size_t)E * 4);
  char* Wprep  = (char*)carve((size_t)16 * 65536);
  u16* tb      = (u16*)carve((size_t)N * 256 * 2);    // bf16 gather operand (t0 / t1 reused)
  u16* e_fullb = (u16*)carve((size_t)E * 256 * 2);    // bf16 edge features
  float* th    = (float*)carve((size_t)N * 256 * 4);  // fp32: node-agg L1 out, then hidden; later dec temps A
  float* t1    = (float*)carve((size_t)N * 256 * 4);  // fp32: spare; later dec temps B
  float* agg   = (float*)carve((size_t)N * 256 * 4);  // fp32: shared aggregate
  int* cur_n   = (int*)carve((size_t)N * 4);
  int* cur_e   = (int*)carve((size_t)E * 4);
  int* cur_be  = (int*)carve((size_t)NBE * 8 * 4);
  int* cur_bn  = (int*)carve((size_t)NBN * 8 * 4);
  u32* SE      = (u32*)carve((size_t)NNZ * 8 * 4);
  u32* SN      = (u32*)carve((size_t)NNZ * 8 * 4);
  const bool staged = off <= ws_size;

  // ---- weight prep table ----
  WPtrs wp;
  wp.p[0] = e1_Wn2e;  wp.p[1] = e1_Wn2e + DD * DD;
  wp.p[2] = e1_We2n;  wp.p[3] = e1_We2n + DD * DD;
  wp.p[4] = e2_Wn2e;  wp.p[5] = e2_Wn2e + DD * DD;
  wp.p[6] = e2_We2n;  wp.p[7] = e2_We2n + DD * DD;
  wp.p[8] = d1_We;    wp.p[9] = d1_We + DD * DD;
  wp.p[10] = d1_Wx;   wp.p[11] = d1_Wx + DD * DD;
  wp.p[12] = d2_We;   wp.p[13] = d2_We + DD * DD;
  wp.p[14] = d2_Wx;   wp.p[15] = d2_Wx + DD * DD;
  auto WP = [&](int i) -> const char* { return Wprep + (size_t)i * 65536; };

  const int thr = 256;
  const int gMax = ((N > E ? N : E) + thr - 1) / thr;
  int gNNZ = (NNZ + thr - 1) / thr; if (gNNZ > 2048) gNNZ = 2048;
  const int NT = (N + 63) / 64;
  const int gGatE = (E + 3) / 4;
  const int gGatN = (N + 3) / 4;

  prep_w_k<<<128, 256, 0, stream>>>(wp, Wprep);
  init_counts_k<<<gMax, thr, 0, stream>>>(cn, ce, N, E);
  hist_k<<<gNNZ, thr, 0, stream>>>(node_idx, edge_idx, cn, ce, NNZ);
  exscan2_k<<<2, 1024, 0, stream>>>(cn, offs_n, N, ce, offs_e, E);
  fill_deg_k<<<gMax, thr, 0, stream>>>(offs_n, offs_e, Dn_inv, De_inv,
                                       cur_be, cur_bn, cur_n, cur_e, N, E, NBE, NBN);

  if (staged) {
    partition2_k<<<gNNZ, thr, 0, stream>>>(node_idx, edge_idx, cur_be, cur_bn, SE, SN, NNZ);
    scatter2_k<<<NBE, 256, 0, stream>>>(SE, offs_e, cur_be, listE, E);
    scatter2_k<<<NBN, 256, 0, stream>>>(SN, offs_n, cur_bn, listN, N);
  } else {
    fill_nnz_k<<<gNNZ, thr, 0, stream>>>(node_idx, edge_idx, cur_n, cur_e, listN, listE, NNZ);
  }

  // ---- fused dual-encoder (width-256; gather operands bf16, GEMM chain fp32) ----
  // L1 in: tb = bf16([x@W0 | xx@W4])
  gemm_halves_k<0, 1><<<NT, 256, 0, stream>>>(x, DD, 0, WP(0), nullptr,
                                              xx, DD, 0, WP(4), nullptr, alphap, tb, N);
  // e(L1) -> e_fullb
  gather_edge_k<0><<<gGatE, 256, 0, stream>>>(tb, offs_e, listE, De_inv, e1_bn2e, e2_bn2e,
                                              alphap, e_fullb, nullptr, nullptr, E);
  // th = Dn_inv*(prelu(tb+bn2e_0) + seg_n(e))   [fp32]
  gather_node_k<<<gGatN, 256, 0, stream>>>(e_fullb, tb, offs_n, listN, Dn_inv, e1_bn2e, e2_bn2e,
                                           alphap, th, N);
  // hidden: t1 = prelu(th@We2n_0 + be2n_0)   [fp32]
  gemm_halves_k<1, 0><<<NT, 256, 0, stream>>>(th, 256, 0, WP(2), e1_be2n,
                                              th, 256, 128, WP(6), e2_be2n, alphap, t1, N);
  // L2 in: tb = bf16(hidden@Wn2e_1)
  gemm_halves_k<0, 1><<<NT, 256, 0, stream>>>(t1, 256, 0, WP(1), nullptr,
                                              t1, 256, 128, WP(5), nullptr, alphap, tb, N);
  // e(L2) -> e_fullb (+ fp32 e1o/e2o)
  gather_edge_k<1><<<gGatE, 256, 0, stream>>>(tb, offs_e, listE, De_inv, e1_bn2e + DD, e2_bn2e + DD,
                                              alphap, e_fullb, e1o, e2o, E);
  // agg = Dn_inv*(prelu(tb+bn2e_1) + seg_n(e))   [fp32]
  gather_node_k<<<gGatN, 256, 0, stream>>>(e_fullb, tb, offs_n, listN, Dn_inv, e1_bn2e + DD, e2_bn2e + DD,
                                           alphap, agg, N);
  // n1, n2, nn1
  enc_final_k<<<NT, 256, 0, stream>>>(agg, WP(3), e1_be2n + DD, WP(7), e2_be2n + DD,
                                      alphap, n1, n2, nn1, N);

  // ---- decoders (merged streams; th/t1 reused as dense [N][128] temps) ----
  float* dt0a = th;
  float* dt1a = th + (size_t)N * DD;
  float* dt0b = t1;
  float* dt1b = t1 + (size_t)N * DD;
  dim3 gDec(NT, 2);
  dec_pair2_k<<<gDec, 256, 0, stream>>>(n1, n1, n2, n2, agg,
                                        WP(10), WP(8), d1_b, WP(14), WP(12), d2_b, alphap,
                                        dt0a, dt1a, dt0b, dt1b, N);
  dec_pair2_k<<<gDec, 256, 0, stream>>>(dt0a, dt1a, dt0b, dt1b, agg,
                                        WP(11), WP(9), d1_b + DD, WP(15), WP(13), d2_b + DD, alphap,
                                        x11, x22, x12, x21, N);
}

// Round 8
// 697.318 us; speedup vs baseline: 1.6239x; 1.0544x over previous
//
#include <hip/hip_runtime.h>

#define DD 128

typedef __attribute__((ext_vector_type(8))) short bh8;       // 8 bf16 (as i16 bits)
typedef __attribute__((ext_vector_type(8))) unsigned short us8;
typedef __attribute__((ext_vector_type(4))) unsigned short us4;
typedef __attribute__((ext_vector_type(4))) float f4;
typedef unsigned int u32;
typedef unsigned short u16;

__device__ __forceinline__ u16 tob(float f) {           // fp32 -> bf16 RNE
  u32 u = __builtin_bit_cast(u32, f);
  u += 0x7FFFu + ((u >> 16) & 1u);
  return (u16)(u >> 16);
}
__device__ __forceinline__ float fb(u16 h) { return __builtin_bit_cast(float, (u32)h << 16); }

// ================= CSR build (real edges only; self-loops analytic) =================

__global__ __launch_bounds__(256) void init_counts_k(int* cn, int* ce, int N, int E) {
  int g = blockIdx.x * blockDim.x + threadIdx.x;
  if (g < E) ce[g] = 0;
  if (g < N) cn[g] = 0;
}

__global__ __launch_bounds__(256) void hist_k(const int* __restrict__ ni, const int* __restrict__ ei,
                                              int* cn, int* ce, int nnz) {
  int stride = gridDim.x * blockDim.x;
  for (int j = blockIdx.x * blockDim.x + threadIdx.x; j < nnz; j += stride) {
    atomicAdd(&cn[ni[j]], 1);
    atomicAdd(&ce[ei[j]], 1);
  }
}

__global__ __launch_bounds__(1024) void exscan2_k(const int* __restrict__ cn, int* offs_n, int N,
                                                  const int* __restrict__ ce, int* offs_e, int E) {
  const int* cnt = blockIdx.x ? ce : cn;
  int* offs = blockIdx.x ? offs_e : offs_n;
  int n = blockIdx.x ? E : N;
  __shared__ int sums[1024];
  __shared__ int carry;
  const int tid = threadIdx.x;
  if (tid == 0) carry = 0;
  __syncthreads();
  const int PER = 8;
  const int CH = 1024 * PER;
  for (int base = 0; base < n; base += CH) {
    int i0 = base + tid * PER;
    int v[PER]; int s = 0;
    #pragma unroll
    for (int j = 0; j < PER; ++j) { int i = i0 + j; int t = (i < n) ? cnt[i] : 0; v[j] = t; s += t; }
    sums[tid] = s;
    __syncthreads();
    for (int off = 1; off < 1024; off <<= 1) {
      int t = (tid >= off) ? sums[tid - off] : 0;
      __syncthreads();
      sums[tid] += t;
      __syncthreads();
    }
    int excl = sums[tid] - s + carry;
    #pragma unroll
    for (int j = 0; j < PER; ++j) { int i = i0 + j; if (i < n) offs[i] = excl; excl += v[j]; }
    __syncthreads();
    if (tid == 0) carry += sums[1023];
    __syncthreads();
  }
  if (tid == 0) offs[n] = carry;
}

__global__ __launch_bounds__(256) void fill_deg_k(const int* __restrict__ offs_n, const int* __restrict__ offs_e,
                                                  float* Dn_inv, float* De_inv,
                                                  int* cur_be, int* cur_bn, int* cur_n, int* cur_e,
                                                  int N, int E, int NBE, int NBN) {
  int g = blockIdx.x * blockDim.x + threadIdx.x;
  if (g < E) {
    int b = offs_e[g], e = offs_e[g + 1];
    De_inv[g] = (e > b) ? 1.0f / (float)(e - b) : 0.0f;
    cur_e[g] = b;
  }
  if (g < N) {
    int b = offs_n[g], e = offs_n[g + 1];
    Dn_inv[g] = 1.0f / (float)(e - b + 1);   // +1 self loop
    cur_n[g] = b;
  }
  if (g < NBE) {
    int r1 = (g + 1) * 32; if (r1 > E) r1 = E;
    int o0 = offs_e[g * 32], o1 = offs_e[r1];
    int C = o1 - o0, base = 8 * o0;
    #pragma unroll
    for (int k = 0; k < 8; ++k) cur_be[g * 8 + k] = base + k * C;
  }
  if (g < NBN) {
    int r1 = (g + 1) * 32; if (r1 > N) r1 = N;
    int o0 = offs_n[g * 32], o1 = offs_n[r1];
    int C = o1 - o0, base = 8 * o0;
    #pragma unroll
    for (int k = 0; k < 8; ++k) cur_bn[g * 8 + k] = base + k * C;
  }
}

__global__ __launch_bounds__(256) void partition2_k(const int* __restrict__ ni, const int* __restrict__ ei,
                                                    int* cur_be, int* cur_bn,
                                                    u32* __restrict__ SE, u32* __restrict__ SN, int nnz) {
  int xcd;
  asm volatile("s_getreg_b32 %0, hwreg(HW_REG_XCC_ID)" : "=s"(xcd));
  xcd &= 7;
  int stride = gridDim.x * blockDim.x;
  for (int j = blockIdx.x * blockDim.x + threadIdx.x; j < nnz; j += stride) {
    int n = ni[j], e = ei[j];
    int pe = atomicAdd(&cur_be[(e >> 5) * 8 + xcd], 1);
    SE[pe] = ((u32)(e & 31) << 17) | (u32)n;
    int pn = atomicAdd(&cur_bn[(n >> 5) * 8 + xcd], 1);
    SN[pn] = ((u32)(n & 31) << 17) | (u32)e;
  }
}

__global__ __launch_bounds__(256) void scatter2_k(const u32* __restrict__ S, const int* __restrict__ offs,
                                                  const int* __restrict__ cur_b,
                                                  int* __restrict__ list, int nRows) {
  __shared__ int cur[32];
  const int b = blockIdx.x;
  const int i0 = b << 5;
  const int tid = threadIdx.x;
  if (tid < 32) {
    int row = i0 + tid;
    cur[tid] = (row < nRows) ? offs[row] : 0;
  }
  __syncthreads();
  int r1 = i0 + 32; if (r1 > nRows) r1 = nRows;
  const int o0 = offs[i0];
  const int C = offs[r1] - o0;
  #pragma unroll 1
  for (int k = 0; k < 8; ++k) {
    int sbeg = 8 * o0 + k * C;
    int send = cur_b[b * 8 + k];
    for (int i = sbeg + tid; i < send; i += 256) {
      u32 v = S[i];
      int pos = atomicAdd(&cur[v >> 17], 1);
      list[pos] = (int)(v & 0x1FFFFu);
    }
  }
}

__global__ __launch_bounds__(256) void fill_nnz_k(const int* __restrict__ ni, const int* __restrict__ ei,
                                                  int* cur_n, int* cur_e, int* listN, int* listE, int nnz) {
  int stride = gridDim.x * blockDim.x;
  for (int j = blockIdx.x * blockDim.x + threadIdx.x; j < nnz; j += stride) {
    int n = ni[j], e = ei[j];
    int pn = atomicAdd(&cur_n[n], 1); listN[pn] = e;
    int pe = atomicAdd(&cur_e[e], 1); listE[pe] = n;
  }
}

// ================= gathers (width 256, bf16 operands, 1 wave/row, 4 bf16/lane) =================

__device__ __forceinline__ void acc4(float4& a, us4 v) {
  a.x += fb(v[0]); a.y += fb(v[1]); a.z += fb(v[2]); a.w += fb(v[3]);
}

// edge rows: e = prelu(De_inv*sum(t[members]) + bias) -> e_fullb (bf16) [+ fp32 split outs]
template<int SPLIT>
__global__ __launch_bounds__(256) void gather_edge_k(const u16* __restrict__ srcb,
                                                     const int* __restrict__ offs, const int* __restrict__ list,
                                                     const float* __restrict__ De_inv,
                                                     const float* __restrict__ b1, const float* __restrict__ b2,
                                                     const float* __restrict__ alphap,
                                                     u16* __restrict__ e_fullb,
                                                     float* __restrict__ d2a, float* __restrict__ d2b, int E) {
  const int wave = threadIdx.x >> 6, lane = threadIdx.x & 63;
  const int row = blockIdx.x * 4 + wave;
  if (row >= E) return;
  const int c = lane * 4;
  const int beg = offs[row], end = offs[row + 1];
  float4 a0 = {0,0,0,0}, a1 = {0,0,0,0}, a2 = {0,0,0,0}, a3 = {0,0,0,0};
  int i = beg;
  for (; i + 3 < end; i += 4) {
    int s0 = list[i], s1 = list[i + 1], s2 = list[i + 2], s3 = list[i + 3];
    us4 v0 = *(const us4*)&srcb[(size_t)s0 * 256 + c];
    us4 v1 = *(const us4*)&srcb[(size_t)s1 * 256 + c];
    us4 v2 = *(const us4*)&srcb[(size_t)s2 * 256 + c];
    us4 v3 = *(const us4*)&srcb[(size_t)s3 * 256 + c];
    acc4(a0, v0); acc4(a1, v1); acc4(a2, v2); acc4(a3, v3);
  }
  for (; i < end; ++i) acc4(a0, *(const us4*)&srcb[(size_t)list[i] * 256 + c]);
  float sc = De_inv[row];
  const float* bp = (c < 128) ? (b1 + c) : (b2 + c - 128);
  float4 bt = *(const float4*)bp;
  float al = *alphap;
  float4 o;
  o.x = sc * ((a0.x + a1.x) + (a2.x + a3.x)) + bt.x;
  o.y = sc * ((a0.y + a1.y) + (a2.y + a3.y)) + bt.y;
  o.z = sc * ((a0.z + a1.z) + (a2.z + a3.z)) + bt.z;
  o.w = sc * ((a0.w + a1.w) + (a2.w + a3.w)) + bt.w;
  o.x = (o.x >= 0.f) ? o.x : al * o.x;
  o.y = (o.y >= 0.f) ? o.y : al * o.y;
  o.z = (o.z >= 0.f) ? o.z : al * o.z;
  o.w = (o.w >= 0.f) ? o.w : al * o.w;
  us4 ob = {tob(o.x), tob(o.y), tob(o.z), tob(o.w)};
  *(us4*)&e_fullb[(size_t)row * 256 + c] = ob;
  if constexpr (SPLIT == 1) {
    if (c < 128) *(float4*)&d2a[(size_t)row * DD + c] = o;
    else         *(float4*)&d2b[(size_t)row * DD + c - 128] = o;
  }
}

// node rows: dst(bf16) = Dn_inv * ( prelu(t[row]+bias) + sum(e_fullb[edges]) )
__global__ __launch_bounds__(256) void gather_node_k(const u16* __restrict__ e_fullb,
                                                     const u16* __restrict__ tb,
                                                     const int* __restrict__ offs, const int* __restrict__ list,
                                                     const float* __restrict__ Dn_inv,
                                                     const float* __restrict__ b1, const float* __restrict__ b2,
                                                     const float* __restrict__ alphap,
                                                     u16* __restrict__ dstb, int N) {
  const int wave = threadIdx.x >> 6, lane = threadIdx.x & 63;
  const int row = blockIdx.x * 4 + wave;
  if (row >= N) return;
  const int c = lane * 4;
  const int beg = offs[row], end = offs[row + 1];
  float4 a0 = {0,0,0,0}, a1 = {0,0,0,0}, a2 = {0,0,0,0}, a3 = {0,0,0,0};
  int i = beg;
  for (; i + 3 < end; i += 4) {
    int s0 = list[i], s1 = list[i + 1], s2 = list[i + 2], s3 = list[i + 3];
    us4 v0 = *(const us4*)&e_fullb[(size_t)s0 * 256 + c];
    us4 v1 = *(const us4*)&e_fullb[(size_t)s1 * 256 + c];
    us4 v2 = *(const us4*)&e_fullb[(size_t)s2 * 256 + c];
    us4 v3 = *(const us4*)&e_fullb[(size_t)s3 * 256 + c];
    acc4(a0, v0); acc4(a1, v1); acc4(a2, v2); acc4(a3, v3);
  }
  for (; i < end; ++i) acc4(a0, *(const us4*)&e_fullb[(size_t)list[i] * 256 + c]);
  us4 tv4 = *(const us4*)&tb[(size_t)row * 256 + c];
  const float* bp = (c < 128) ? (b1 + c) : (b2 + c - 128);
  float4 bt = *(const float4*)bp;
  float al = *alphap;
  float sx = fb(tv4[0]) + bt.x; sx = (sx >= 0.f) ? sx : al * sx;
  float sy = fb(tv4[1]) + bt.y; sy = (sy >= 0.f) ? sy : al * sy;
  float sz = fb(tv4[2]) + bt.z; sz = (sz >= 0.f) ? sz : al * sz;
  float sw = fb(tv4[3]) + bt.w; sw = (sw >= 0.f) ? sw : al * sw;
  float sc = Dn_inv[row];
  us4 ob;
  ob[0] = tob(sc * (sx + ((a0.x + a1.x) + (a2.x + a3.x))));
  ob[1] = tob(sc * (sy + ((a0.y + a1.y) + (a2.y + a3.y))));
  ob[2] = tob(sc * (sz + ((a0.z + a1.z) + (a2.z + a3.z))));
  ob[3] = tob(sc * (sw + ((a0.w + a1.w) + (a2.w + a3.w))));
  *(us4*)&dstb[(size_t)row * 256 + c] = ob;
}

// ================= weight prep =================

struct WPtrs { const float* p[16]; };

__global__ __launch_bounds__(256) void prep_w_k(WPtrs wp, char* dst) {
  int m = blockIdx.x >> 3, s = blockIdx.x & 7;
  const float* W = wp.p[m];
  int t = threadIdx.x;
  int n = t & 127;
  int k0 = s * 16 + (t >> 7) * 8;
  us8 vhi, vlo;
  #pragma unroll
  for (int j = 0; j < 8; ++j) {
    float x = W[(size_t)(k0 + j) * DD + n];
    u32 ux = __builtin_bit_cast(u32, x);
    float hf = __builtin_bit_cast(float, ux & 0xFFFF0000u);
    float l = x - hf;
    vhi[j] = (u16)(ux >> 16);
    vlo[j] = (u16)(__builtin_bit_cast(u32, l) >> 16);
  }
  char* base = dst + (size_t)m * 65536;
  int byte = n * 256 + k0 * 2;
  byte ^= (n & 7) << 4;
  *(us8*)(base + byte) = vhi;
  *(us8*)(base + 32768 + byte) = vlo;
}

// ================= MFMA machinery =================

__device__ __forceinline__ void stage_w(const char* gsrc, char* lds, int tid) {
  int wave = tid >> 6, lane = tid & 63;
  #pragma unroll
  for (int i = 0; i < 16; ++i) {
    int off = (wave * 16 + i) * 1024;
    __builtin_amdgcn_global_load_lds(
        (const __attribute__((address_space(1))) u32*)(gsrc + off + lane * 16),
        (__attribute__((address_space(3))) u32*)(lds + off), 16, 0, 0);
  }
}

__device__ __forceinline__ void split8(const float vs[8], bh8& hi, bh8& lo) {
  #pragma unroll
  for (int j = 0; j < 8; ++j) {
    u32 u = __builtin_bit_cast(u32, vs[j]);
    float hf = __builtin_bit_cast(float, u & 0xFFFF0000u);
    float l = vs[j] - hf;
    hi[j] = (short)(u >> 16);
    lo[j] = (short)(__builtin_bit_cast(u32, l) >> 16);
  }
}

__device__ __forceinline__ void mk_afrag(const float* rowp, int koff, bh8& hi, bh8& lo) {
  float4 v0 = *(const float4*)(rowp + koff);
  float4 v1 = *(const float4*)(rowp + koff + 4);
  float vs[8] = {v0.x, v0.y, v0.z, v0.w, v1.x, v1.y, v1.z, v1.w};
  split8(vs, hi, lo);
}

// fp32-A split-3 path
__device__ __forceinline__ void mfma_ks(const bh8& ahi, const bh8& alo, const char* Wl,
                                        int ks, int lane, f4 acc[8]) {
  const int koff0 = (lane >> 4) * 8;
  const int k2 = (ks * 32 + koff0) * 2;
  #pragma unroll
  for (int cb = 0; cb < 8; ++cb) {
    int n = cb * 16 + (lane & 15);
    int byte = (n * 256 + k2) ^ ((n & 7) << 4);
    bh8 bhiF = *(const bh8*)(Wl + byte);
    bh8 bloF = *(const bh8*)(Wl + 32768 + byte);
    acc[cb] = __builtin_amdgcn_mfma_f32_16x16x32_bf16(ahi, bhiF, acc[cb], 0, 0, 0);
    acc[cb] = __builtin_amdgcn_mfma_f32_16x16x32_bf16(ahi, bloF, acc[cb], 0, 0, 0);
    acc[cb] = __builtin_amdgcn_mfma_f32_16x16x32_bf16(alo, bhiF, acc[cb], 0, 0, 0);
  }
}

// bf16-A exact path (2 MFMA)
__device__ __forceinline__ void mfma_ks_bf(const bh8& a, const char* Wl,
                                           int ks, int lane, f4 acc[8]) {
  const int koff0 = (lane >> 4) * 8;
  const int k2 = (ks * 32 + koff0) * 2;
  #pragma unroll
  for (int cb = 0; cb < 8; ++cb) {
    int n = cb * 16 + (lane & 15);
    int byte = (n * 256 + k2) ^ ((n & 7) << 4);
    bh8 bhiF = *(const bh8*)(Wl + byte);
    bh8 bloF = *(const bh8*)(Wl + 32768 + byte);
    acc[cb] = __builtin_amdgcn_mfma_f32_16x16x32_bf16(a, bhiF, acc[cb], 0, 0, 0);
    acc[cb] = __builtin_amdgcn_mfma_f32_16x16x32_bf16(a, bloF, acc[cb], 0, 0, 0);
  }
}

__device__ __forceinline__ void mfma_passS(const float* __restrict__ A, size_t astride, int acoff,
                                           const char* Wl, int rbase, int nrows, int lane, f4 acc[8]) {
  int r = rbase + (lane & 15);
  if (r >= nrows) r = nrows - 1;
  const float* rowp = A + (size_t)r * astride + acoff;
  const int koff0 = (lane >> 4) * 8;
  #pragma unroll
  for (int ks = 0; ks < 4; ++ks) {
    bh8 ahi, alo;
    mk_afrag(rowp, ks * 32 + koff0, ahi, alo);
    mfma_ks(ahi, alo, Wl, ks, lane, acc);
  }
}

// bf16-A pass (direct us8 loads)
__device__ __forceinline__ void mfma_passB(const u16* __restrict__ A, size_t astride, int acoff,
                                           const char* Wl, int rbase, int nrows, int lane, f4 acc[8]) {
  int r = rbase + (lane & 15);
  if (r >= nrows) r = nrows - 1;
  const u16* rowp = A + (size_t)r * astride + acoff;
  const int koff0 = (lane >> 4) * 8;
  #pragma unroll
  for (int ks = 0; ks < 4; ++ks) {
    bh8 a = __builtin_bit_cast(bh8, *(const us8*)(rowp + ks * 32 + koff0));
    mfma_ks_bf(a, Wl, ks, lane, acc);
  }
}

struct AFrag { bh8 hi[4]; bh8 lo[4]; };
struct AFragB { bh8 a[4]; };

__device__ __forceinline__ void load_afragS(const float* __restrict__ A, size_t astride, int acoff,
                                            int rbase, int nrows, int lane, AFrag& f) {
  int r = rbase + (lane & 15);
  if (r >= nrows) r = nrows - 1;
  const float* rowp = A + (size_t)r * astride + acoff;
  const int koff0 = (lane >> 4) * 8;
  #pragma unroll
  for (int ks = 0; ks < 4; ++ks) mk_afrag(rowp, ks * 32 + koff0, f.hi[ks], f.lo[ks]);
}

__device__ __forceinline__ void load_afragB(const u16* __restrict__ A, size_t astride, int acoff,
                                            int rbase, int nrows, int lane, AFragB& f) {
  int r = rbase + (lane & 15);
  if (r >= nrows) r = nrows - 1;
  const u16* rowp = A + (size_t)r * astride + acoff;
  const int koff0 = (lane >> 4) * 8;
  #pragma unroll
  for (int ks = 0; ks < 4; ++ks)
    f.a[ks] = __builtin_bit_cast(bh8, *(const us8*)(rowp + ks * 32 + koff0));
}

__device__ __forceinline__ void mfma_pass_fragB(const AFragB& f, const char* Wl, int lane, f4 acc[8]) {
  #pragma unroll
  for (int ks = 0; ks < 4; ++ks) mfma_ks_bf(f.a[ks], Wl, ks, lane, acc);
}

// MODE 0: raw; MODE 1: +bias +prelu.  OBF: write bf16 [row*ostride+...] instead of fp32.
template<int MODE, int OBF>
__device__ __forceinline__ void epilogueS(f4 acc[8], const float* bias, const float* alphap,
                                          void* outp, size_t ostride, int ocoff,
                                          int rbase, int nrows, int lane) {
  float al = 0.f;
  if constexpr (MODE == 1) al = *alphap;
  const int cidx = lane & 15;
  int rq = rbase + (lane >> 4) * 4;
  float b8[8];
  if constexpr (MODE == 1) {
    #pragma unroll
    for (int cb = 0; cb < 8; ++cb) b8[cb] = bias[cb * 16 + cidx];
  }
  #pragma unroll
  for (int q = 0; q < 4; ++q) {
    int row = rq + q;
    if (row < nrows) {
      #pragma unroll
      for (int cb = 0; cb < 8; ++cb) {
        float v = acc[cb][q];
        if constexpr (MODE == 1) { v += b8[cb]; v = (v >= 0.f) ? v : al * v; }
        if constexpr (OBF == 1) {
          u16* op = (u16*)outp + (size_t)row * ostride + ocoff + cidx;
          op[cb * 16] = tob(v);
        } else {
          float* op = (float*)outp + (size_t)row * ostride + ocoff + cidx;
          op[cb * 16] = v;
        }
      }
    }
  }
}

#define ACC_ZERO(acc) { _Pragma("unroll") for (int cb = 0; cb < 8; ++cb) acc[cb] = {0.f, 0.f, 0.f, 0.f}; }

// ================= GEMM kernels (per-tile grids) =================

// ABF: A operands are bf16 (2-term MFMA). Otherwise fp32 split-3.
template<int MODE, int OBF, int ABF>
__global__ __launch_bounds__(256, 2) void gemm_halves_k(const void* __restrict__ A1, size_t as1, int ac1, const char* W1, const float* b1_,
                                                        const void* __restrict__ A2, size_t as2, int ac2, const char* W2, const float* b2_,
                                                        const float* __restrict__ alphap,
                                                        void* __restrict__ out, int nrows) {
  __shared__ char Wl[65536];
  const int wave = threadIdx.x >> 6, lane = threadIdx.x & 63;
  const int rbase = blockIdx.x * 64 + wave * 16;
  f4 acc[8];
  stage_w(W1, Wl, threadIdx.x);
  __syncthreads();
  ACC_ZERO(acc);
  if constexpr (ABF) mfma_passB((const u16*)A1, as1, ac1, Wl, rbase, nrows, lane, acc);
  else               mfma_passS((const float*)A1, as1, ac1, Wl, rbase, nrows, lane, acc);
  epilogueS<MODE, OBF>(acc, b1_, alphap, out, 256, 0, rbase, nrows, lane);
  __syncthreads();
  stage_w(W2, Wl, threadIdx.x);
  __syncthreads();
  ACC_ZERO(acc);
  if constexpr (ABF) mfma_passB((const u16*)A2, as2, ac2, Wl, rbase, nrows, lane, acc);
  else               mfma_passS((const float*)A2, as2, ac2, Wl, rbase, nrows, lane, acc);
  epilogueS<MODE, OBF>(acc, b2_, alphap, out, 256, 128, rbase, nrows, lane);
}

// encoder final (A = aggb bf16): n1/n2 fp32 + nn1 halves fp32
__global__ __launch_bounds__(256, 2) void enc_final_k(const u16* __restrict__ aggb, const char* W1, const float* b1_,
                                                      const char* W2, const float* b2_,
                                                      const float* __restrict__ alphap,
                                                      float* __restrict__ n1, float* __restrict__ n2,
                                                      float* __restrict__ nn1, int nrows) {
  __shared__ char Wl[65536];
  const int wave = threadIdx.x >> 6, lane = threadIdx.x & 63;
  const int rbase = blockIdx.x * 64 + wave * 16;
  const int cidx = lane & 15;
  f4 acc[8];
  float al = *alphap;
  #pragma unroll 1
  for (int h = 0; h < 2; ++h) {
    if (h) __syncthreads();
    stage_w(h ? W2 : W1, Wl, threadIdx.x);
    __syncthreads();
    const float* bp = h ? b2_ : b1_;
    float* nout = h ? n2 : n1;
    float b8[8];
    #pragma unroll
    for (int cb = 0; cb < 8; ++cb) b8[cb] = bp[cb * 16 + cidx];
    ACC_ZERO(acc);
    mfma_passB(aggb, 256, h * 128, Wl, rbase, nrows, lane, acc);
    int rq = rbase + (lane >> 4) * 4;
    #pragma unroll
    for (int q = 0; q < 4; ++q) {
      int row = rq + q;
      if (row < nrows) {
        float* op = nout + (size_t)row * DD + cidx;
        float* op2 = nn1 + (size_t)row * 256 + h * 128 + cidx;
        #pragma unroll
        for (int cb = 0; cb < 8; ++cb) {
          float v = acc[cb][q] + b8[cb];
          v = (v >= 0.f) ? v : al * v;
          op[cb * 16] = v;
          op2[cb * 16] = v;
        }
      }
    }
  }
}

// decoder pair layer, 2 streams via blockIdx.y; agg fragment is bf16
__global__ __launch_bounds__(256, 2) void dec_pair2_k(const float* __restrict__ xA0, const float* __restrict__ xB0,
                                                      const float* __restrict__ xA1, const float* __restrict__ xB1,
                                                      const u16* __restrict__ aggb,
                                                      const char* WxA, const char* WeA, const float* bA,
                                                      const char* WxB, const char* WeB, const float* bB,
                                                      const float* __restrict__ alphap,
                                                      float* __restrict__ o1_0, float* __restrict__ o2_0,
                                                      float* __restrict__ o1_1, float* __restrict__ o2_1,
                                                      int nrows) {
  __shared__ char Wl[65536];
  const int y = blockIdx.y;
  const float* xA = y ? xA1 : xA0;
  const float* xB = y ? xB1 : xB0;
  float* o1 = y ? o1_1 : o1_0;
  float* o2 = y ? o2_1 : o2_0;
  const int acoff = y * 128;
  const int wave = threadIdx.x >> 6, lane = threadIdx.x & 63;
  const int rbase = blockIdx.x * 64 + wave * 16;
  AFragB fa;
  load_afragB(aggb, 256, acoff, rbase, nrows, lane, fa);
  f4 acc[8];
  stage_w(WxA, Wl, threadIdx.x);
  __syncthreads();
  ACC_ZERO(acc);
  mfma_passS(xA, DD, 0, Wl, rbase, nrows, lane, acc);
  __syncthreads();
  stage_w(WeA, Wl, threadIdx.x);
  __syncthreads();
  mfma_pass_fragB(fa, Wl, lane, acc);
  epilogueS<1, 0>(acc, bA, alphap, o1, DD, 0, rbase, nrows, lane);
  __syncthreads();
  stage_w(WxB, Wl, threadIdx.x);
  __syncthreads();
  ACC_ZERO(acc);
  mfma_passS(xB, DD, 0, Wl, rbase, nrows, lane, acc);
  __syncthreads();
  stage_w(WeB, Wl, threadIdx.x);
  __syncthreads();
  mfma_pass_fragB(fa, Wl, lane, acc);
  epilogueS<1, 0>(acc, bB, alphap, o2, DD, 0, rbase, nrows, lane);
}

// ================= host =================

extern "C" void kernel_launch(void* const* d_in, const int* in_sizes, int n_in,
                              void* d_out, int out_size, void* d_ws, size_t ws_size,
                              hipStream_t stream) {
  const float* x        = (const float*)d_in[0];
  const float* xx       = (const float*)d_in[1];
  const int*   node_idx = (const int*)d_in[2];
  const int*   edge_idx = (const int*)d_in[3];
  const float* alphap   = (const float*)d_in[6];
  const float* e1_Wn2e  = (const float*)d_in[7];
  const float* e1_bn2e  = (const float*)d_in[8];
  const float* e1_We2n  = (const float*)d_in[9];
  const float* e1_be2n  = (const float*)d_in[10];
  const float* e2_Wn2e  = (const float*)d_in[11];
  const float* e2_bn2e  = (const float*)d_in[12];
  const float* e2_We2n  = (const float*)d_in[13];
  const float* e2_be2n  = (const float*)d_in[14];
  const float* d1_We    = (const float*)d_in[15];
  const float* d1_Wx    = (const float*)d_in[16];
  const float* d1_b     = (const float*)d_in[17];
  const float* d2_We    = (const float*)d_in[18];
  const float* d2_Wx    = (const float*)d_in[19];
  const float* d2_b     = (const float*)d_in[20];

  const int N   = in_sizes[0] / DD;
  const int NNZ = in_sizes[2];
  const int E   = (out_size - 1024 * N) / 256;
  const int NBE = (E + 31) >> 5;
  const int NBN = (N + 31) >> 5;

  // ---- d_out slot map ----
  float* out  = (float*)d_out;
  float* nn1  = out;
  float* n1   = out + (size_t)N * 256;
  float* e1o  = n1 + (size_t)N * DD;
  float* n2   = e1o + (size_t)E * DD;
  float* e2o  = n2 + (size_t)N * DD;
  float* x11  = e2o + (size_t)E * DD;
  float* x21  = x11 + (size_t)N * DD;
  float* x12  = x21 + (size_t)N * DD;
  float* x22  = x12 + (size_t)N * DD;

  // ---- workspace carve ----
  size_t off = 0;
  char* w0 = (char*)d_ws;
  auto carve = [&](size_t bytes) -> void* {
    void* p = (void*)(w0 + off);
    off += (bytes + 255) & ~(size_t)255;
    return p;
  };
  int* cn      = (int*)carve((size_t)N * 4);
  int* ce      = (int*)carve((size_t)E * 4);
  int* offs_n  = (int*)carve((size_t)(N + 1) * 4);
  int* offs_e  = (int*)carve((size_t)(E + 1) * 4);
  int* listN   = (int*)carve((size_t)NNZ * 4);
  int* listE   = (int*)carve((size_t)NNZ * 4);
  float* Dn_inv = (float*)carve((size_t)N * 4);
  float* De_inv = (float*)carve((size_t)E * 4);
  char* Wprep  = (char*)carve((size_t)16 * 65536);
  u16* tb      = (u16*)carve((size_t)N * 256 * 2);    // bf16: GEMM1/GEMM3 out (edge-gather src)
  u16* e_fullb = (u16*)carve((size_t)E * 256 * 2);    // bf16 edge features
  u16* thb     = (u16*)carve((size_t)N * 256 * 2);    // bf16: node-agg L1 (hidden GEMM A)
  u16* aggb    = (u16*)carve((size_t)N * 256 * 2);    // bf16: shared aggregate (enc_final + dec A)
  float* t1    = (float*)carve((size_t)N * 256 * 4);  // fp32: hidden; later dec temps A
  float* td    = (float*)carve((size_t)N * 256 * 4);  // fp32: dec temps B
  int* cur_n   = (int*)carve((size_t)N * 4);
  int* cur_e   = (int*)carve((size_t)E * 4);
  int* cur_be  = (int*)carve((size_t)NBE * 8 * 4);
  int* cur_bn  = (int*)carve((size_t)NBN * 8 * 4);
  u32* SE      = (u32*)carve((size_t)NNZ * 8 * 4);
  u32* SN      = (u32*)carve((size_t)NNZ * 8 * 4);
  const bool staged = off <= ws_size;

  // ---- weight prep table ----
  WPtrs wp;
  wp.p[0] = e1_Wn2e;  wp.p[1] = e1_Wn2e + DD * DD;
  wp.p[2] = e1_We2n;  wp.p[3] = e1_We2n + DD * DD;
  wp.p[4] = e2_Wn2e;  wp.p[5] = e2_Wn2e + DD * DD;
  wp.p[6] = e2_We2n;  wp.p[7] = e2_We2n + DD * DD;
  wp.p[8] = d1_We;    wp.p[9] = d1_We + DD * DD;
  wp.p[10] = d1_Wx;   wp.p[11] = d1_Wx + DD * DD;
  wp.p[12] = d2_We;   wp.p[13] = d2_We + DD * DD;
  wp.p[14] = d2_Wx;   wp.p[15] = d2_Wx + DD * DD;
  auto WP = [&](int i) -> const char* { return Wprep + (size_t)i * 65536; };

  const int thr = 256;
  const int gMax = ((N > E ? N : E) + thr - 1) / thr;
  int gNNZ = (NNZ + thr - 1) / thr; if (gNNZ > 2048) gNNZ = 2048;
  const int NT = (N + 63) / 64;
  const int gGatE = (E + 3) / 4;
  const int gGatN = (N + 3) / 4;

  prep_w_k<<<128, 256, 0, stream>>>(wp, Wprep);
  init_counts_k<<<gMax, thr, 0, stream>>>(cn, ce, N, E);
  hist_k<<<gNNZ, thr, 0, stream>>>(node_idx, edge_idx, cn, ce, NNZ);
  exscan2_k<<<2, 1024, 0, stream>>>(cn, offs_n, N, ce, offs_e, E);
  fill_deg_k<<<gMax, thr, 0, stream>>>(offs_n, offs_e, Dn_inv, De_inv,
                                       cur_be, cur_bn, cur_n, cur_e, N, E, NBE, NBN);

  if (staged) {
    partition2_k<<<gNNZ, thr, 0, stream>>>(node_idx, edge_idx, cur_be, cur_bn, SE, SN, NNZ);
    scatter2_k<<<NBE, 256, 0, stream>>>(SE, offs_e, cur_be, listE, E);
    scatter2_k<<<NBN, 256, 0, stream>>>(SN, offs_n, cur_bn, listN, N);
  } else {
    fill_nnz_k<<<gNNZ, thr, 0, stream>>>(node_idx, edge_idx, cur_n, cur_e, listN, listE, NNZ);
  }

  // ---- fused dual-encoder (width-256; bf16 data plane, fp32 where cheap) ----
  // L1 in: tb = bf16([x@W0 | xx@W4])   (A fp32 split-3)
  gemm_halves_k<0, 1, 0><<<NT, 256, 0, stream>>>(x, DD, 0, WP(0), nullptr,
                                                 xx, DD, 0, WP(4), nullptr, alphap, tb, N);
  // e(L1) -> e_fullb
  gather_edge_k<0><<<gGatE, 256, 0, stream>>>(tb, offs_e, listE, De_inv, e1_bn2e, e2_bn2e,
                                              alphap, e_fullb, nullptr, nullptr, E);
  // thb = bf16(Dn_inv*(prelu(tb+bn2e_0) + seg_n(e)))
  gather_node_k<<<gGatN, 256, 0, stream>>>(e_fullb, tb, offs_n, listN, Dn_inv, e1_bn2e, e2_bn2e,
                                           alphap, thb, N);
  // hidden: t1 = prelu(thb@We2n_0 + be2n_0)   [A bf16 2-term, out fp32]
  gemm_halves_k<1, 0, 1><<<NT, 256, 0, stream>>>(thb, 256, 0, WP(2), e1_be2n,
                                                 thb, 256, 128, WP(6), e2_be2n, alphap, t1, N);
  // L2 in: tb = bf16(hidden@Wn2e_1)   (A fp32 split-3)
  gemm_halves_k<0, 1, 0><<<NT, 256, 0, stream>>>(t1, 256, 0, WP(1), nullptr,
                                                 t1, 256, 128, WP(5), nullptr, alphap, tb, N);
  // e(L2) -> e_fullb (+ fp32 e1o/e2o)
  gather_edge_k<1><<<gGatE, 256, 0, stream>>>(tb, offs_e, listE, De_inv, e1_bn2e + DD, e2_bn2e + DD,
                                              alphap, e_fullb, e1o, e2o, E);
  // aggb = bf16(Dn_inv*(prelu(tb+bn2e_1) + seg_n(e)))
  gather_node_k<<<gGatN, 256, 0, stream>>>(e_fullb, tb, offs_n, listN, Dn_inv, e1_bn2e + DD, e2_bn2e + DD,
                                           alphap, aggb, N);
  // n1, n2, nn1  (A bf16 2-term)
  enc_final_k<<<NT, 256, 0, stream>>>(aggb, WP(3), e1_be2n + DD, WP(7), e2_be2n + DD,
                                      alphap, n1, n2, nn1, N);

  // ---- decoders (merged streams; t1/td reused as dense [N][128] fp32 temps) ----
  float* dt0a = t1;
  float* dt1a = t1 + (size_t)N * DD;
  float* dt0b = td;
  float* dt1b = td + (size_t)N * DD;
  dim3 gDec(NT, 2);
  dec_pair2_k<<<gDec, 256, 0, stream>>>(n1, n1, n2, n2, aggb,
                                        WP(10), WP(8), d1_b, WP(14), WP(12), d2_b, alphap,
                                        dt0a, dt1a, dt0b, dt1b, N);
  dec_pair2_k<<<gDec, 256, 0, stream>>>(dt0a, dt1a, dt0b, dt1b, aggb,
                                        WP(11), WP(9), d1_b + DD, WP(15), WP(13), d2_b + DD, alphap,
                                        x11, x22, x12, x21, N);
}

// Round 9
// 677.688 us; speedup vs baseline: 1.6710x; 1.0290x over previous
//
#include <hip/hip_runtime.h>

#define DD 128

typedef __attribute__((ext_vector_type(8))) short bh8;       // 8 bf16 (as i16 bits)
typedef __attribute__((ext_vector_type(8))) unsigned short us8;
typedef __attribute__((ext_vector_type(4))) unsigned short us4;
typedef __attribute__((ext_vector_type(4))) float f4;
typedef unsigned int u32;
typedef unsigned short u16;

__device__ __forceinline__ u16 tob(float f) {           // fp32 -> bf16 RNE
  u32 u = __builtin_bit_cast(u32, f);
  u += 0x7FFFu + ((u >> 16) & 1u);
  return (u16)(u >> 16);
}
__device__ __forceinline__ float fb(u16 h) { return __builtin_bit_cast(float, (u32)h << 16); }

// ================= CSR build (real edges only; self-loops analytic) =================

__global__ __launch_bounds__(256) void init_counts_k(int* cn, int* ce, int N, int E) {
  int g = blockIdx.x * blockDim.x + threadIdx.x;
  if (g < E) ce[g] = 0;
  if (g < N) cn[g] = 0;
}

__global__ __launch_bounds__(256) void hist_k(const int* __restrict__ ni, const int* __restrict__ ei,
                                              int* cn, int* ce, int nnz) {
  int stride = gridDim.x * blockDim.x;
  for (int j = blockIdx.x * blockDim.x + threadIdx.x; j < nnz; j += stride) {
    atomicAdd(&cn[ni[j]], 1);
    atomicAdd(&ce[ei[j]], 1);
  }
}

__global__ __launch_bounds__(1024) void exscan2_k(const int* __restrict__ cn, int* offs_n, int N,
                                                  const int* __restrict__ ce, int* offs_e, int E) {
  const int* cnt = blockIdx.x ? ce : cn;
  int* offs = blockIdx.x ? offs_e : offs_n;
  int n = blockIdx.x ? E : N;
  __shared__ int sums[1024];
  __shared__ int carry;
  const int tid = threadIdx.x;
  if (tid == 0) carry = 0;
  __syncthreads();
  const int PER = 8;
  const int CH = 1024 * PER;
  for (int base = 0; base < n; base += CH) {
    int i0 = base + tid * PER;
    int v[PER]; int s = 0;
    #pragma unroll
    for (int j = 0; j < PER; ++j) { int i = i0 + j; int t = (i < n) ? cnt[i] : 0; v[j] = t; s += t; }
    sums[tid] = s;
    __syncthreads();
    for (int off = 1; off < 1024; off <<= 1) {
      int t = (tid >= off) ? sums[tid - off] : 0;
      __syncthreads();
      sums[tid] += t;
      __syncthreads();
    }
    int excl = sums[tid] - s + carry;
    #pragma unroll
    for (int j = 0; j < PER; ++j) { int i = i0 + j; if (i < n) offs[i] = excl; excl += v[j]; }
    __syncthreads();
    if (tid == 0) carry += sums[1023];
    __syncthreads();
  }
  if (tid == 0) offs[n] = carry;
}

__global__ __launch_bounds__(256) void fill_deg_k(const int* __restrict__ offs_n, const int* __restrict__ offs_e,
                                                  float* Dn_inv, float* De_inv,
                                                  int* cur_be, int* cur_bn, int* cur_n, int* cur_e,
                                                  int N, int E, int NBE, int NBN) {
  int g = blockIdx.x * blockDim.x + threadIdx.x;
  if (g < E) {
    int b = offs_e[g], e = offs_e[g + 1];
    De_inv[g] = (e > b) ? 1.0f / (float)(e - b) : 0.0f;
    cur_e[g] = b;
  }
  if (g < N) {
    int b = offs_n[g], e = offs_n[g + 1];
    Dn_inv[g] = 1.0f / (float)(e - b + 1);   // +1 self loop
    cur_n[g] = b;
  }
  if (g < NBE) {
    int r1 = (g + 1) * 32; if (r1 > E) r1 = E;
    int o0 = offs_e[g * 32], o1 = offs_e[r1];
    int C = o1 - o0, base = 8 * o0;
    #pragma unroll
    for (int k = 0; k < 8; ++k) cur_be[g * 8 + k] = base + k * C;
  }
  if (g < NBN) {
    int r1 = (g + 1) * 32; if (r1 > N) r1 = N;
    int o0 = offs_n[g * 32], o1 = offs_n[r1];
    int C = o1 - o0, base = 8 * o0;
    #pragma unroll
    for (int k = 0; k < 8; ++k) cur_bn[g * 8 + k] = base + k * C;
  }
}

__global__ __launch_bounds__(256) void partition2_k(const int* __restrict__ ni, const int* __restrict__ ei,
                                                    int* cur_be, int* cur_bn,
                                                    u32* __restrict__ SE, u32* __restrict__ SN, int nnz) {
  int xcd;
  asm volatile("s_getreg_b32 %0, hwreg(HW_REG_XCC_ID)" : "=s"(xcd));
  xcd &= 7;
  int stride = gridDim.x * blockDim.x;
  for (int j = blockIdx.x * blockDim.x + threadIdx.x; j < nnz; j += stride) {
    int n = ni[j], e = ei[j];
    int pe = atomicAdd(&cur_be[(e >> 5) * 8 + xcd], 1);
    SE[pe] = ((u32)(e & 31) << 17) | (u32)n;
    int pn = atomicAdd(&cur_bn[(n >> 5) * 8 + xcd], 1);
    SN[pn] = ((u32)(n & 31) << 17) | (u32)e;
  }
}

__global__ __launch_bounds__(256) void scatter2_k(const u32* __restrict__ S, const int* __restrict__ offs,
                                                  const int* __restrict__ cur_b,
                                                  int* __restrict__ list, int nRows) {
  __shared__ int cur[32];
  const int b = blockIdx.x;
  const int i0 = b << 5;
  const int tid = threadIdx.x;
  if (tid < 32) {
    int row = i0 + tid;
    cur[tid] = (row < nRows) ? offs[row] : 0;
  }
  __syncthreads();
  int r1 = i0 + 32; if (r1 > nRows) r1 = nRows;
  const int o0 = offs[i0];
  const int C = offs[r1] - o0;
  #pragma unroll 1
  for (int k = 0; k < 8; ++k) {
    int sbeg = 8 * o0 + k * C;
    int send = cur_b[b * 8 + k];
    for (int i = sbeg + tid; i < send; i += 256) {
      u32 v = S[i];
      int pos = atomicAdd(&cur[v >> 17], 1);
      list[pos] = (int)(v & 0x1FFFFu);
    }
  }
}

__global__ __launch_bounds__(256) void fill_nnz_k(const int* __restrict__ ni, const int* __restrict__ ei,
                                                  int* cur_n, int* cur_e, int* listN, int* listE, int nnz) {
  int stride = gridDim.x * blockDim.x;
  for (int j = blockIdx.x * blockDim.x + threadIdx.x; j < nnz; j += stride) {
    int n = ni[j], e = ei[j];
    int pn = atomicAdd(&cur_n[n], 1); listN[pn] = e;
    int pe = atomicAdd(&cur_e[e], 1); listE[pe] = n;
  }
}

// ================= gathers (width 256, bf16 operands, 1 wave/row, 4 bf16/lane) =================

__device__ __forceinline__ void acc4(float4& a, us4 v) {
  a.x += fb(v[0]); a.y += fb(v[1]); a.z += fb(v[2]); a.w += fb(v[3]);
}

// edge rows: e = prelu(De_inv*sum(t[members]) + bias) -> e_fullb (bf16) [+ fp32 split outs]
template<int SPLIT>
__global__ __launch_bounds__(256) void gather_edge_k(const u16* __restrict__ srcb,
                                                     const int* __restrict__ offs, const int* __restrict__ list,
                                                     const float* __restrict__ De_inv,
                                                     const float* __restrict__ b1, const float* __restrict__ b2,
                                                     const float* __restrict__ alphap,
                                                     u16* __restrict__ e_fullb,
                                                     float* __restrict__ d2a, float* __restrict__ d2b, int E) {
  const int wave = threadIdx.x >> 6, lane = threadIdx.x & 63;
  const int row = blockIdx.x * 4 + wave;
  if (row >= E) return;
  const int c = lane * 4;
  const int beg = offs[row], end = offs[row + 1];
  float4 a0 = {0,0,0,0}, a1 = {0,0,0,0}, a2 = {0,0,0,0}, a3 = {0,0,0,0};
  int i = beg;
  for (; i + 3 < end; i += 4) {
    int s0 = list[i], s1 = list[i + 1], s2 = list[i + 2], s3 = list[i + 3];
    us4 v0 = *(const us4*)&srcb[(size_t)s0 * 256 + c];
    us4 v1 = *(const us4*)&srcb[(size_t)s1 * 256 + c];
    us4 v2 = *(const us4*)&srcb[(size_t)s2 * 256 + c];
    us4 v3 = *(const us4*)&srcb[(size_t)s3 * 256 + c];
    acc4(a0, v0); acc4(a1, v1); acc4(a2, v2); acc4(a3, v3);
  }
  for (; i < end; ++i) acc4(a0, *(const us4*)&srcb[(size_t)list[i] * 256 + c]);
  float sc = De_inv[row];
  const float* bp = (c < 128) ? (b1 + c) : (b2 + c - 128);
  float4 bt = *(const float4*)bp;
  float al = *alphap;
  float4 o;
  o.x = sc * ((a0.x + a1.x) + (a2.x + a3.x)) + bt.x;
  o.y = sc * ((a0.y + a1.y) + (a2.y + a3.y)) + bt.y;
  o.z = sc * ((a0.z + a1.z) + (a2.z + a3.z)) + bt.z;
  o.w = sc * ((a0.w + a1.w) + (a2.w + a3.w)) + bt.w;
  o.x = (o.x >= 0.f) ? o.x : al * o.x;
  o.y = (o.y >= 0.f) ? o.y : al * o.y;
  o.z = (o.z >= 0.f) ? o.z : al * o.z;
  o.w = (o.w >= 0.f) ? o.w : al * o.w;
  us4 ob = {tob(o.x), tob(o.y), tob(o.z), tob(o.w)};
  *(us4*)&e_fullb[(size_t)row * 256 + c] = ob;
  if constexpr (SPLIT == 1) {
    if (c < 128) *(float4*)&d2a[(size_t)row * DD + c] = o;
    else         *(float4*)&d2b[(size_t)row * DD + c - 128] = o;
  }
}

// node rows: dst(bf16) = Dn_inv * ( prelu(t[row]+bias) + sum(e_fullb[edges]) )
__global__ __launch_bounds__(256) void gather_node_k(const u16* __restrict__ e_fullb,
                                                     const u16* __restrict__ tb,
                                                     const int* __restrict__ offs, const int* __restrict__ list,
                                                     const float* __restrict__ Dn_inv,
                                                     const float* __restrict__ b1, const float* __restrict__ b2,
                                                     const float* __restrict__ alphap,
                                                     u16* __restrict__ dstb, int N) {
  const int wave = threadIdx.x >> 6, lane = threadIdx.x & 63;
  const int row = blockIdx.x * 4 + wave;
  if (row >= N) return;
  const int c = lane * 4;
  const int beg = offs[row], end = offs[row + 1];
  float4 a0 = {0,0,0,0}, a1 = {0,0,0,0}, a2 = {0,0,0,0}, a3 = {0,0,0,0};
  int i = beg;
  for (; i + 3 < end; i += 4) {
    int s0 = list[i], s1 = list[i + 1], s2 = list[i + 2], s3 = list[i + 3];
    us4 v0 = *(const us4*)&e_fullb[(size_t)s0 * 256 + c];
    us4 v1 = *(const us4*)&e_fullb[(size_t)s1 * 256 + c];
    us4 v2 = *(const us4*)&e_fullb[(size_t)s2 * 256 + c];
    us4 v3 = *(const us4*)&e_fullb[(size_t)s3 * 256 + c];
    acc4(a0, v0); acc4(a1, v1); acc4(a2, v2); acc4(a3, v3);
  }
  for (; i < end; ++i) acc4(a0, *(const us4*)&e_fullb[(size_t)list[i] * 256 + c]);
  us4 tv4 = *(const us4*)&tb[(size_t)row * 256 + c];
  const float* bp = (c < 128) ? (b1 + c) : (b2 + c - 128);
  float4 bt = *(const float4*)bp;
  float al = *alphap;
  float sx = fb(tv4[0]) + bt.x; sx = (sx >= 0.f) ? sx : al * sx;
  float sy = fb(tv4[1]) + bt.y; sy = (sy >= 0.f) ? sy : al * sy;
  float sz = fb(tv4[2]) + bt.z; sz = (sz >= 0.f) ? sz : al * sz;
  float sw = fb(tv4[3]) + bt.w; sw = (sw >= 0.f) ? sw : al * sw;
  float sc = Dn_inv[row];
  us4 ob;
  ob[0] = tob(sc * (sx + ((a0.x + a1.x) + (a2.x + a3.x))));
  ob[1] = tob(sc * (sy + ((a0.y + a1.y) + (a2.y + a3.y))));
  ob[2] = tob(sc * (sz + ((a0.z + a1.z) + (a2.z + a3.z))));
  ob[3] = tob(sc * (sw + ((a0.w + a1.w) + (a2.w + a3.w))));
  *(us4*)&dstb[(size_t)row * 256 + c] = ob;
}

// ================= weight prep =================

struct WPtrs { const float* p[16]; };

__global__ __launch_bounds__(256) void prep_w_k(WPtrs wp, char* dst) {
  int m = blockIdx.x >> 3, s = blockIdx.x & 7;
  const float* W = wp.p[m];
  int t = threadIdx.x;
  int n = t & 127;
  int k0 = s * 16 + (t >> 7) * 8;
  us8 vhi, vlo;
  #pragma unroll
  for (int j = 0; j < 8; ++j) {
    float x = W[(size_t)(k0 + j) * DD + n];
    u32 ux = __builtin_bit_cast(u32, x);
    float hf = __builtin_bit_cast(float, ux & 0xFFFF0000u);
    float l = x - hf;
    vhi[j] = (u16)(ux >> 16);
    vlo[j] = (u16)(__builtin_bit_cast(u32, l) >> 16);
  }
  char* base = dst + (size_t)m * 65536;
  int byte = n * 256 + k0 * 2;
  byte ^= (n & 7) << 4;
  *(us8*)(base + byte) = vhi;
  *(us8*)(base + 32768 + byte) = vlo;
}

// ================= MFMA machinery =================

__device__ __forceinline__ void stage_w(const char* gsrc, char* lds, int tid) {
  int wave = tid >> 6, lane = tid & 63;
  #pragma unroll
  for (int i = 0; i < 16; ++i) {
    int off = (wave * 16 + i) * 1024;
    __builtin_amdgcn_global_load_lds(
        (const __attribute__((address_space(1))) u32*)(gsrc + off + lane * 16),
        (__attribute__((address_space(3))) u32*)(lds + off), 16, 0, 0);
  }
}

__device__ __forceinline__ void split8(const float vs[8], bh8& hi, bh8& lo) {
  #pragma unroll
  for (int j = 0; j < 8; ++j) {
    u32 u = __builtin_bit_cast(u32, vs[j]);
    float hf = __builtin_bit_cast(float, u & 0xFFFF0000u);
    float l = vs[j] - hf;
    hi[j] = (short)(u >> 16);
    lo[j] = (short)(__builtin_bit_cast(u32, l) >> 16);
  }
}

__device__ __forceinline__ void mk_afrag(const float* rowp, int koff, bh8& hi, bh8& lo) {
  float4 v0 = *(const float4*)(rowp + koff);
  float4 v1 = *(const float4*)(rowp + koff + 4);
  float vs[8] = {v0.x, v0.y, v0.z, v0.w, v1.x, v1.y, v1.z, v1.w};
  split8(vs, hi, lo);
}

// fp32-A split-3 path
__device__ __forceinline__ void mfma_ks(const bh8& ahi, const bh8& alo, const char* Wl,
                                        int ks, int lane, f4 acc[8]) {
  const int koff0 = (lane >> 4) * 8;
  const int k2 = (ks * 32 + koff0) * 2;
  #pragma unroll
  for (int cb = 0; cb < 8; ++cb) {
    int n = cb * 16 + (lane & 15);
    int byte = (n * 256 + k2) ^ ((n & 7) << 4);
    bh8 bhiF = *(const bh8*)(Wl + byte);
    bh8 bloF = *(const bh8*)(Wl + 32768 + byte);
    acc[cb] = __builtin_amdgcn_mfma_f32_16x16x32_bf16(ahi, bhiF, acc[cb], 0, 0, 0);
    acc[cb] = __builtin_amdgcn_mfma_f32_16x16x32_bf16(ahi, bloF, acc[cb], 0, 0, 0);
    acc[cb] = __builtin_amdgcn_mfma_f32_16x16x32_bf16(alo, bhiF, acc[cb], 0, 0, 0);
  }
}

// bf16-A exact path (2 MFMA)
__device__ __forceinline__ void mfma_ks_bf(const bh8& a, const char* Wl,
                                           int ks, int lane, f4 acc[8]) {
  const int koff0 = (lane >> 4) * 8;
  const int k2 = (ks * 32 + koff0) * 2;
  #pragma unroll
  for (int cb = 0; cb < 8; ++cb) {
    int n = cb * 16 + (lane & 15);
    int byte = (n * 256 + k2) ^ ((n & 7) << 4);
    bh8 bhiF = *(const bh8*)(Wl + byte);
    bh8 bloF = *(const bh8*)(Wl + 32768 + byte);
    acc[cb] = __builtin_amdgcn_mfma_f32_16x16x32_bf16(a, bhiF, acc[cb], 0, 0, 0);
    acc[cb] = __builtin_amdgcn_mfma_f32_16x16x32_bf16(a, bloF, acc[cb], 0, 0, 0);
  }
}

__device__ __forceinline__ void mfma_passS(const float* __restrict__ A, size_t astride, int acoff,
                                           const char* Wl, int rbase, int nrows, int lane, f4 acc[8]) {
  int r = rbase + (lane & 15);
  if (r >= nrows) r = nrows - 1;
  const float* rowp = A + (size_t)r * astride + acoff;
  const int koff0 = (lane >> 4) * 8;
  #pragma unroll
  for (int ks = 0; ks < 4; ++ks) {
    bh8 ahi, alo;
    mk_afrag(rowp, ks * 32 + koff0, ahi, alo);
    mfma_ks(ahi, alo, Wl, ks, lane, acc);
  }
}

// bf16-A pass (direct us8 loads)
__device__ __forceinline__ void mfma_passB(const u16* __restrict__ A, size_t astride, int acoff,
                                           const char* Wl, int rbase, int nrows, int lane, f4 acc[8]) {
  int r = rbase + (lane & 15);
  if (r >= nrows) r = nrows - 1;
  const u16* rowp = A + (size_t)r * astride + acoff;
  const int koff0 = (lane >> 4) * 8;
  #pragma unroll
  for (int ks = 0; ks < 4; ++ks) {
    bh8 a = __builtin_bit_cast(bh8, *(const us8*)(rowp + ks * 32 + koff0));
    mfma_ks_bf(a, Wl, ks, lane, acc);
  }
}

struct AFragB { bh8 a[4]; };

__device__ __forceinline__ void load_afragB(const u16* __restrict__ A, size_t astride, int acoff,
                                            int rbase, int nrows, int lane, AFragB& f) {
  int r = rbase + (lane & 15);
  if (r >= nrows) r = nrows - 1;
  const u16* rowp = A + (size_t)r * astride + acoff;
  const int koff0 = (lane >> 4) * 8;
  #pragma unroll
  for (int ks = 0; ks < 4; ++ks)
    f.a[ks] = __builtin_bit_cast(bh8, *(const us8*)(rowp + ks * 32 + koff0));
}

__device__ __forceinline__ void mfma_pass_fragB(const AFragB& f, const char* Wl, int lane, f4 acc[8]) {
  #pragma unroll
  for (int ks = 0; ks < 4; ++ks) mfma_ks_bf(f.a[ks], Wl, ks, lane, acc);
}

// MODE 0: raw; MODE 1: +bias +prelu.  OBF: write bf16 [row*ostride+...] instead of fp32.
template<int MODE, int OBF>
__device__ __forceinline__ void epilogueS(f4 acc[8], const float* bias, const float* alphap,
                                          void* outp, size_t ostride, int ocoff,
                                          int rbase, int nrows, int lane) {
  float al = 0.f;
  if constexpr (MODE == 1) al = *alphap;
  const int cidx = lane & 15;
  int rq = rbase + (lane >> 4) * 4;
  float b8[8];
  if constexpr (MODE == 1) {
    #pragma unroll
    for (int cb = 0; cb < 8; ++cb) b8[cb] = bias[cb * 16 + cidx];
  }
  #pragma unroll
  for (int q = 0; q < 4; ++q) {
    int row = rq + q;
    if (row < nrows) {
      #pragma unroll
      for (int cb = 0; cb < 8; ++cb) {
        float v = acc[cb][q];
        if constexpr (MODE == 1) { v += b8[cb]; v = (v >= 0.f) ? v : al * v; }
        if constexpr (OBF == 1) {
          u16* op = (u16*)outp + (size_t)row * ostride + ocoff + cidx;
          op[cb * 16] = tob(v);
        } else {
          float* op = (float*)outp + (size_t)row * ostride + ocoff + cidx;
          op[cb * 16] = v;
        }
      }
    }
  }
}

#define ACC_ZERO(acc) { _Pragma("unroll") for (int cb = 0; cb < 8; ++cb) acc[cb] = {0.f, 0.f, 0.f, 0.f}; }

// ================= GEMM kernels (per-tile grids) =================

// ABF: A operands are bf16 (2-term MFMA). Otherwise fp32 split-3.
template<int MODE, int OBF, int ABF>
__global__ __launch_bounds__(256, 2) void gemm_halves_k(const void* __restrict__ A1, size_t as1, int ac1, const char* W1, const float* b1_,
                                                        const void* __restrict__ A2, size_t as2, int ac2, const char* W2, const float* b2_,
                                                        const float* __restrict__ alphap,
                                                        void* __restrict__ out, int nrows) {
  __shared__ char Wl[65536];
  const int wave = threadIdx.x >> 6, lane = threadIdx.x & 63;
  const int rbase = blockIdx.x * 64 + wave * 16;
  f4 acc[8];
  stage_w(W1, Wl, threadIdx.x);
  __syncthreads();
  ACC_ZERO(acc);
  if constexpr (ABF) mfma_passB((const u16*)A1, as1, ac1, Wl, rbase, nrows, lane, acc);
  else               mfma_passS((const float*)A1, as1, ac1, Wl, rbase, nrows, lane, acc);
  epilogueS<MODE, OBF>(acc, b1_, alphap, out, 256, 0, rbase, nrows, lane);
  __syncthreads();
  stage_w(W2, Wl, threadIdx.x);
  __syncthreads();
  ACC_ZERO(acc);
  if constexpr (ABF) mfma_passB((const u16*)A2, as2, ac2, Wl, rbase, nrows, lane, acc);
  else               mfma_passS((const float*)A2, as2, ac2, Wl, rbase, nrows, lane, acc);
  epilogueS<MODE, OBF>(acc, b2_, alphap, out, 256, 128, rbase, nrows, lane);
}

// encoder final (A = aggb bf16): n1/n2 fp32 + nn1 fp32 + bf16 side copies n1b/n2b
__global__ __launch_bounds__(256, 2) void enc_final_k(const u16* __restrict__ aggb, const char* W1, const float* b1_,
                                                      const char* W2, const float* b2_,
                                                      const float* __restrict__ alphap,
                                                      float* __restrict__ n1, float* __restrict__ n2,
                                                      u16* __restrict__ n1b, u16* __restrict__ n2b,
                                                      float* __restrict__ nn1, int nrows) {
  __shared__ char Wl[65536];
  const int wave = threadIdx.x >> 6, lane = threadIdx.x & 63;
  const int rbase = blockIdx.x * 64 + wave * 16;
  const int cidx = lane & 15;
  f4 acc[8];
  float al = *alphap;
  #pragma unroll 1
  for (int h = 0; h < 2; ++h) {
    if (h) __syncthreads();
    stage_w(h ? W2 : W1, Wl, threadIdx.x);
    __syncthreads();
    const float* bp = h ? b2_ : b1_;
    float* nout = h ? n2 : n1;
    u16* nbout = h ? n2b : n1b;
    float b8[8];
    #pragma unroll
    for (int cb = 0; cb < 8; ++cb) b8[cb] = bp[cb * 16 + cidx];
    ACC_ZERO(acc);
    mfma_passB(aggb, 256, h * 128, Wl, rbase, nrows, lane, acc);
    int rq = rbase + (lane >> 4) * 4;
    #pragma unroll
    for (int q = 0; q < 4; ++q) {
      int row = rq + q;
      if (row < nrows) {
        float* op = nout + (size_t)row * DD + cidx;
        float* op2 = nn1 + (size_t)row * 256 + h * 128 + cidx;
        u16* op3 = nbout + (size_t)row * DD + cidx;
        #pragma unroll
        for (int cb = 0; cb < 8; ++cb) {
          float v = acc[cb][q] + b8[cb];
          v = (v >= 0.f) ? v : al * v;
          op[cb * 16] = v;
          op2[cb * 16] = v;
          op3[cb * 16] = tob(v);
        }
      }
    }
  }
}

// decoder pair layer, 2 streams via blockIdx.y; ALL A-operands bf16, frags register-resident.
// OBF=1: outputs bf16 (decoder temps); OBF=0: outputs fp32 (graded).
template<int OBF>
__global__ __launch_bounds__(256, 2) void dec_pair2b_k(const u16* __restrict__ xA0, const u16* __restrict__ xB0,
                                                       const u16* __restrict__ xA1, const u16* __restrict__ xB1,
                                                       const u16* __restrict__ aggb,
                                                       const char* WxA, const char* WeA, const float* bA,
                                                       const char* WxB, const char* WeB, const float* bB,
                                                       const float* __restrict__ alphap,
                                                       void* __restrict__ o1_0, void* __restrict__ o2_0,
                                                       void* __restrict__ o1_1, void* __restrict__ o2_1,
                                                       int nrows) {
  __shared__ char Wl[65536];
  const int y = blockIdx.y;
  const u16* xA = y ? xA1 : xA0;
  const u16* xB = y ? xB1 : xB0;
  void* o1 = y ? o1_1 : o1_0;
  void* o2 = y ? o2_1 : o2_0;
  const int acoff = y * 128;
  const int wave = threadIdx.x >> 6, lane = threadIdx.x & 63;
  const int rbase = blockIdx.x * 64 + wave * 16;
  AFragB fa, fxA, fxB;
  load_afragB(aggb, 256, acoff, rbase, nrows, lane, fa);
  load_afragB(xA, DD, 0, rbase, nrows, lane, fxA);
  load_afragB(xB, DD, 0, rbase, nrows, lane, fxB);
  f4 acc[8];
  stage_w(WxA, Wl, threadIdx.x);
  __syncthreads();
  ACC_ZERO(acc);
  mfma_pass_fragB(fxA, Wl, lane, acc);
  __syncthreads();
  stage_w(WeA, Wl, threadIdx.x);
  __syncthreads();
  mfma_pass_fragB(fa, Wl, lane, acc);
  epilogueS<1, OBF>(acc, bA, alphap, o1, DD, 0, rbase, nrows, lane);
  __syncthreads();
  stage_w(WxB, Wl, threadIdx.x);
  __syncthreads();
  ACC_ZERO(acc);
  mfma_pass_fragB(fxB, Wl, lane, acc);
  __syncthreads();
  stage_w(WeB, Wl, threadIdx.x);
  __syncthreads();
  mfma_pass_fragB(fa, Wl, lane, acc);
  epilogueS<1, OBF>(acc, bB, alphap, o2, DD, 0, rbase, nrows, lane);
}

// ================= host =================

extern "C" void kernel_launch(void* const* d_in, const int* in_sizes, int n_in,
                              void* d_out, int out_size, void* d_ws, size_t ws_size,
                              hipStream_t stream) {
  const float* x        = (const float*)d_in[0];
  const float* xx       = (const float*)d_in[1];
  const int*   node_idx = (const int*)d_in[2];
  const int*   edge_idx = (const int*)d_in[3];
  const float* alphap   = (const float*)d_in[6];
  const float* e1_Wn2e  = (const float*)d_in[7];
  const float* e1_bn2e  = (const float*)d_in[8];
  const float* e1_We2n  = (const float*)d_in[9];
  const float* e1_be2n  = (const float*)d_in[10];
  const float* e2_Wn2e  = (const float*)d_in[11];
  const float* e2_bn2e  = (const float*)d_in[12];
  const float* e2_We2n  = (const float*)d_in[13];
  const float* e2_be2n  = (const float*)d_in[14];
  const float* d1_We    = (const float*)d_in[15];
  const float* d1_Wx    = (const float*)d_in[16];
  const float* d1_b     = (const float*)d_in[17];
  const float* d2_We    = (const float*)d_in[18];
  const float* d2_Wx    = (const float*)d_in[19];
  const float* d2_b     = (const float*)d_in[20];

  const int N   = in_sizes[0] / DD;
  const int NNZ = in_sizes[2];
  const int E   = (out_size - 1024 * N) / 256;
  const int NBE = (E + 31) >> 5;
  const int NBN = (N + 31) >> 5;

  // ---- d_out slot map ----
  float* out  = (float*)d_out;
  float* nn1  = out;
  float* n1   = out + (size_t)N * 256;
  float* e1o  = n1 + (size_t)N * DD;
  float* n2   = e1o + (size_t)E * DD;
  float* e2o  = n2 + (size_t)N * DD;
  float* x11  = e2o + (size_t)E * DD;
  float* x21  = x11 + (size_t)N * DD;
  float* x12  = x21 + (size_t)N * DD;
  float* x22  = x12 + (size_t)N * DD;

  // ---- workspace carve ----
  size_t off = 0;
  char* w0 = (char*)d_ws;
  auto carve = [&](size_t bytes) -> void* {
    void* p = (void*)(w0 + off);
    off += (bytes + 255) & ~(size_t)255;
    return p;
  };
  int* cn      = (int*)carve((size_t)N * 4);
  int* ce      = (int*)carve((size_t)E * 4);
  int* offs_n  = (int*)carve((size_t)(N + 1) * 4);
  int* offs_e  = (int*)carve((size_t)(E + 1) * 4);
  int* listN   = (int*)carve((size_t)NNZ * 4);
  int* listE   = (int*)carve((size_t)NNZ * 4);
  float* Dn_inv = (float*)carve((size_t)N * 4);
  float* De_inv = (float*)carve((size_t)E * 4);
  char* Wprep  = (char*)carve((size_t)16 * 65536);
  u16* tb      = (u16*)carve((size_t)N * 256 * 2);    // bf16: GEMM1/GEMM3 out (edge-gather src)
  u16* e_fullb = (u16*)carve((size_t)E * 256 * 2);    // bf16 edge features
  u16* thb     = (u16*)carve((size_t)N * 256 * 2);    // bf16: node-agg L1 (hidden GEMM A)
  u16* aggb    = (u16*)carve((size_t)N * 256 * 2);    // bf16: shared aggregate
  u16* t1b     = (u16*)carve((size_t)N * 256 * 2);    // bf16: hidden (GEMM3 A)
  u16* n1b     = (u16*)carve((size_t)N * DD * 2);     // bf16 copy of n1 (dec L0 A)
  u16* n2b     = (u16*)carve((size_t)N * DD * 2);     // bf16 copy of n2
  u16* dt0a    = (u16*)carve((size_t)N * DD * 2);     // bf16 decoder temps
  u16* dt1a    = (u16*)carve((size_t)N * DD * 2);
  u16* dt0b    = (u16*)carve((size_t)N * DD * 2);
  u16* dt1b    = (u16*)carve((size_t)N * DD * 2);
  int* cur_n   = (int*)carve((size_t)N * 4);
  int* cur_e   = (int*)carve((size_t)E * 4);
  int* cur_be  = (int*)carve((size_t)NBE * 8 * 4);
  int* cur_bn  = (int*)carve((size_t)NBN * 8 * 4);
  u32* SE      = (u32*)carve((size_t)NNZ * 8 * 4);
  u32* SN      = (u32*)carve((size_t)NNZ * 8 * 4);
  const bool staged = off <= ws_size;

  // ---- weight prep table ----
  WPtrs wp;
  wp.p[0] = e1_Wn2e;  wp.p[1] = e1_Wn2e + DD * DD;
  wp.p[2] = e1_We2n;  wp.p[3] = e1_We2n + DD * DD;
  wp.p[4] = e2_Wn2e;  wp.p[5] = e2_Wn2e + DD * DD;
  wp.p[6] = e2_We2n;  wp.p[7] = e2_We2n + DD * DD;
  wp.p[8] = d1_We;    wp.p[9] = d1_We + DD * DD;
  wp.p[10] = d1_Wx;   wp.p[11] = d1_Wx + DD * DD;
  wp.p[12] = d2_We;   wp.p[13] = d2_We + DD * DD;
  wp.p[14] = d2_Wx;   wp.p[15] = d2_Wx + DD * DD;
  auto WP = [&](int i) -> const char* { return Wprep + (size_t)i * 65536; };

  const int thr = 256;
  const int gMax = ((N > E ? N : E) + thr - 1) / thr;
  int gNNZ = (NNZ + thr - 1) / thr; if (gNNZ > 2048) gNNZ = 2048;
  const int NT = (N + 63) / 64;
  const int gGatE = (E + 3) / 4;
  const int gGatN = (N + 3) / 4;

  prep_w_k<<<128, 256, 0, stream>>>(wp, Wprep);
  init_counts_k<<<gMax, thr, 0, stream>>>(cn, ce, N, E);
  hist_k<<<gNNZ, thr, 0, stream>>>(node_idx, edge_idx, cn, ce, NNZ);
  exscan2_k<<<2, 1024, 0, stream>>>(cn, offs_n, N, ce, offs_e, E);
  fill_deg_k<<<gMax, thr, 0, stream>>>(offs_n, offs_e, Dn_inv, De_inv,
                                       cur_be, cur_bn, cur_n, cur_e, N, E, NBE, NBN);

  if (staged) {
    partition2_k<<<gNNZ, thr, 0, stream>>>(node_idx, edge_idx, cur_be, cur_bn, SE, SN, NNZ);
    scatter2_k<<<NBE, 256, 0, stream>>>(SE, offs_e, cur_be, listE, E);
    scatter2_k<<<NBN, 256, 0, stream>>>(SN, offs_n, cur_bn, listN, N);
  } else {
    fill_nnz_k<<<gNNZ, thr, 0, stream>>>(node_idx, edge_idx, cur_n, cur_e, listN, listE, NNZ);
  }

  // ---- fused dual-encoder (width-256; bf16 data plane) ----
  // L1 in: tb = bf16([x@W0 | xx@W4])   (A fp32 split-3, graded inputs stay exact)
  gemm_halves_k<0, 1, 0><<<NT, 256, 0, stream>>>(x, DD, 0, WP(0), nullptr,
                                                 xx, DD, 0, WP(4), nullptr, alphap, tb, N);
  // e(L1) -> e_fullb
  gather_edge_k<0><<<gGatE, 256, 0, stream>>>(tb, offs_e, listE, De_inv, e1_bn2e, e2_bn2e,
                                              alphap, e_fullb, nullptr, nullptr, E);
  // thb = bf16(Dn_inv*(prelu(tb+bn2e_0) + seg_n(e)))
  gather_node_k<<<gGatN, 256, 0, stream>>>(e_fullb, tb, offs_n, listN, Dn_inv, e1_bn2e, e2_bn2e,
                                           alphap, thb, N);
  // hidden: t1b = bf16(prelu(thb@We2n_0 + be2n_0))   [A bf16 2-term]
  gemm_halves_k<1, 1, 1><<<NT, 256, 0, stream>>>(thb, 256, 0, WP(2), e1_be2n,
                                                 thb, 256, 128, WP(6), e2_be2n, alphap, t1b, N);
  // L2 in: tb = bf16(hidden@Wn2e_1)   [A bf16 2-term]
  gemm_halves_k<0, 1, 1><<<NT, 256, 0, stream>>>(t1b, 256, 0, WP(1), nullptr,
                                                 t1b, 256, 128, WP(5), nullptr, alphap, tb, N);
  // e(L2) -> e_fullb (+ fp32 e1o/e2o)
  gather_edge_k<1><<<gGatE, 256, 0, stream>>>(tb, offs_e, listE, De_inv, e1_bn2e + DD, e2_bn2e + DD,
                                              alphap, e_fullb, e1o, e2o, E);
  // aggb = bf16(Dn_inv*(prelu(tb+bn2e_1) + seg_n(e)))
  gather_node_k<<<gGatN, 256, 0, stream>>>(e_fullb, tb, offs_n, listN, Dn_inv, e1_bn2e + DD, e2_bn2e + DD,
                                           alphap, aggb, N);
  // n1, n2, nn1 (+ bf16 side copies)
  enc_final_k<<<NT, 256, 0, stream>>>(aggb, WP(3), e1_be2n + DD, WP(7), e2_be2n + DD,
                                      alphap, n1, n2, n1b, n2b, nn1, N);

  // ---- decoders (merged streams; all-bf16 A, register frags) ----
  dim3 gDec(NT, 2);
  dec_pair2b_k<1><<<gDec, 256, 0, stream>>>(n1b, n1b, n2b, n2b, aggb,
                                            WP(10), WP(8), d1_b, WP(14), WP(12), d2_b, alphap,
                                            dt0a, dt1a, dt0b, dt1b, N);
  dec_pair2b_k<0><<<gDec, 256, 0, stream>>>(dt0a, dt1a, dt0b, dt1b, aggb,
                                            WP(11), WP(9), d1_b + DD, WP(15), WP(13), d2_b + DD, alphap,
                                            x11, x22, x12, x21, N);
}

// Round 10
// 609.258 us; speedup vs baseline: 1.8586x; 1.1123x over previous
//
#include <hip/hip_runtime.h>

#define DD 128

typedef __attribute__((ext_vector_type(8))) short bh8;       // 8 bf16 (as i16 bits)
typedef __attribute__((ext_vector_type(8))) unsigned short us8;
typedef __attribute__((ext_vector_type(4))) unsigned short us4;
typedef __attribute__((ext_vector_type(4))) float f4;
typedef unsigned int u32;
typedef unsigned short u16;

__device__ __forceinline__ u16 tob(float f) {           // fp32 -> bf16 RNE
  u32 u = __builtin_bit_cast(u32, f);
  u += 0x7FFFu + ((u >> 16) & 1u);
  return (u16)(u >> 16);
}
__device__ __forceinline__ float fb(u16 h) { return __builtin_bit_cast(float, (u32)h << 16); }

// ================= CSR build (real edges only; self-loops analytic) =================

__global__ __launch_bounds__(256) void init_counts_k(int* cn, int* ce, int N, int E) {
  int g = blockIdx.x * blockDim.x + threadIdx.x;
  if (g < E) ce[g] = 0;
  if (g < N) cn[g] = 0;
}

__global__ __launch_bounds__(256) void hist_k(const int* __restrict__ ni, const int* __restrict__ ei,
                                              int* cn, int* ce, int nnz) {
  int stride = gridDim.x * blockDim.x;
  for (int j = blockIdx.x * blockDim.x + threadIdx.x; j < nnz; j += stride) {
    atomicAdd(&cn[ni[j]], 1);
    atomicAdd(&ce[ei[j]], 1);
  }
}

// ---- parallel hierarchical exclusive scan (chunks of 1024) ----

__global__ __launch_bounds__(256) void scan_partials_k(const int* __restrict__ cn, const int* __restrict__ ce,
                                                       int* part, int NCHN, int N, int NCHE, int E) {
  __shared__ int red[256];
  int b = blockIdx.x, tid = threadIdx.x;
  const int* cnt = (b < NCHN) ? cn : ce;
  int n = (b < NCHN) ? N : E;
  int base = ((b < NCHN) ? b : (b - NCHN)) << 10;
  int i0 = base + tid * 4;
  int s = 0;
  #pragma unroll
  for (int j = 0; j < 4; ++j) { int i = i0 + j; if (i < n) s += cnt[i]; }
  red[tid] = s; __syncthreads();
  for (int off = 128; off > 0; off >>= 1) {
    if (tid < off) red[tid] += red[tid + off];
    __syncthreads();
  }
  if (tid == 0) part[b] = red[0];
}

__device__ __forceinline__ int blk_excl_scan(int s, int tid, int* sums) {
  sums[tid] = s; __syncthreads();
  for (int off = 1; off < 256; off <<= 1) {
    int t = (tid >= off) ? sums[tid - off] : 0;
    __syncthreads();
    sums[tid] += t;
    __syncthreads();
  }
  int ex = sums[tid] - s;
  __syncthreads();
  return ex;
}

__global__ __launch_bounds__(256) void scan_chunks_k(int* part, int NCHN, int NCHE) {
  __shared__ int sums[256];
  int tid = threadIdx.x;
  {
    int v = (tid < NCHN) ? part[tid] : 0;       // NCHN <= 256 (N <= 262144)
    int ex = blk_excl_scan(v, tid, sums);
    if (tid < NCHN) part[tid] = ex;
  }
  __syncthreads();
  {
    int v = (tid < NCHE) ? part[NCHN + tid] : 0;
    int ex = blk_excl_scan(v, tid, sums);
    if (tid < NCHE) part[NCHN + tid] = ex;
  }
}

__global__ __launch_bounds__(256) void scan_apply_k(const int* __restrict__ cn, const int* __restrict__ ce,
                                                    const int* __restrict__ part,
                                                    int* offs_n, int* offs_e,
                                                    int NCHN, int N, int NCHE, int E) {
  __shared__ int sums[256];
  int b = blockIdx.x, tid = threadIdx.x;
  const int* cnt = (b < NCHN) ? cn : ce;
  int* offs = (b < NCHN) ? offs_n : offs_e;
  int n = (b < NCHN) ? N : E;
  int base = ((b < NCHN) ? b : (b - NCHN)) << 10;
  int i0 = base + tid * 4;
  int v[4]; int s = 0;
  #pragma unroll
  for (int j = 0; j < 4; ++j) { int i = i0 + j; int t = (i < n) ? cnt[i] : 0; v[j] = t; s += t; }
  int ex = blk_excl_scan(s, tid, sums);
  int run = part[b] + ex;
  #pragma unroll
  for (int j = 0; j < 4; ++j) { int i = i0 + j; if (i < n) offs[i] = run; run += v[j]; }
  if (tid == 255 && base + 1024 >= n) offs[n] = run;
}

__global__ __launch_bounds__(256) void fill_deg_k(const int* __restrict__ offs_n, const int* __restrict__ offs_e,
                                                  float* Dn_inv, float* De_inv,
                                                  int* cur_be, int* cur_bn, int* cur_n, int* cur_e,
                                                  int N, int E, int NBE, int NBN) {
  int g = blockIdx.x * blockDim.x + threadIdx.x;
  if (g < E) {
    int b = offs_e[g], e = offs_e[g + 1];
    De_inv[g] = (e > b) ? 1.0f / (float)(e - b) : 0.0f;
    cur_e[g] = b;
  }
  if (g < N) {
    int b = offs_n[g], e = offs_n[g + 1];
    Dn_inv[g] = 1.0f / (float)(e - b + 1);   // +1 self loop
    cur_n[g] = b;
  }
  if (g < NBE) {
    int r1 = (g + 1) * 32; if (r1 > E) r1 = E;
    int o0 = offs_e[g * 32], o1 = offs_e[r1];
    int C = o1 - o0, base = 8 * o0;
    #pragma unroll
    for (int k = 0; k < 8; ++k) cur_be[g * 8 + k] = base + k * C;
  }
  if (g < NBN) {
    int r1 = (g + 1) * 32; if (r1 > N) r1 = N;
    int o0 = offs_n[g * 32], o1 = offs_n[r1];
    int C = o1 - o0, base = 8 * o0;
    #pragma unroll
    for (int k = 0; k < 8; ++k) cur_bn[g * 8 + k] = base + k * C;
  }
}

__global__ __launch_bounds__(256) void partition2_k(const int* __restrict__ ni, const int* __restrict__ ei,
                                                    int* cur_be, int* cur_bn,
                                                    u32* __restrict__ SE, u32* __restrict__ SN, int nnz) {
  int xcd;
  asm volatile("s_getreg_b32 %0, hwreg(HW_REG_XCC_ID)" : "=s"(xcd));
  xcd &= 7;
  int stride = gridDim.x * blockDim.x;
  for (int j = blockIdx.x * blockDim.x + threadIdx.x; j < nnz; j += stride) {
    int n = ni[j], e = ei[j];
    int pe = atomicAdd(&cur_be[(e >> 5) * 8 + xcd], 1);
    SE[pe] = ((u32)(e & 31) << 17) | (u32)n;
    int pn = atomicAdd(&cur_bn[(n >> 5) * 8 + xcd], 1);
    SN[pn] = ((u32)(n & 31) << 17) | (u32)e;
  }
}

__global__ __launch_bounds__(256) void scatter2_k(const u32* __restrict__ S, const int* __restrict__ offs,
                                                  const int* __restrict__ cur_b,
                                                  int* __restrict__ list, int nRows) {
  __shared__ int cur[32];
  const int b = blockIdx.x;
  const int i0 = b << 5;
  const int tid = threadIdx.x;
  if (tid < 32) {
    int row = i0 + tid;
    cur[tid] = (row < nRows) ? offs[row] : 0;
  }
  __syncthreads();
  int r1 = i0 + 32; if (r1 > nRows) r1 = nRows;
  const int o0 = offs[i0];
  const int C = offs[r1] - o0;
  #pragma unroll 1
  for (int k = 0; k < 8; ++k) {
    int sbeg = 8 * o0 + k * C;
    int send = cur_b[b * 8 + k];
    for (int i = sbeg + tid; i < send; i += 256) {
      u32 v = S[i];
      int pos = atomicAdd(&cur[v >> 17], 1);
      list[pos] = (int)(v & 0x1FFFFu);
    }
  }
}

__global__ __launch_bounds__(256) void fill_nnz_k(const int* __restrict__ ni, const int* __restrict__ ei,
                                                  int* cur_n, int* cur_e, int* listN, int* listE, int nnz) {
  int stride = gridDim.x * blockDim.x;
  for (int j = blockIdx.x * blockDim.x + threadIdx.x; j < nnz; j += stride) {
    int n = ni[j], e = ei[j];
    int pn = atomicAdd(&cur_n[n], 1); listN[pn] = e;
    int pe = atomicAdd(&cur_e[e], 1); listE[pe] = n;
  }
}

// ================= gathers (width 256, bf16 operands, 1 wave/row, 4 bf16/lane) =================

__device__ __forceinline__ void acc4(float4& a, us4 v) {
  a.x += fb(v[0]); a.y += fb(v[1]); a.z += fb(v[2]); a.w += fb(v[3]);
}

template<int SPLIT>
__global__ __launch_bounds__(256) void gather_edge_k(const u16* __restrict__ srcb,
                                                     const int* __restrict__ offs, const int* __restrict__ list,
                                                     const float* __restrict__ De_inv,
                                                     const float* __restrict__ b1, const float* __restrict__ b2,
                                                     const float* __restrict__ alphap,
                                                     u16* __restrict__ e_fullb,
                                                     float* __restrict__ d2a, float* __restrict__ d2b, int E) {
  const int wave = threadIdx.x >> 6, lane = threadIdx.x & 63;
  const int row = blockIdx.x * 4 + wave;
  if (row >= E) return;
  const int c = lane * 4;
  const int beg = offs[row], end = offs[row + 1];
  float4 a0 = {0,0,0,0}, a1 = {0,0,0,0}, a2 = {0,0,0,0}, a3 = {0,0,0,0};
  int i = beg;
  for (; i + 3 < end; i += 4) {
    int s0 = list[i], s1 = list[i + 1], s2 = list[i + 2], s3 = list[i + 3];
    us4 v0 = *(const us4*)&srcb[(size_t)s0 * 256 + c];
    us4 v1 = *(const us4*)&srcb[(size_t)s1 * 256 + c];
    us4 v2 = *(const us4*)&srcb[(size_t)s2 * 256 + c];
    us4 v3 = *(const us4*)&srcb[(size_t)s3 * 256 + c];
    acc4(a0, v0); acc4(a1, v1); acc4(a2, v2); acc4(a3, v3);
  }
  for (; i < end; ++i) acc4(a0, *(const us4*)&srcb[(size_t)list[i] * 256 + c]);
  float sc = De_inv[row];
  const float* bp = (c < 128) ? (b1 + c) : (b2 + c - 128);
  float4 bt = *(const float4*)bp;
  float al = *alphap;
  float4 o;
  o.x = sc * ((a0.x + a1.x) + (a2.x + a3.x)) + bt.x;
  o.y = sc * ((a0.y + a1.y) + (a2.y + a3.y)) + bt.y;
  o.z = sc * ((a0.z + a1.z) + (a2.z + a3.z)) + bt.z;
  o.w = sc * ((a0.w + a1.w) + (a2.w + a3.w)) + bt.w;
  o.x = (o.x >= 0.f) ? o.x : al * o.x;
  o.y = (o.y >= 0.f) ? o.y : al * o.y;
  o.z = (o.z >= 0.f) ? o.z : al * o.z;
  o.w = (o.w >= 0.f) ? o.w : al * o.w;
  us4 ob = {tob(o.x), tob(o.y), tob(o.z), tob(o.w)};
  *(us4*)&e_fullb[(size_t)row * 256 + c] = ob;
  if constexpr (SPLIT == 1) {
    if (c < 128) *(float4*)&d2a[(size_t)row * DD + c] = o;
    else         *(float4*)&d2b[(size_t)row * DD + c - 128] = o;
  }
}

__global__ __launch_bounds__(256) void gather_node_k(const u16* __restrict__ e_fullb,
                                                     const u16* __restrict__ tb,
                                                     const int* __restrict__ offs, const int* __restrict__ list,
                                                     const float* __restrict__ Dn_inv,
                                                     const float* __restrict__ b1, const float* __restrict__ b2,
                                                     const float* __restrict__ alphap,
                                                     u16* __restrict__ dstb, int N) {
  const int wave = threadIdx.x >> 6, lane = threadIdx.x & 63;
  const int row = blockIdx.x * 4 + wave;
  if (row >= N) return;
  const int c = lane * 4;
  const int beg = offs[row], end = offs[row + 1];
  float4 a0 = {0,0,0,0}, a1 = {0,0,0,0}, a2 = {0,0,0,0}, a3 = {0,0,0,0};
  int i = beg;
  for (; i + 3 < end; i += 4) {
    int s0 = list[i], s1 = list[i + 1], s2 = list[i + 2], s3 = list[i + 3];
    us4 v0 = *(const us4*)&e_fullb[(size_t)s0 * 256 + c];
    us4 v1 = *(const us4*)&e_fullb[(size_t)s1 * 256 + c];
    us4 v2 = *(const us4*)&e_fullb[(size_t)s2 * 256 + c];
    us4 v3 = *(const us4*)&e_fullb[(size_t)s3 * 256 + c];
    acc4(a0, v0); acc4(a1, v1); acc4(a2, v2); acc4(a3, v3);
  }
  for (; i < end; ++i) acc4(a0, *(const us4*)&e_fullb[(size_t)list[i] * 256 + c]);
  us4 tv4 = *(const us4*)&tb[(size_t)row * 256 + c];
  const float* bp = (c < 128) ? (b1 + c) : (b2 + c - 128);
  float4 bt = *(const float4*)bp;
  float al = *alphap;
  float sx = fb(tv4[0]) + bt.x; sx = (sx >= 0.f) ? sx : al * sx;
  float sy = fb(tv4[1]) + bt.y; sy = (sy >= 0.f) ? sy : al * sy;
  float sz = fb(tv4[2]) + bt.z; sz = (sz >= 0.f) ? sz : al * sz;
  float sw = fb(tv4[3]) + bt.w; sw = (sw >= 0.f) ? sw : al * sw;
  float sc = Dn_inv[row];
  us4 ob;
  ob[0] = tob(sc * (sx + ((a0.x + a1.x) + (a2.x + a3.x))));
  ob[1] = tob(sc * (sy + ((a0.y + a1.y) + (a2.y + a3.y))));
  ob[2] = tob(sc * (sz + ((a0.z + a1.z) + (a2.z + a3.z))));
  ob[3] = tob(sc * (sw + ((a0.w + a1.w) + (a2.w + a3.w))));
  *(us4*)&dstb[(size_t)row * 256 + c] = ob;
}

// ================= weight prep =================

struct WPtrs { const float* p[16]; };

__global__ __launch_bounds__(256) void prep_w_k(WPtrs wp, char* dst) {
  int m = blockIdx.x >> 3, s = blockIdx.x & 7;
  const float* W = wp.p[m];
  int t = threadIdx.x;
  int n = t & 127;
  int k0 = s * 16 + (t >> 7) * 8;
  us8 vhi, vlo;
  #pragma unroll
  for (int j = 0; j < 8; ++j) {
    float x = W[(size_t)(k0 + j) * DD + n];
    u32 ux = __builtin_bit_cast(u32, x);
    float hf = __builtin_bit_cast(float, ux & 0xFFFF0000u);
    float l = x - hf;
    vhi[j] = (u16)(ux >> 16);
    vlo[j] = (u16)(__builtin_bit_cast(u32, l) >> 16);
  }
  char* base = dst + (size_t)m * 65536;
  int byte = n * 256 + k0 * 2;
  byte ^= (n & 7) << 4;
  *(us8*)(base + byte) = vhi;
  *(us8*)(base + 32768 + byte) = vlo;
}

// ================= MFMA machinery =================

__device__ __forceinline__ void stage_w(const char* gsrc, char* lds, int tid) {
  int wave = tid >> 6, lane = tid & 63;
  #pragma unroll
  for (int i = 0; i < 16; ++i) {
    int off = (wave * 16 + i) * 1024;
    __builtin_amdgcn_global_load_lds(
        (const __attribute__((address_space(1))) u32*)(gsrc + off + lane * 16),
        (__attribute__((address_space(3))) u32*)(lds + off), 16, 0, 0);
  }
}

__device__ __forceinline__ void split8(const float vs[8], bh8& hi, bh8& lo) {
  #pragma unroll
  for (int j = 0; j < 8; ++j) {
    u32 u = __builtin_bit_cast(u32, vs[j]);
    float hf = __builtin_bit_cast(float, u & 0xFFFF0000u);
    float l = vs[j] - hf;
    hi[j] = (short)(u >> 16);
    lo[j] = (short)(__builtin_bit_cast(u32, l) >> 16);
  }
}

__device__ __forceinline__ void mk_afrag(const float* rowp, int koff, bh8& hi, bh8& lo) {
  float4 v0 = *(const float4*)(rowp + koff);
  float4 v1 = *(const float4*)(rowp + koff + 4);
  float vs[8] = {v0.x, v0.y, v0.z, v0.w, v1.x, v1.y, v1.z, v1.w};
  split8(vs, hi, lo);
}

// fp32-A split-3 path
__device__ __forceinline__ void mfma_ks(const bh8& ahi, const bh8& alo, const char* Wl,
                                        int ks, int lane, f4 acc[8]) {
  const int koff0 = (lane >> 4) * 8;
  const int k2 = (ks * 32 + koff0) * 2;
  #pragma unroll
  for (int cb = 0; cb < 8; ++cb) {
    int n = cb * 16 + (lane & 15);
    int byte = (n * 256 + k2) ^ ((n & 7) << 4);
    bh8 bhiF = *(const bh8*)(Wl + byte);
    bh8 bloF = *(const bh8*)(Wl + 32768 + byte);
    acc[cb] = __builtin_amdgcn_mfma_f32_16x16x32_bf16(ahi, bhiF, acc[cb], 0, 0, 0);
    acc[cb] = __builtin_amdgcn_mfma_f32_16x16x32_bf16(ahi, bloF, acc[cb], 0, 0, 0);
    acc[cb] = __builtin_amdgcn_mfma_f32_16x16x32_bf16(alo, bhiF, acc[cb], 0, 0, 0);
  }
}

// bf16-A exact path (2 MFMA)
__device__ __forceinline__ void mfma_ks_bf(const bh8& a, const char* Wl,
                                           int ks, int lane, f4 acc[8]) {
  const int koff0 = (lane >> 4) * 8;
  const int k2 = (ks * 32 + koff0) * 2;
  #pragma unroll
  for (int cb = 0; cb < 8; ++cb) {
    int n = cb * 16 + (lane & 15);
    int byte = (n * 256 + k2) ^ ((n & 7) << 4);
    bh8 bhiF = *(const bh8*)(Wl + byte);
    bh8 bloF = *(const bh8*)(Wl + 32768 + byte);
    acc[cb] = __builtin_amdgcn_mfma_f32_16x16x32_bf16(a, bhiF, acc[cb], 0, 0, 0);
    acc[cb] = __builtin_amdgcn_mfma_f32_16x16x32_bf16(a, bloF, acc[cb], 0, 0, 0);
  }
}

__device__ __forceinline__ void mfma_passS(const float* __restrict__ A, size_t astride, int acoff,
                                           const char* Wl, int rbase, int nrows, int lane, f4 acc[8]) {
  int r = rbase + (lane & 15);
  if (r >= nrows) r = nrows - 1;
  const float* rowp = A + (size_t)r * astride + acoff;
  const int koff0 = (lane >> 4) * 8;
  #pragma unroll
  for (int ks = 0; ks < 4; ++ks) {
    bh8 ahi, alo;
    mk_afrag(rowp, ks * 32 + koff0, ahi, alo);
    mfma_ks(ahi, alo, Wl, ks, lane, acc);
  }
}

__device__ __forceinline__ void mfma_passB(const u16* __restrict__ A, size_t astride, int acoff,
                                           const char* Wl, int rbase, int nrows, int lane, f4 acc[8]) {
  int r = rbase + (lane & 15);
  if (r >= nrows) r = nrows - 1;
  const u16* rowp = A + (size_t)r * astride + acoff;
  const int koff0 = (lane >> 4) * 8;
  #pragma unroll
  for (int ks = 0; ks < 4; ++ks) {
    bh8 a = __builtin_bit_cast(bh8, *(const us8*)(rowp + ks * 32 + koff0));
    mfma_ks_bf(a, Wl, ks, lane, acc);
  }
}

struct AFragB { bh8 a[4]; };

__device__ __forceinline__ void load_afragB(const u16* __restrict__ A, size_t astride, int acoff,
                                            int rbase, int nrows, int lane, AFragB& f) {
  int r = rbase + (lane & 15);
  if (r >= nrows) r = nrows - 1;
  const u16* rowp = A + (size_t)r * astride + acoff;
  const int koff0 = (lane >> 4) * 8;
  #pragma unroll
  for (int ks = 0; ks < 4; ++ks)
    f.a[ks] = __builtin_bit_cast(bh8, *(const us8*)(rowp + ks * 32 + koff0));
}

__device__ __forceinline__ void mfma_pass_fragB(const AFragB& f, const char* Wl, int lane, f4 acc[8]) {
  #pragma unroll
  for (int ks = 0; ks < 4; ++ks) mfma_ks_bf(f.a[ks], Wl, ks, lane, acc);
}

// ---- LDS T-tile (64 rows x 128 bf16, XOR-swizzled, aliased into Wl[0:16KB]) ----

__device__ __forceinline__ void acc_to_T(f4 acc[8], const float* bias, float al,
                                         char* Tb, int wave, int lane) {
  const int cidx = lane & 15;
  float b8[8];
  #pragma unroll
  for (int cb = 0; cb < 8; ++cb) b8[cb] = bias[cb * 16 + cidx];
  #pragma unroll
  for (int q = 0; q < 4; ++q) {
    int row = wave * 16 + (lane >> 4) * 4 + q;
    #pragma unroll
    for (int cb = 0; cb < 8; ++cb) {
      float v = acc[cb][q] + b8[cb];
      v = (v >= 0.f) ? v : al * v;
      int byte = (row * 256 + (cb * 16 + cidx) * 2) ^ ((row & 7) << 4);
      *(u16*)(Tb + byte) = tob(v);
    }
  }
}

__device__ __forceinline__ void load_fT(const char* Tb, int wave, int lane, AFragB& f) {
  const int row = wave * 16 + (lane & 15);
  const int koff0 = (lane >> 4) * 8;
  #pragma unroll
  for (int ks = 0; ks < 4; ++ks) {
    int byte = (row * 256 + (ks * 32 + koff0) * 2) ^ ((row & 7) << 4);
    f.a[ks] = __builtin_bit_cast(bh8, *(const us8*)(Tb + byte));
  }
}

// MODE 0: raw; MODE 1: +bias +prelu.  OBF: write bf16 instead of fp32.
template<int MODE, int OBF>
__device__ __forceinline__ void epilogueS(f4 acc[8], const float* bias, const float* alphap,
                                          void* outp, size_t ostride, int ocoff,
                                          int rbase, int nrows, int lane) {
  float al = 0.f;
  if constexpr (MODE == 1) al = *alphap;
  const int cidx = lane & 15;
  int rq = rbase + (lane >> 4) * 4;
  float b8[8];
  if constexpr (MODE == 1) {
    #pragma unroll
    for (int cb = 0; cb < 8; ++cb) b8[cb] = bias[cb * 16 + cidx];
  }
  #pragma unroll
  for (int q = 0; q < 4; ++q) {
    int row = rq + q;
    if (row < nrows) {
      #pragma unroll
      for (int cb = 0; cb < 8; ++cb) {
        float v = acc[cb][q];
        if constexpr (MODE == 1) { v += b8[cb]; v = (v >= 0.f) ? v : al * v; }
        if constexpr (OBF == 1) {
          u16* op = (u16*)outp + (size_t)row * ostride + ocoff + cidx;
          op[cb * 16] = tob(v);
        } else {
          float* op = (float*)outp + (size_t)row * ostride + ocoff + cidx;
          op[cb * 16] = v;
        }
      }
    }
  }
}

#define ACC_ZERO(acc) { _Pragma("unroll") for (int cb = 0; cb < 8; ++cb) acc[cb] = {0.f, 0.f, 0.f, 0.f}; }

// ================= GEMM kernels (per-tile grids) =================

template<int MODE, int OBF, int ABF>
__global__ __launch_bounds__(256, 2) void gemm_halves_k(const void* __restrict__ A1, size_t as1, int ac1, const char* W1, const float* b1_,
                                                        const void* __restrict__ A2, size_t as2, int ac2, const char* W2, const float* b2_,
                                                        const float* __restrict__ alphap,
                                                        void* __restrict__ out, int nrows) {
  __shared__ char Wl[65536];
  const int wave = threadIdx.x >> 6, lane = threadIdx.x & 63;
  const int rbase = blockIdx.x * 64 + wave * 16;
  f4 acc[8];
  stage_w(W1, Wl, threadIdx.x);
  __syncthreads();
  ACC_ZERO(acc);
  if constexpr (ABF) mfma_passB((const u16*)A1, as1, ac1, Wl, rbase, nrows, lane, acc);
  else               mfma_passS((const float*)A1, as1, ac1, Wl, rbase, nrows, lane, acc);
  epilogueS<MODE, OBF>(acc, b1_, alphap, out, 256, 0, rbase, nrows, lane);
  __syncthreads();
  stage_w(W2, Wl, threadIdx.x);
  __syncthreads();
  ACC_ZERO(acc);
  if constexpr (ABF) mfma_passB((const u16*)A2, as2, ac2, Wl, rbase, nrows, lane, acc);
  else               mfma_passS((const float*)A2, as2, ac2, Wl, rbase, nrows, lane, acc);
  epilogueS<MODE, OBF>(acc, b2_, alphap, out, 256, 128, rbase, nrows, lane);
}

// fused hidden + GEMM3 per half: T = prelu(thb_h@We2n_h + be2n_h); tb_h = bf16(T@Wn2e_h1)
__global__ __launch_bounds__(256, 2) void gemm_fuse_hid_k(const u16* __restrict__ thb,
                                                          const char* W20, const float* b20, const char* W21,
                                                          const char* W60, const float* b60, const char* W61,
                                                          const float* __restrict__ alphap,
                                                          u16* __restrict__ tb_out, int nrows) {
  __shared__ char Wl[65536];
  const int wave = threadIdx.x >> 6, lane = threadIdx.x & 63;
  const int rbase = blockIdx.x * 64 + wave * 16;
  const float al = *alphap;
  f4 acc[8];
  AFragB fT;
  #pragma unroll 1
  for (int h = 0; h < 2; ++h) {
    if (h) __syncthreads();
    stage_w(h ? W60 : W20, Wl, threadIdx.x);
    __syncthreads();
    ACC_ZERO(acc);
    mfma_passB(thb, 256, h * 128, Wl, rbase, nrows, lane, acc);
    __syncthreads();
    acc_to_T(acc, h ? b60 : b20, al, Wl, wave, lane);
    __syncthreads();
    load_fT(Wl, wave, lane, fT);
    __syncthreads();
    stage_w(h ? W61 : W21, Wl, threadIdx.x);
    __syncthreads();
    ACC_ZERO(acc);
    mfma_pass_fragB(fT, Wl, lane, acc);
    epilogueS<0, 1>(acc, nullptr, nullptr, tb_out, 256, h * 128, rbase, nrows, lane);
  }
}

// encoder final (A = aggb bf16): n1/n2 fp32 + nn1 fp32 + bf16 side copies n1b/n2b
__global__ __launch_bounds__(256, 2) void enc_final_k(const u16* __restrict__ aggb, const char* W1, const float* b1_,
                                                      const char* W2, const float* b2_,
                                                      const float* __restrict__ alphap,
                                                      float* __restrict__ n1, float* __restrict__ n2,
                                                      u16* __restrict__ n1b, u16* __restrict__ n2b,
                                                      float* __restrict__ nn1, int nrows) {
  __shared__ char Wl[65536];
  const int wave = threadIdx.x >> 6, lane = threadIdx.x & 63;
  const int rbase = blockIdx.x * 64 + wave * 16;
  const int cidx = lane & 15;
  f4 acc[8];
  float al = *alphap;
  #pragma unroll 1
  for (int h = 0; h < 2; ++h) {
    if (h) __syncthreads();
    stage_w(h ? W2 : W1, Wl, threadIdx.x);
    __syncthreads();
    const float* bp = h ? b2_ : b1_;
    float* nout = h ? n2 : n1;
    u16* nbout = h ? n2b : n1b;
    float b8[8];
    #pragma unroll
    for (int cb = 0; cb < 8; ++cb) b8[cb] = bp[cb * 16 + cidx];
    ACC_ZERO(acc);
    mfma_passB(aggb, 256, h * 128, Wl, rbase, nrows, lane, acc);
    int rq = rbase + (lane >> 4) * 4;
    #pragma unroll
    for (int q = 0; q < 4; ++q) {
      int row = rq + q;
      if (row < nrows) {
        float* op = nout + (size_t)row * DD + cidx;
        float* op2 = nn1 + (size_t)row * 256 + h * 128 + cidx;
        u16* op3 = nbout + (size_t)row * DD + cidx;
        #pragma unroll
        for (int cb = 0; cb < 8; ++cb) {
          float v = acc[cb][q] + b8[cb];
          v = (v >= 0.f) ? v : al * v;
          op[cb * 16] = v;
          op2[cb * 16] = v;
          op3[cb * 16] = tob(v);
        }
      }
    }
  }
}

// fully-fused decoder (L0+L1, both d-streams), 2 y-streams via blockIdx.y.
// per s-stream: T = prelu(fx@Wx_s0 + fa@We_s0 + b_s0); out_s = prelu(T@Wx_s1 + fa@We_s1 + b_s1)
__global__ __launch_bounds__(256, 2) void dec_fused_k(const u16* __restrict__ n1b, const u16* __restrict__ n2b,
                                                      const u16* __restrict__ aggb,
                                                      const char* Wx10, const char* We10, const float* b1_0,
                                                      const char* Wx11, const char* We11, const float* b1_1,
                                                      const char* Wx20, const char* We20, const float* b2_0,
                                                      const char* Wx21, const char* We21, const float* b2_1,
                                                      const float* __restrict__ alphap,
                                                      float* __restrict__ x11, float* __restrict__ x22,
                                                      float* __restrict__ x12, float* __restrict__ x21,
                                                      int nrows) {
  __shared__ char Wl[65536];
  const int y = blockIdx.y;
  const u16* xb = y ? n2b : n1b;
  float* od1 = y ? x12 : x11;
  float* od2 = y ? x21 : x22;
  const int acoff = y * 128;
  const int wave = threadIdx.x >> 6, lane = threadIdx.x & 63;
  const int rbase = blockIdx.x * 64 + wave * 16;
  const float al = *alphap;
  AFragB fx, fa, fT;
  load_afragB(xb, DD, 0, rbase, nrows, lane, fx);
  load_afragB(aggb, 256, acoff, rbase, nrows, lane, fa);
  f4 acc[8];
  #pragma unroll 1
  for (int s = 0; s < 2; ++s) {
    const char* Wx0 = s ? Wx20 : Wx10;
    const char* We0 = s ? We20 : We10;
    const char* Wx1 = s ? Wx21 : Wx11;
    const char* We1 = s ? We21 : We11;
    const float* b0 = s ? b2_0 : b1_0;
    const float* b1 = s ? b2_1 : b1_1;
    float* out = s ? od2 : od1;
    if (s) __syncthreads();
    stage_w(Wx0, Wl, threadIdx.x);
    __syncthreads();
    ACC_ZERO(acc);
    mfma_pass_fragB(fx, Wl, lane, acc);
    __syncthreads();
    stage_w(We0, Wl, threadIdx.x);
    __syncthreads();
    mfma_pass_fragB(fa, Wl, lane, acc);
    __syncthreads();
    acc_to_T(acc, b0, al, Wl, wave, lane);
    __syncthreads();
    load_fT(Wl, wave, lane, fT);
    __syncthreads();
    stage_w(Wx1, Wl, threadIdx.x);
    __syncthreads();
    ACC_ZERO(acc);
    mfma_pass_fragB(fT, Wl, lane, acc);
    __syncthreads();
    stage_w(We1, Wl, threadIdx.x);
    __syncthreads();
    mfma_pass_fragB(fa, Wl, lane, acc);
    epilogueS<1, 0>(acc, b1, alphap, out, DD, 0, rbase, nrows, lane);
  }
}

// ================= host =================

extern "C" void kernel_launch(void* const* d_in, const int* in_sizes, int n_in,
                              void* d_out, int out_size, void* d_ws, size_t ws_size,
                              hipStream_t stream) {
  const float* x        = (const float*)d_in[0];
  const float* xx       = (const float*)d_in[1];
  const int*   node_idx = (const int*)d_in[2];
  const int*   edge_idx = (const int*)d_in[3];
  const float* alphap   = (const float*)d_in[6];
  const float* e1_Wn2e  = (const float*)d_in[7];
  const float* e1_bn2e  = (const float*)d_in[8];
  const float* e1_We2n  = (const float*)d_in[9];
  const float* e1_be2n  = (const float*)d_in[10];
  const float* e2_Wn2e  = (const float*)d_in[11];
  const float* e2_bn2e  = (const float*)d_in[12];
  const float* e2_We2n  = (const float*)d_in[13];
  const float* e2_be2n  = (const float*)d_in[14];
  const float* d1_We    = (const float*)d_in[15];
  const float* d1_Wx    = (const float*)d_in[16];
  const float* d1_b     = (const float*)d_in[17];
  const float* d2_We    = (const float*)d_in[18];
  const float* d2_Wx    = (const float*)d_in[19];
  const float* d2_b     = (const float*)d_in[20];

  const int N   = in_sizes[0] / DD;
  const int NNZ = in_sizes[2];
  const int E   = (out_size - 1024 * N) / 256;
  const int NBE = (E + 31) >> 5;
  const int NBN = (N + 31) >> 5;
  const int NCHN = (N + 1023) >> 10;
  const int NCHE = (E + 1023) >> 10;

  // ---- d_out slot map ----
  float* out  = (float*)d_out;
  float* nn1  = out;
  float* n1   = out + (size_t)N * 256;
  float* e1o  = n1 + (size_t)N * DD;
  float* n2   = e1o + (size_t)E * DD;
  float* e2o  = n2 + (size_t)N * DD;
  float* x11  = e2o + (size_t)E * DD;
  float* x21  = x11 + (size_t)N * DD;
  float* x12  = x21 + (size_t)N * DD;
  float* x22  = x12 + (size_t)N * DD;

  // ---- workspace carve ----
  size_t off = 0;
  char* w0 = (char*)d_ws;
  auto carve = [&](size_t bytes) -> void* {
    void* p = (void*)(w0 + off);
    off += (bytes + 255) & ~(size_t)255;
    return p;
  };
  int* cn      = (int*)carve((size_t)N * 4);
  int* ce      = (int*)carve((size_t)E * 4);
  int* offs_n  = (int*)carve((size_t)(N + 1) * 4);
  int* offs_e  = (int*)carve((size_t)(E + 1) * 4);
  int* part    = (int*)carve((size_t)(NCHN + NCHE) * 4);
  int* listN   = (int*)carve((size_t)NNZ * 4);
  int* listE   = (int*)carve((size_t)NNZ * 4);
  float* Dn_inv = (float*)carve((size_t)N * 4);
  float* De_inv = (float*)carve((size_t)E * 4);
  char* Wprep  = (char*)carve((size_t)16 * 65536);
  u16* tb      = (u16*)carve((size_t)N * 256 * 2);    // bf16: GEMM1/GEMM3 out (edge-gather src)
  u16* e_fullb = (u16*)carve((size_t)E * 256 * 2);    // bf16 edge features
  u16* thb     = (u16*)carve((size_t)N * 256 * 2);    // bf16: node-agg L1
  u16* aggb    = (u16*)carve((size_t)N * 256 * 2);    // bf16: shared aggregate
  u16* n1b     = (u16*)carve((size_t)N * DD * 2);     // bf16 copy of n1
  u16* n2b     = (u16*)carve((size_t)N * DD * 2);     // bf16 copy of n2
  int* cur_n   = (int*)carve((size_t)N * 4);
  int* cur_e   = (int*)carve((size_t)E * 4);
  int* cur_be  = (int*)carve((size_t)NBE * 8 * 4);
  int* cur_bn  = (int*)carve((size_t)NBN * 8 * 4);
  u32* SE      = (u32*)carve((size_t)NNZ * 8 * 4);
  u32* SN      = (u32*)carve((size_t)NNZ * 8 * 4);
  const bool staged = off <= ws_size;

  // ---- weight prep table ----
  WPtrs wp;
  wp.p[0] = e1_Wn2e;  wp.p[1] = e1_Wn2e + DD * DD;
  wp.p[2] = e1_We2n;  wp.p[3] = e1_We2n + DD * DD;
  wp.p[4] = e2_Wn2e;  wp.p[5] = e2_Wn2e + DD * DD;
  wp.p[6] = e2_We2n;  wp.p[7] = e2_We2n + DD * DD;
  wp.p[8] = d1_We;    wp.p[9] = d1_We + DD * DD;
  wp.p[10] = d1_Wx;   wp.p[11] = d1_Wx + DD * DD;
  wp.p[12] = d2_We;   wp.p[13] = d2_We + DD * DD;
  wp.p[14] = d2_Wx;   wp.p[15] = d2_Wx + DD * DD;
  auto WP = [&](int i) -> const char* { return Wprep + (size_t)i * 65536; };

  const int thr = 256;
  const int gMax = ((N > E ? N : E) + thr - 1) / thr;
  int gNNZ = (NNZ + thr - 1) / thr; if (gNNZ > 2048) gNNZ = 2048;
  const int NT = (N + 63) / 64;
  const int gGatE = (E + 3) / 4;
  const int gGatN = (N + 3) / 4;

  prep_w_k<<<128, 256, 0, stream>>>(wp, Wprep);
  init_counts_k<<<gMax, thr, 0, stream>>>(cn, ce, N, E);
  hist_k<<<gNNZ, thr, 0, stream>>>(node_idx, edge_idx, cn, ce, NNZ);
  scan_partials_k<<<NCHN + NCHE, 256, 0, stream>>>(cn, ce, part, NCHN, N, NCHE, E);
  scan_chunks_k<<<1, 256, 0, stream>>>(part, NCHN, NCHE);
  scan_apply_k<<<NCHN + NCHE, 256, 0, stream>>>(cn, ce, part, offs_n, offs_e, NCHN, N, NCHE, E);
  fill_deg_k<<<gMax, thr, 0, stream>>>(offs_n, offs_e, Dn_inv, De_inv,
                                       cur_be, cur_bn, cur_n, cur_e, N, E, NBE, NBN);

  if (staged) {
    partition2_k<<<gNNZ, thr, 0, stream>>>(node_idx, edge_idx, cur_be, cur_bn, SE, SN, NNZ);
    scatter2_k<<<NBE, 256, 0, stream>>>(SE, offs_e, cur_be, listE, E);
    scatter2_k<<<NBN, 256, 0, stream>>>(SN, offs_n, cur_bn, listN, N);
  } else {
    fill_nnz_k<<<gNNZ, thr, 0, stream>>>(node_idx, edge_idx, cur_n, cur_e, listN, listE, NNZ);
  }

  // ---- fused dual-encoder (width-256; bf16 data plane) ----
  // L1 in: tb = bf16([x@W0 | xx@W4])   (A fp32 split-3)
  gemm_halves_k<0, 1, 0><<<NT, 256, 0, stream>>>(x, DD, 0, WP(0), nullptr,
                                                 xx, DD, 0, WP(4), nullptr, alphap, tb, N);
  gather_edge_k<0><<<gGatE, 256, 0, stream>>>(tb, offs_e, listE, De_inv, e1_bn2e, e2_bn2e,
                                              alphap, e_fullb, nullptr, nullptr, E);
  gather_node_k<<<gGatN, 256, 0, stream>>>(e_fullb, tb, offs_n, listN, Dn_inv, e1_bn2e, e2_bn2e,
                                           alphap, thb, N);
  // fused: hidden = prelu(thb@We2n_0 + be2n_0); tb = bf16(hidden@Wn2e_1)
  gemm_fuse_hid_k<<<NT, 256, 0, stream>>>(thb, WP(2), e1_be2n, WP(1),
                                          WP(6), e2_be2n, WP(5), alphap, tb, N);
  gather_edge_k<1><<<gGatE, 256, 0, stream>>>(tb, offs_e, listE, De_inv, e1_bn2e + DD, e2_bn2e + DD,
                                              alphap, e_fullb, e1o, e2o, E);
  gather_node_k<<<gGatN, 256, 0, stream>>>(e_fullb, tb, offs_n, listN, Dn_inv, e1_bn2e + DD, e2_bn2e + DD,
                                           alphap, aggb, N);
  enc_final_k<<<NT, 256, 0, stream>>>(aggb, WP(3), e1_be2n + DD, WP(7), e2_be2n + DD,
                                      alphap, n1, n2, n1b, n2b, nn1, N);

  // ---- fully-fused decoders ----
  dim3 gDec(NT, 2);
  dec_fused_k<<<gDec, 256, 0, stream>>>(n1b, n2b, aggb,
                                        WP(10), WP(8), d1_b, WP(11), WP(9), d1_b + DD,
                                        WP(14), WP(12), d2_b, WP(15), WP(13), d2_b + DD,
                                        alphap, x11, x22, x12, x21, N);
}

// Round 11
// 585.895 us; speedup vs baseline: 1.9328x; 1.0399x over previous
//
#include <hip/hip_runtime.h>

#define DD 128

typedef __attribute__((ext_vector_type(8))) short bh8;       // 8 bf16 (as i16 bits)
typedef __attribute__((ext_vector_type(8))) unsigned short us8;
typedef __attribute__((ext_vector_type(4))) unsigned short us4;
typedef __attribute__((ext_vector_type(4))) float f4;
typedef unsigned int u32;
typedef unsigned short u16;

__device__ __forceinline__ u16 tob(float f) {           // fp32 -> bf16 RNE
  u32 u = __builtin_bit_cast(u32, f);
  u += 0x7FFFu + ((u >> 16) & 1u);
  return (u16)(u >> 16);
}
__device__ __forceinline__ float fb(u16 h) { return __builtin_bit_cast(float, (u32)h << 16); }

// ================= CSR build (real edges only; self-loops analytic) =================

__global__ __launch_bounds__(256) void init_counts_k(int* cn, int* ce, int N, int E) {
  int g = blockIdx.x * blockDim.x + threadIdx.x;
  if (g < E) ce[g] = 0;
  if (g < N) cn[g] = 0;
}

// ---- parallel hierarchical exclusive scan (chunks of 1024) ----

__global__ __launch_bounds__(256) void scan_partials_k(const int* __restrict__ cn, const int* __restrict__ ce,
                                                       int* part, int NCHN, int N, int NCHE, int E) {
  __shared__ int red[256];
  int b = blockIdx.x, tid = threadIdx.x;
  const int* cnt = (b < NCHN) ? cn : ce;
  int n = (b < NCHN) ? N : E;
  int base = ((b < NCHN) ? b : (b - NCHN)) << 10;
  int i0 = base + tid * 4;
  int s = 0;
  #pragma unroll
  for (int j = 0; j < 4; ++j) { int i = i0 + j; if (i < n) s += cnt[i]; }
  red[tid] = s; __syncthreads();
  for (int off = 128; off > 0; off >>= 1) {
    if (tid < off) red[tid] += red[tid + off];
    __syncthreads();
  }
  if (tid == 0) part[b] = red[0];
}

__device__ __forceinline__ int blk_excl_scan(int s, int tid, int* sums) {
  sums[tid] = s; __syncthreads();
  for (int off = 1; off < 256; off <<= 1) {
    int t = (tid >= off) ? sums[tid - off] : 0;
    __syncthreads();
    sums[tid] += t;
    __syncthreads();
  }
  int ex = sums[tid] - s;
  __syncthreads();
  return ex;
}

__global__ __launch_bounds__(256) void scan_chunks_k(int* part, int NCHN, int NCHE) {
  __shared__ int sums[256];
  int tid = threadIdx.x;
  {
    int v = (tid < NCHN) ? part[tid] : 0;       // NCHN <= 256
    int ex = blk_excl_scan(v, tid, sums);
    if (tid < NCHN) part[tid] = ex;
  }
  __syncthreads();
  {
    int v = (tid < NCHE) ? part[NCHN + tid] : 0;
    int ex = blk_excl_scan(v, tid, sums);
    if (tid < NCHE) part[NCHN + tid] = ex;
  }
}

__global__ __launch_bounds__(256) void scan_apply_k(const int* __restrict__ cn, const int* __restrict__ ce,
                                                    const int* __restrict__ part,
                                                    int* offs_n, int* offs_e,
                                                    int NCHN, int N, int NCHE, int E) {
  __shared__ int sums[256];
  int b = blockIdx.x, tid = threadIdx.x;
  const int* cnt = (b < NCHN) ? cn : ce;
  int* offs = (b < NCHN) ? offs_n : offs_e;
  int n = (b < NCHN) ? N : E;
  int base = ((b < NCHN) ? b : (b - NCHN)) << 10;
  int i0 = base + tid * 4;
  int v[4]; int s = 0;
  #pragma unroll
  for (int j = 0; j < 4; ++j) { int i = i0 + j; int t = (i < n) ? cnt[i] : 0; v[j] = t; s += t; }
  int ex = blk_excl_scan(s, tid, sums);
  int run = part[b] + ex;
  #pragma unroll
  for (int j = 0; j < 4; ++j) { int i = i0 + j; if (i < n) offs[i] = run; run += v[j]; }
  if (tid == 255 && base + 1024 >= n) offs[n] = run;
}

__global__ __launch_bounds__(256) void fill_deg_k(const int* __restrict__ offs_n, const int* __restrict__ offs_e,
                                                  float* Dn_inv, float* De_inv,
                                                  int* cur_be, int* cur_bn, int* cur_n, int* cur_e,
                                                  int N, int E, int NBE, int NBN) {
  int g = blockIdx.x * blockDim.x + threadIdx.x;
  if (g < E) {
    int b = offs_e[g], e = offs_e[g + 1];
    De_inv[g] = (e > b) ? 1.0f / (float)(e - b) : 0.0f;
    cur_e[g] = b;
  }
  if (g < N) {
    int b = offs_n[g], e = offs_n[g + 1];
    Dn_inv[g] = 1.0f / (float)(e - b + 1);   // +1 self loop
    cur_n[g] = b;
  }
  if (g < NBE) {
    int r1 = (g + 1) * 32; if (r1 > E) r1 = E;
    int o0 = offs_e[g * 32], o1 = offs_e[r1];
    int C = o1 - o0, base = 8 * o0;
    #pragma unroll
    for (int k = 0; k < 8; ++k) cur_be[g * 8 + k] = base + k * C;
  }
  if (g < NBN) {
    int r1 = (g + 1) * 32; if (r1 > N) r1 = N;
    int o0 = offs_n[g * 32], o1 = offs_n[r1];
    int C = o1 - o0, base = 8 * o0;
    #pragma unroll
    for (int k = 0; k < 8; ++k) cur_bn[g * 8 + k] = base + k * C;
  }
}

__global__ __launch_bounds__(256) void partition2_k(const int* __restrict__ ni, const int* __restrict__ ei,
                                                    int* cur_be, int* cur_bn,
                                                    u32* __restrict__ SE, u32* __restrict__ SN, int nnz) {
  int xcd;
  asm volatile("s_getreg_b32 %0, hwreg(HW_REG_XCC_ID)" : "=s"(xcd));
  xcd &= 7;
  int stride = gridDim.x * blockDim.x;
  for (int j = blockIdx.x * blockDim.x + threadIdx.x; j < nnz; j += stride) {
    int n = ni[j], e = ei[j];
    int pe = atomicAdd(&cur_be[(e >> 5) * 8 + xcd], 1);
    SE[pe] = ((u32)(e & 31) << 17) | (u32)n;
    int pn = atomicAdd(&cur_bn[(n >> 5) * 8 + xcd], 1);
    SN[pn] = ((u32)(n & 31) << 17) | (u32)e;
  }
}

__device__ __forceinline__ void scatter_body(const u32* __restrict__ S, const int* __restrict__ offs,
                                             const int* __restrict__ cur_b,
                                             int* __restrict__ list, int nRows, int b, int tid, int* cur) {
  const int i0 = b << 5;
  if (tid < 32) {
    int row = i0 + tid;
    cur[tid] = (row < nRows) ? offs[row] : 0;
  }
  __syncthreads();
  int r1 = i0 + 32; if (r1 > nRows) r1 = nRows;
  const int o0 = offs[i0];
  const int C = offs[r1] - o0;
  #pragma unroll 1
  for (int k = 0; k < 8; ++k) {
    int sbeg = 8 * o0 + k * C;
    int send = cur_b[b * 8 + k];
    for (int i = sbeg + tid; i < send; i += 256) {
      u32 v = S[i];
      int pos = atomicAdd(&cur[v >> 17], 1);
      list[pos] = (int)(v & 0x1FFFFu);
    }
  }
}

// merged edges+nodes scatter (block-range dispatch)
__global__ __launch_bounds__(256) void scatter_both_k(const u32* SE, const int* offs_e, const int* cur_be,
                                                      int* listE, int E, int NBE,
                                                      const u32* SN, const int* offs_n, const int* cur_bn,
                                                      int* listN, int N) {
  __shared__ int cur[32];
  int b = blockIdx.x, tid = threadIdx.x;
  if (b < NBE) scatter_body(SE, offs_e, cur_be, listE, E, b, tid, cur);
  else         scatter_body(SN, offs_n, cur_bn, listN, N, b - NBE, tid, cur);
}

// ================= gathers (width 256, bf16, split-wave: 16B/lane, 2 members in flight/half) =================

__device__ __forceinline__ void acc8(float a[8], us8 v) {
  #pragma unroll
  for (int j = 0; j < 8; ++j) a[j] += fb(v[j]);
}

template<int SPLIT>
__global__ __launch_bounds__(256) void gather_edge_k(const u16* __restrict__ srcb,
                                                     const int* __restrict__ offs, const int* __restrict__ list,
                                                     const float* __restrict__ De_inv,
                                                     const float* __restrict__ b1, const float* __restrict__ b2,
                                                     const float* __restrict__ alphap,
                                                     u16* __restrict__ e_fullb,
                                                     float* __restrict__ d2a, float* __restrict__ d2b, int E) {
  const int wave = threadIdx.x >> 6, lane = threadIdx.x & 63;
  const int row = blockIdx.x * 4 + wave;
  if (row >= E) return;
  const int half = lane >> 5, cl = lane & 31;
  const int c8 = cl * 8;
  const int beg = offs[row], end = offs[row + 1];
  float a0[8] = {0,0,0,0,0,0,0,0}, a1[8] = {0,0,0,0,0,0,0,0};
  int i = beg + half;
  for (; i + 2 < end; i += 4) {
    us8 v0 = *(const us8*)&srcb[(size_t)list[i] * 256 + c8];
    us8 v1 = *(const us8*)&srcb[(size_t)list[i + 2] * 256 + c8];
    acc8(a0, v0); acc8(a1, v1);
  }
  if (i < end) acc8(a0, *(const us8*)&srcb[(size_t)list[i] * 256 + c8]);
  float s[8];
  #pragma unroll
  for (int j = 0; j < 8; ++j) s[j] = a0[j] + a1[j];
  #pragma unroll
  for (int j = 0; j < 8; ++j) s[j] += __shfl_xor(s[j], 32);
  if (half == 0) {
    float sc = De_inv[row];
    const float* bp = (c8 < 128) ? (b1 + c8) : (b2 + c8 - 128);
    float4 bt0 = *(const float4*)bp;
    float4 bt1 = *(const float4*)(bp + 4);
    float bb[8] = {bt0.x, bt0.y, bt0.z, bt0.w, bt1.x, bt1.y, bt1.z, bt1.w};
    float al = *alphap;
    us8 ob;
    float ov[8];
    #pragma unroll
    for (int j = 0; j < 8; ++j) {
      float v = sc * s[j] + bb[j];
      v = (v >= 0.f) ? v : al * v;
      ov[j] = v; ob[j] = tob(v);
    }
    *(us8*)&e_fullb[(size_t)row * 256 + c8] = ob;
    if constexpr (SPLIT == 1) {
      float* dp = (c8 < 128) ? &d2a[(size_t)row * DD + c8] : &d2b[(size_t)row * DD + c8 - 128];
      float4 w0 = {ov[0], ov[1], ov[2], ov[3]};
      float4 w1 = {ov[4], ov[5], ov[6], ov[7]};
      *(float4*)dp = w0;
      *(float4*)(dp + 4) = w1;
    }
  }
}

__global__ __launch_bounds__(256) void gather_node_k(const u16* __restrict__ e_fullb,
                                                     const u16* __restrict__ tb,
                                                     const int* __restrict__ offs, const int* __restrict__ list,
                                                     const float* __restrict__ Dn_inv,
                                                     const float* __restrict__ b1, const float* __restrict__ b2,
                                                     const float* __restrict__ alphap,
                                                     u16* __restrict__ dstb, int N) {
  const int wave = threadIdx.x >> 6, lane = threadIdx.x & 63;
  const int row = blockIdx.x * 4 + wave;
  if (row >= N) return;
  const int half = lane >> 5, cl = lane & 31;
  const int c8 = cl * 8;
  const int beg = offs[row], end = offs[row + 1];
  float a0[8] = {0,0,0,0,0,0,0,0}, a1[8] = {0,0,0,0,0,0,0,0};
  int i = beg + half;
  for (; i + 2 < end; i += 4) {
    us8 v0 = *(const us8*)&e_fullb[(size_t)list[i] * 256 + c8];
    us8 v1 = *(const us8*)&e_fullb[(size_t)list[i + 2] * 256 + c8];
    acc8(a0, v0); acc8(a1, v1);
  }
  if (i < end) acc8(a0, *(const us8*)&e_fullb[(size_t)list[i] * 256 + c8]);
  float s[8];
  #pragma unroll
  for (int j = 0; j < 8; ++j) s[j] = a0[j] + a1[j];
  #pragma unroll
  for (int j = 0; j < 8; ++j) s[j] += __shfl_xor(s[j], 32);
  if (half == 0) {
    us8 tv = *(const us8*)&tb[(size_t)row * 256 + c8];
    const float* bp = (c8 < 128) ? (b1 + c8) : (b2 + c8 - 128);
    float4 bt0 = *(const float4*)bp;
    float4 bt1 = *(const float4*)(bp + 4);
    float bb[8] = {bt0.x, bt0.y, bt0.z, bt0.w, bt1.x, bt1.y, bt1.z, bt1.w};
    float al = *alphap;
    float sc = Dn_inv[row];
    us8 ob;
    #pragma unroll
    for (int j = 0; j < 8; ++j) {
      float sv = fb(tv[j]) + bb[j];
      sv = (sv >= 0.f) ? sv : al * sv;
      ob[j] = tob(sc * (sv + s[j]));
    }
    *(us8*)&dstb[(size_t)row * 256 + c8] = ob;
  }
}

// ================= weight prep =================

struct WPtrs { const float* p[16]; };

__global__ __launch_bounds__(256) void prep_w_k(WPtrs wp, char* dst) {
  int m = blockIdx.x >> 3, s = blockIdx.x & 7;
  const float* W = wp.p[m];
  int t = threadIdx.x;
  int n = t & 127;
  int k0 = s * 16 + (t >> 7) * 8;
  us8 vhi, vlo;
  #pragma unroll
  for (int j = 0; j < 8; ++j) {
    float x = W[(size_t)(k0 + j) * DD + n];
    u32 ux = __builtin_bit_cast(u32, x);
    float hf = __builtin_bit_cast(float, ux & 0xFFFF0000u);
    float l = x - hf;
    vhi[j] = (u16)(ux >> 16);
    vlo[j] = (u16)(__builtin_bit_cast(u32, l) >> 16);
  }
  char* base = dst + (size_t)m * 65536;
  int byte = n * 256 + k0 * 2;
  byte ^= (n & 7) << 4;
  *(us8*)(base + byte) = vhi;
  *(us8*)(base + 32768 + byte) = vlo;
}

// ================= MFMA machinery =================

__device__ __forceinline__ void stage_w(const char* gsrc, char* lds, int tid) {
  int wave = tid >> 6, lane = tid & 63;
  #pragma unroll
  for (int i = 0; i < 16; ++i) {
    int off = (wave * 16 + i) * 1024;
    __builtin_amdgcn_global_load_lds(
        (const __attribute__((address_space(1))) u32*)(gsrc + off + lane * 16),
        (__attribute__((address_space(3))) u32*)(lds + off), 16, 0, 0);
  }
}

__device__ __forceinline__ void split8(const float vs[8], bh8& hi, bh8& lo) {
  #pragma unroll
  for (int j = 0; j < 8; ++j) {
    u32 u = __builtin_bit_cast(u32, vs[j]);
    float hf = __builtin_bit_cast(float, u & 0xFFFF0000u);
    float l = vs[j] - hf;
    hi[j] = (short)(u >> 16);
    lo[j] = (short)(__builtin_bit_cast(u32, l) >> 16);
  }
}

__device__ __forceinline__ void mk_afrag(const float* rowp, int koff, bh8& hi, bh8& lo) {
  float4 v0 = *(const float4*)(rowp + koff);
  float4 v1 = *(const float4*)(rowp + koff + 4);
  float vs[8] = {v0.x, v0.y, v0.z, v0.w, v1.x, v1.y, v1.z, v1.w};
  split8(vs, hi, lo);
}

// fp32-A split-3 path
__device__ __forceinline__ void mfma_ks(const bh8& ahi, const bh8& alo, const char* Wl,
                                        int ks, int lane, f4 acc[8]) {
  const int koff0 = (lane >> 4) * 8;
  const int k2 = (ks * 32 + koff0) * 2;
  #pragma unroll
  for (int cb = 0; cb < 8; ++cb) {
    int n = cb * 16 + (lane & 15);
    int byte = (n * 256 + k2) ^ ((n & 7) << 4);
    bh8 bhiF = *(const bh8*)(Wl + byte);
    bh8 bloF = *(const bh8*)(Wl + 32768 + byte);
    acc[cb] = __builtin_amdgcn_mfma_f32_16x16x32_bf16(ahi, bhiF, acc[cb], 0, 0, 0);
    acc[cb] = __builtin_amdgcn_mfma_f32_16x16x32_bf16(ahi, bloF, acc[cb], 0, 0, 0);
    acc[cb] = __builtin_amdgcn_mfma_f32_16x16x32_bf16(alo, bhiF, acc[cb], 0, 0, 0);
  }
}

// bf16-A exact path (2 MFMA)
__device__ __forceinline__ void mfma_ks_bf(const bh8& a, const char* Wl,
                                           int ks, int lane, f4 acc[8]) {
  const int koff0 = (lane >> 4) * 8;
  const int k2 = (ks * 32 + koff0) * 2;
  #pragma unroll
  for (int cb = 0; cb < 8; ++cb) {
    int n = cb * 16 + (lane & 15);
    int byte = (n * 256 + k2) ^ ((n & 7) << 4);
    bh8 bhiF = *(const bh8*)(Wl + byte);
    bh8 bloF = *(const bh8*)(Wl + 32768 + byte);
    acc[cb] = __builtin_amdgcn_mfma_f32_16x16x32_bf16(a, bhiF, acc[cb], 0, 0, 0);
    acc[cb] = __builtin_amdgcn_mfma_f32_16x16x32_bf16(a, bloF, acc[cb], 0, 0, 0);
  }
}

__device__ __forceinline__ void mfma_passS(const float* __restrict__ A, size_t astride, int acoff,
                                           const char* Wl, int rbase, int nrows, int lane, f4 acc[8]) {
  int r = rbase + (lane & 15);
  if (r >= nrows) r = nrows - 1;
  const float* rowp = A + (size_t)r * astride + acoff;
  const int koff0 = (lane >> 4) * 8;
  #pragma unroll
  for (int ks = 0; ks < 4; ++ks) {
    bh8 ahi, alo;
    mk_afrag(rowp, ks * 32 + koff0, ahi, alo);
    mfma_ks(ahi, alo, Wl, ks, lane, acc);
  }
}

__device__ __forceinline__ void mfma_passB(const u16* __restrict__ A, size_t astride, int acoff,
                                           const char* Wl, int rbase, int nrows, int lane, f4 acc[8]) {
  int r = rbase + (lane & 15);
  if (r >= nrows) r = nrows - 1;
  const u16* rowp = A + (size_t)r * astride + acoff;
  const int koff0 = (lane >> 4) * 8;
  #pragma unroll
  for (int ks = 0; ks < 4; ++ks) {
    bh8 a = __builtin_bit_cast(bh8, *(const us8*)(rowp + ks * 32 + koff0));
    mfma_ks_bf(a, Wl, ks, lane, acc);
  }
}

struct AFragB { bh8 a[4]; };

__device__ __forceinline__ void load_afragB(const u16* __restrict__ A, size_t astride, int acoff,
                                            int rbase, int nrows, int lane, AFragB& f) {
  int r = rbase + (lane & 15);
  if (r >= nrows) r = nrows - 1;
  const u16* rowp = A + (size_t)r * astride + acoff;
  const int koff0 = (lane >> 4) * 8;
  #pragma unroll
  for (int ks = 0; ks < 4; ++ks)
    f.a[ks] = __builtin_bit_cast(bh8, *(const us8*)(rowp + ks * 32 + koff0));
}

__device__ __forceinline__ void mfma_pass_fragB(const AFragB& f, const char* Wl, int lane, f4 acc[8]) {
  #pragma unroll
  for (int ks = 0; ks < 4; ++ks) mfma_ks_bf(f.a[ks], Wl, ks, lane, acc);
}

// ---- LDS T-tile (64 rows x 128 bf16, XOR-swizzled, aliased into Wl[0:16KB]) ----

__device__ __forceinline__ void acc_to_T(f4 acc[8], const float* bias, float al,
                                         char* Tb, int wave, int lane) {
  const int cidx = lane & 15;
  float b8[8];
  #pragma unroll
  for (int cb = 0; cb < 8; ++cb) b8[cb] = bias[cb * 16 + cidx];
  #pragma unroll
  for (int q = 0; q < 4; ++q) {
    int row = wave * 16 + (lane >> 4) * 4 + q;
    #pragma unroll
    for (int cb = 0; cb < 8; ++cb) {
      float v = acc[cb][q] + b8[cb];
      v = (v >= 0.f) ? v : al * v;
      int byte = (row * 256 + (cb * 16 + cidx) * 2) ^ ((row & 7) << 4);
      *(u16*)(Tb + byte) = tob(v);
    }
  }
}

__device__ __forceinline__ void load_fT(const char* Tb, int wave, int lane, AFragB& f) {
  const int row = wave * 16 + (lane & 15);
  const int koff0 = (lane >> 4) * 8;
  #pragma unroll
  for (int ks = 0; ks < 4; ++ks) {
    int byte = (row * 256 + (ks * 32 + koff0) * 2) ^ ((row & 7) << 4);
    f.a[ks] = __builtin_bit_cast(bh8, *(const us8*)(Tb + byte));
  }
}

// MODE 0: raw; MODE 1: +bias +prelu.  OBF: write bf16 instead of fp32.
template<int MODE, int OBF>
__device__ __forceinline__ void epilogueS(f4 acc[8], const float* bias, const float* alphap,
                                          void* outp, size_t ostride, int ocoff,
                                          int rbase, int nrows, int lane) {
  float al = 0.f;
  if constexpr (MODE == 1) al = *alphap;
  const int cidx = lane & 15;
  int rq = rbase + (lane >> 4) * 4;
  float b8[8];
  if constexpr (MODE == 1) {
    #pragma unroll
    for (int cb = 0; cb < 8; ++cb) b8[cb] = bias[cb * 16 + cidx];
  }
  #pragma unroll
  for (int q = 0; q < 4; ++q) {
    int row = rq + q;
    if (row < nrows) {
      #pragma unroll
      for (int cb = 0; cb < 8; ++cb) {
        float v = acc[cb][q];
        if constexpr (MODE == 1) { v += b8[cb]; v = (v >= 0.f) ? v : al * v; }
        if constexpr (OBF == 1) {
          u16* op = (u16*)outp + (size_t)row * ostride + ocoff + cidx;
          op[cb * 16] = tob(v);
        } else {
          float* op = (float*)outp + (size_t)row * ostride + ocoff + cidx;
          op[cb * 16] = v;
        }
      }
    }
  }
}

#define ACC_ZERO(acc) { _Pragma("unroll") for (int cb = 0; cb < 8; ++cb) acc[cb] = {0.f, 0.f, 0.f, 0.f}; }

// ================= GEMM kernels (per-tile grids) =================

// combo: blocks [0,NT) = GEMM1 (x@W0 | xx@W4 -> tb bf16, fp32-A split-3);
//        blocks [NT, NT+HB) = histogram (grid-stride)
__global__ __launch_bounds__(256, 2) void combo1_k(const float* __restrict__ x, const char* W0,
                                                   const float* __restrict__ xx, const char* W4,
                                                   u16* __restrict__ tb, int nrows, int NT,
                                                   const int* __restrict__ ni, const int* __restrict__ ei,
                                                   int* cn, int* ce, int nnz) {
  __shared__ char Wl[65536];
  if ((int)blockIdx.x < NT) {
    const int wave = threadIdx.x >> 6, lane = threadIdx.x & 63;
    const int rbase = blockIdx.x * 64 + wave * 16;
    f4 acc[8];
    stage_w(W0, Wl, threadIdx.x);
    __syncthreads();
    ACC_ZERO(acc);
    mfma_passS(x, DD, 0, Wl, rbase, nrows, lane, acc);
    epilogueS<0, 1>(acc, nullptr, nullptr, tb, 256, 0, rbase, nrows, lane);
    __syncthreads();
    stage_w(W4, Wl, threadIdx.x);
    __syncthreads();
    ACC_ZERO(acc);
    mfma_passS(xx, DD, 0, Wl, rbase, nrows, lane, acc);
    epilogueS<0, 1>(acc, nullptr, nullptr, tb, 256, 128, rbase, nrows, lane);
  } else {
    int nb = gridDim.x - NT;
    int stride = nb * 256;
    for (int j = ((int)blockIdx.x - NT) * 256 + (int)threadIdx.x; j < nnz; j += stride) {
      atomicAdd(&cn[ni[j]], 1);
      atomicAdd(&ce[ei[j]], 1);
    }
  }
}

// fused hidden + GEMM3 per half: T = prelu(thb_h@We2n_h + be2n_h); tb_h = bf16(T@Wn2e_h1)
__global__ __launch_bounds__(256, 2) void gemm_fuse_hid_k(const u16* __restrict__ thb,
                                                          const char* W20, const float* b20, const char* W21,
                                                          const char* W60, const float* b60, const char* W61,
                                                          const float* __restrict__ alphap,
                                                          u16* __restrict__ tb_out, int nrows) {
  __shared__ char Wl[65536];
  const int wave = threadIdx.x >> 6, lane = threadIdx.x & 63;
  const int rbase = blockIdx.x * 64 + wave * 16;
  const float al = *alphap;
  f4 acc[8];
  AFragB fT;
  #pragma unroll 1
  for (int h = 0; h < 2; ++h) {
    if (h) __syncthreads();
    stage_w(h ? W60 : W20, Wl, threadIdx.x);
    __syncthreads();
    ACC_ZERO(acc);
    mfma_passB(thb, 256, h * 128, Wl, rbase, nrows, lane, acc);
    __syncthreads();
    acc_to_T(acc, h ? b60 : b20, al, Wl, wave, lane);
    __syncthreads();
    load_fT(Wl, wave, lane, fT);
    __syncthreads();
    stage_w(h ? W61 : W21, Wl, threadIdx.x);
    __syncthreads();
    ACC_ZERO(acc);
    mfma_pass_fragB(fT, Wl, lane, acc);
    epilogueS<0, 1>(acc, nullptr, nullptr, tb_out, 256, h * 128, rbase, nrows, lane);
  }
}

// encoder final (A = aggb bf16): n1/n2 fp32 + nn1 fp32 + bf16 side copies n1b/n2b
__global__ __launch_bounds__(256, 2) void enc_final_k(const u16* __restrict__ aggb, const char* W1, const float* b1_,
                                                      const char* W2, const float* b2_,
                                                      const float* __restrict__ alphap,
                                                      float* __restrict__ n1, float* __restrict__ n2,
                                                      u16* __restrict__ n1b, u16* __restrict__ n2b,
                                                      float* __restrict__ nn1, int nrows) {
  __shared__ char Wl[65536];
  const int wave = threadIdx.x >> 6, lane = threadIdx.x & 63;
  const int rbase = blockIdx.x * 64 + wave * 16;
  const int cidx = lane & 15;
  f4 acc[8];
  float al = *alphap;
  #pragma unroll 1
  for (int h = 0; h < 2; ++h) {
    if (h) __syncthreads();
    stage_w(h ? W2 : W1, Wl, threadIdx.x);
    __syncthreads();
    const float* bp = h ? b2_ : b1_;
    float* nout = h ? n2 : n1;
    u16* nbout = h ? n2b : n1b;
    float b8[8];
    #pragma unroll
    for (int cb = 0; cb < 8; ++cb) b8[cb] = bp[cb * 16 + cidx];
    ACC_ZERO(acc);
    mfma_passB(aggb, 256, h * 128, Wl, rbase, nrows, lane, acc);
    int rq = rbase + (lane >> 4) * 4;
    #pragma unroll
    for (int q = 0; q < 4; ++q) {
      int row = rq + q;
      if (row < nrows) {
        float* op = nout + (size_t)row * DD + cidx;
        float* op2 = nn1 + (size_t)row * 256 + h * 128 + cidx;
        u16* op3 = nbout + (size_t)row * DD + cidx;
        #pragma unroll
        for (int cb = 0; cb < 8; ++cb) {
          float v = acc[cb][q] + b8[cb];
          v = (v >= 0.f) ? v : al * v;
          op[cb * 16] = v;
          op2[cb * 16] = v;
          op3[cb * 16] = tob(v);
        }
      }
    }
  }
}

// fully-fused decoder (L0+L1, both d-streams), 2 y-streams via blockIdx.y.
__global__ __launch_bounds__(256, 2) void dec_fused_k(const u16* __restrict__ n1b, const u16* __restrict__ n2b,
                                                      const u16* __restrict__ aggb,
                                                      const char* Wx10, const char* We10, const float* b1_0,
                                                      const char* Wx11, const char* We11, const float* b1_1,
                                                      const char* Wx20, const char* We20, const float* b2_0,
                                                      const char* Wx21, const char* We21, const float* b2_1,
                                                      const float* __restrict__ alphap,
                                                      float* __restrict__ x11, float* __restrict__ x22,
                                                      float* __restrict__ x12, float* __restrict__ x21,
                                                      int nrows) {
  __shared__ char Wl[65536];
  const int y = blockIdx.y;
  const u16* xb = y ? n2b : n1b;
  float* od1 = y ? x12 : x11;
  float* od2 = y ? x21 : x22;
  const int acoff = y * 128;
  const int wave = threadIdx.x >> 6, lane = threadIdx.x & 63;
  const int rbase = blockIdx.x * 64 + wave * 16;
  const float al = *alphap;
  AFragB fx, fa, fT;
  load_afragB(xb, DD, 0, rbase, nrows, lane, fx);
  load_afragB(aggb, 256, acoff, rbase, nrows, lane, fa);
  f4 acc[8];
  #pragma unroll 1
  for (int s = 0; s < 2; ++s) {
    const char* Wx0 = s ? Wx20 : Wx10;
    const char* We0 = s ? We20 : We10;
    const char* Wx1 = s ? Wx21 : Wx11;
    const char* We1 = s ? We21 : We11;
    const float* b0 = s ? b2_0 : b1_0;
    const float* b1 = s ? b2_1 : b1_1;
    float* out = s ? od2 : od1;
    if (s) __syncthreads();
    stage_w(Wx0, Wl, threadIdx.x);
    __syncthreads();
    ACC_ZERO(acc);
    mfma_pass_fragB(fx, Wl, lane, acc);
    __syncthreads();
    stage_w(We0, Wl, threadIdx.x);
    __syncthreads();
    mfma_pass_fragB(fa, Wl, lane, acc);
    __syncthreads();
    acc_to_T(acc, b0, al, Wl, wave, lane);
    __syncthreads();
    load_fT(Wl, wave, lane, fT);
    __syncthreads();
    stage_w(Wx1, Wl, threadIdx.x);
    __syncthreads();
    ACC_ZERO(acc);
    mfma_pass_fragB(fT, Wl, lane, acc);
    __syncthreads();
    stage_w(We1, Wl, threadIdx.x);
    __syncthreads();
    mfma_pass_fragB(fa, Wl, lane, acc);
    epilogueS<1, 0>(acc, b1, alphap, out, DD, 0, rbase, nrows, lane);
  }
}

// ================= host =================

extern "C" void kernel_launch(void* const* d_in, const int* in_sizes, int n_in,
                              void* d_out, int out_size, void* d_ws, size_t ws_size,
                              hipStream_t stream) {
  const float* x        = (const float*)d_in[0];
  const float* xx       = (const float*)d_in[1];
  const int*   node_idx = (const int*)d_in[2];
  const int*   edge_idx = (const int*)d_in[3];
  const float* alphap   = (const float*)d_in[6];
  const float* e1_Wn2e  = (const float*)d_in[7];
  const float* e1_bn2e  = (const float*)d_in[8];
  const float* e1_We2n  = (const float*)d_in[9];
  const float* e1_be2n  = (const float*)d_in[10];
  const float* e2_Wn2e  = (const float*)d_in[11];
  const float* e2_bn2e  = (const float*)d_in[12];
  const float* e2_We2n  = (const float*)d_in[13];
  const float* e2_be2n  = (const float*)d_in[14];
  const float* d1_We    = (const float*)d_in[15];
  const float* d1_Wx    = (const float*)d_in[16];
  const float* d1_b     = (const float*)d_in[17];
  const float* d2_We    = (const float*)d_in[18];
  const float* d2_Wx    = (const float*)d_in[19];
  const float* d2_b     = (const float*)d_in[20];

  const int N   = in_sizes[0] / DD;
  const int NNZ = in_sizes[2];
  const int E   = (out_size - 1024 * N) / 256;
  const int NBE = (E + 31) >> 5;
  const int NBN = (N + 31) >> 5;
  const int NCHN = (N + 1023) >> 10;
  const int NCHE = (E + 1023) >> 10;

  // ---- d_out slot map ----
  float* out  = (float*)d_out;
  float* nn1  = out;
  float* n1   = out + (size_t)N * 256;
  float* e1o  = n1 + (size_t)N * DD;
  float* n2   = e1o + (size_t)E * DD;
  float* e2o  = n2 + (size_t)N * DD;
  float* x11  = e2o + (size_t)E * DD;
  float* x21  = x11 + (size_t)N * DD;
  float* x12  = x21 + (size_t)N * DD;
  float* x22  = x12 + (size_t)N * DD;

  // ---- workspace carve ----
  size_t off = 0;
  char* w0 = (char*)d_ws;
  auto carve = [&](size_t bytes) -> void* {
    void* p = (void*)(w0 + off);
    off += (bytes + 255) & ~(size_t)255;
    return p;
  };
  int* cn      = (int*)carve((size_t)N * 4);
  int* ce      = (int*)carve((size_t)E * 4);
  int* offs_n  = (int*)carve((size_t)(N + 1) * 4);
  int* offs_e  = (int*)carve((size_t)(E + 1) * 4);
  int* part    = (int*)carve((size_t)(NCHN + NCHE) * 4);
  int* listN   = (int*)carve((size_t)NNZ * 4);
  int* listE   = (int*)carve((size_t)NNZ * 4);
  float* Dn_inv = (float*)carve((size_t)N * 4);
  float* De_inv = (float*)carve((size_t)E * 4);
  char* Wprep  = (char*)carve((size_t)16 * 65536);
  u16* tb      = (u16*)carve((size_t)N * 256 * 2);
  u16* e_fullb = (u16*)carve((size_t)E * 256 * 2);
  u16* thb     = (u16*)carve((size_t)N * 256 * 2);
  u16* aggb    = (u16*)carve((size_t)N * 256 * 2);
  u16* n1b     = (u16*)carve((size_t)N * DD * 2);
  u16* n2b     = (u16*)carve((size_t)N * DD * 2);
  int* cur_n   = (int*)carve((size_t)N * 4);
  int* cur_e   = (int*)carve((size_t)E * 4);
  int* cur_be  = (int*)carve((size_t)NBE * 8 * 4);
  int* cur_bn  = (int*)carve((size_t)NBN * 8 * 4);
  u32* SE      = (u32*)carve((size_t)NNZ * 8 * 4);
  u32* SN      = (u32*)carve((size_t)NNZ * 8 * 4);
  (void)cur_n; (void)cur_e;

  // ---- weight prep table ----
  WPtrs wp;
  wp.p[0] = e1_Wn2e;  wp.p[1] = e1_Wn2e + DD * DD;
  wp.p[2] = e1_We2n;  wp.p[3] = e1_We2n + DD * DD;
  wp.p[4] = e2_Wn2e;  wp.p[5] = e2_Wn2e + DD * DD;
  wp.p[6] = e2_We2n;  wp.p[7] = e2_We2n + DD * DD;
  wp.p[8] = d1_We;    wp.p[9] = d1_We + DD * DD;
  wp.p[10] = d1_Wx;   wp.p[11] = d1_Wx + DD * DD;
  wp.p[12] = d2_We;   wp.p[13] = d2_We + DD * DD;
  wp.p[14] = d2_Wx;   wp.p[15] = d2_Wx + DD * DD;
  auto WP = [&](int i) -> const char* { return Wprep + (size_t)i * 65536; };

  const int thr = 256;
  const int gMax = ((N > E ? N : E) + thr - 1) / thr;
  const int NT = (N + 63) / 64;
  const int HB = 512;                    // histogram blocks co-running with GEMM1
  int gNNZ = (NNZ + thr - 1) / thr; if (gNNZ > 2048) gNNZ = 2048;
  const int gGatE = (E + 3) / 4;
  const int gGatN = (N + 3) / 4;

  prep_w_k<<<128, 256, 0, stream>>>(wp, Wprep);
  init_counts_k<<<gMax, thr, 0, stream>>>(cn, ce, N, E);
  // GEMM1 ∥ histogram (independent; co-scheduled in one launch)
  combo1_k<<<NT + HB, 256, 0, stream>>>(x, WP(0), xx, WP(4), tb, N, NT,
                                        node_idx, edge_idx, cn, ce, NNZ);
  scan_partials_k<<<NCHN + NCHE, 256, 0, stream>>>(cn, ce, part, NCHN, N, NCHE, E);
  scan_chunks_k<<<1, 256, 0, stream>>>(part, NCHN, NCHE);
  scan_apply_k<<<NCHN + NCHE, 256, 0, stream>>>(cn, ce, part, offs_n, offs_e, NCHN, N, NCHE, E);
  fill_deg_k<<<gMax, thr, 0, stream>>>(offs_n, offs_e, Dn_inv, De_inv,
                                       cur_be, cur_bn, cur_n, cur_e, N, E, NBE, NBN);
  partition2_k<<<gNNZ, thr, 0, stream>>>(node_idx, edge_idx, cur_be, cur_bn, SE, SN, NNZ);
  scatter_both_k<<<NBE + NBN, 256, 0, stream>>>(SE, offs_e, cur_be, listE, E, NBE,
                                                SN, offs_n, cur_bn, listN, N);

  // ---- fused dual-encoder (width-256; bf16 data plane) ----
  gather_edge_k<0><<<gGatE, 256, 0, stream>>>(tb, offs_e, listE, De_inv, e1_bn2e, e2_bn2e,
                                              alphap, e_fullb, nullptr, nullptr, E);
  gather_node_k<<<gGatN, 256, 0, stream>>>(e_fullb, tb, offs_n, listN, Dn_inv, e1_bn2e, e2_bn2e,
                                           alphap, thb, N);
  gemm_fuse_hid_k<<<NT, 256, 0, stream>>>(thb, WP(2), e1_be2n, WP(1),
                                          WP(6), e2_be2n, WP(5), alphap, tb, N);
  gather_edge_k<1><<<gGatE, 256, 0, stream>>>(tb, offs_e, listE, De_inv, e1_bn2e + DD, e2_bn2e + DD,
                                              alphap, e_fullb, e1o, e2o, E);
  gather_node_k<<<gGatN, 256, 0, stream>>>(e_fullb, tb, offs_n, listN, Dn_inv, e1_bn2e + DD, e2_bn2e + DD,
                                           alphap, aggb, N);
  enc_final_k<<<NT, 256, 0, stream>>>(aggb, WP(3), e1_be2n + DD, WP(7), e2_be2n + DD,
                                      alphap, n1, n2, n1b, n2b, nn1, N);

  // ---- fully-fused decoders ----
  dim3 gDec(NT, 2);
  dec_fused_k<<<gDec, 256, 0, stream>>>(n1b, n2b, aggb,
                                        WP(10), WP(8), d1_b, WP(11), WP(9), d1_b + DD,
                                        WP(14), WP(12), d2_b, WP(15), WP(13), d2_b + DD,
                                        alphap, x11, x22, x12, x21, N);
}